// Round 14
// baseline (1204.065 us; speedup 1.0000x reference)
//
#include <hip/hip_runtime.h>
#include <hip/hip_bf16.h>

// ============================================================================
// EstVAEStudent forward, round 14: round 13 +
//  (a) mean-pool fused into conv3 epilogue (atomicAdd into zeroed f32 h):
//      kills 57MB y3 store + 115MB mean7 kernel.
//  (b) hlin2 -> bf16 MFMA (padded-N weights, col<64 guard).
//  (c) head -> 3-term hi/lo MFMA (o2 bf16 pair, padded hi/lo weights, col<23).
//  Remaining fp32 VALU GEMM: router only (routing safety).
// ============================================================================

#define BATCH 4096
typedef unsigned short u16;
typedef unsigned int u32;
using bf16x8 = __attribute__((ext_vector_type(8))) __bf16;
using f32x4  = __attribute__((ext_vector_type(4))) float;

__device__ __forceinline__ float silu_f(float v) { return v / (1.f + __expf(-v)); }

__device__ __forceinline__ float b2f(u16 u) {
  union { u32 i; float f; } c; c.i = ((u32)u) << 16; return c.f;
}
__device__ __forceinline__ u16 f2b(float f) {
  union { float f; u32 i; } c; c.f = f;
  u32 r = c.i + 0x7FFFu + ((c.i >> 16) & 1u);
  return (u16)(r >> 16);
}
__device__ __forceinline__ float4 ld4(const float* p) { return *(const float4*)p; }
__device__ __forceinline__ float4 ld4(const u16* p) {
  ushort4 v = *(const ushort4*)p;
  return make_float4(b2f(v.x), b2f(v.y), b2f(v.z), b2f(v.w));
}

// global_load_lds, 16B per lane, wave-uniform LDS base (lane l -> base+l*16B).
__device__ __forceinline__ void gll16(const u16* g, u16* l) {
  __attribute__((address_space(3))) u32* lp =
      reinterpret_cast<__attribute__((address_space(3))) u32*>(
          reinterpret_cast<uintptr_t>(l));
  __builtin_amdgcn_global_load_lds(reinterpret_cast<const u32*>(g), lp, 16, 0, 0);
}

union U8 { uint4 u; bf16x8 b; };

// ---------------- workspace layout (BYTE offsets) ----------------
static constexpr size_t WT1T_B = 0;               // 256x288 bf16
static constexpr size_t WT2T_B = 147456;          // 512x768
static constexpr size_t WT3T_B = 933888;          // 1024x1536
static constexpr size_t HL1T_B = 4079616;         // 1024x1024 -> ends 6176768
static constexpr size_t RA_B   = 6176768;         // 58,720,256 B
static constexpr size_t RB_B   = 64897024;        // 54,525,952 B
static constexpr size_t P_B    = 119422976;
// RA phases:
static constexpr size_t FRH_B  = RA_B;                    // fut_ref hi bf16 20,971,520
static constexpr size_t FRL_B  = RA_B + 20971520;
static constexpr size_t E1H_B  = RA_B + 41943040;         // e1 pair bf16 8,388,608 ea
static constexpr size_t E1L_B  = RA_B + 50331648;
static constexpr size_t E2H_B  = RA_B;                    // e2 pair (fr dead) 8,388,608 ea
static constexpr size_t E2L_B  = RA_B + 8388608;
static constexpr size_t Y1_B   = RA_B;                    // conv1 out (52,428,800)
static constexpr size_t H_B    = RA_B;                    // h f32 16,777,216 (y1 dead)
static constexpr size_t WGT_B  = RA_B;                    // experts bf16 (h dead)
static constexpr size_t WUT_B  = RA_B + 16777216;
static constexpr size_t WDT_B  = RA_B + 33554432;
static constexpr size_t X_B    = RA_B + 50331648;         // x f32 8,388,608
static constexpr size_t SHGT_B = RA_B;                    // after moe_up (wg/wu dead)
static constexpr size_t SHUT_B = RA_B + 2097152;
static constexpr size_t SHDT_B = RA_B + 4194304;
static constexpr size_t O1T_B  = RA_B + 6291456;
static constexpr size_t O2T_B  = RA_B + 7340032;          // ends RA+9,437,184
static constexpr size_t H2_B   = RA_B + 25165824;         // f32 8,388,608
static constexpr size_t H2B_B  = RA_B + 33554432;         // h2 bf16 4,194,304 (wdT dead)
// RB phases:
static constexpr size_t E1TH_B = RB_B;                    // enc1 WT pair 5,242,880 ea
static constexpr size_t E1TL_B = RB_B + 5242880;
static constexpr size_t E2TH_B = RB_B + 10485760;         // enc2 WT pair 2,097,152 ea
static constexpr size_t E2TL_B = RB_B + 12582912;         // ends 14,680,064
static constexpr size_t PENC_B = RB_B + 14680064;         // K-split partials f32 2x16,777,216
static constexpr size_t HSB_B  = RB_B;                    // hist_seq bf16 (enc dead)
static constexpr size_t Y2_B   = RB_B;                    // conv2 out
static constexpr size_t HB_B   = RB_B;                    // hb bf16 8,388,608 (y2 dead)
static constexpr size_t HI1_B  = RB_B + 8388608;          // hi1b bf16 8,388,608
static constexpr size_t XCH_B  = RB_B + 16777216;         // concat pair bf16 3,145,728 ea
static constexpr size_t XCL_B  = RB_B + 19922944;
static constexpr size_t XH_B   = RB_B;                    // x bf16 4,194,304 (hb dead)
static constexpr size_t TM_B   = RB_B + 8388608;          // t_moe bf16 33,554,432
static constexpr size_t STB_B  = RB_B + 8388608;          // stb bf16 16,777,216 (tm dead)
static constexpr size_t O1B_B  = RB_B;                    // o1 bf16 8,388,608 (xh dead)
static constexpr size_t O2H_B  = RB_B + 16777216;         // o2 pair bf16 8,388,608 ea
static constexpr size_t O2L_B  = RB_B + 25165824;
// P smalls:
static constexpr size_t HLAT_B = P_B;
static constexpr size_t E3P_B  = P_B + 1048576;
static constexpr size_t Z_B    = P_B + 3145728;
static constexpr size_t LOG_B  = P_B + 4194304;
static constexpr size_t TID_B  = P_B + 4456448;
static constexpr size_t TW_B   = P_B + 4521984;
static constexpr size_t POS_B  = P_B + 4587520;
static constexpr size_t CNT_B  = P_B + 4653056;
static constexpr size_t OFS_B  = P_B + 4653184;
static constexpr size_t ROWL_B = P_B + 4653312;
static constexpr size_t WL_B   = P_B + 4718848;
static constexpr size_t ZP_B   = P_B + 4784384;           // 4096 B zero page
static constexpr size_t PRJH_B = P_B + 4788480;           // proj WT pair 393,216 ea
static constexpr size_t PRJL_B = P_B + 5181696;
static constexpr size_t E3TH_B = P_B + 5574912;           // enc3 WT pair 262,144 ea
static constexpr size_t E3TL_B = P_B + 5837056;           // ends P+6,099,200
static constexpr size_t HL2P_B = P_B + 6099200;           // hlin2 padded WT 262,144
static constexpr size_t HDH_B  = P_B + 6361344;           // head padded WT pair 262,144 ea
static constexpr size_t HDL_B  = P_B + 6623488;           // ends P+6,885,632

// XCD-coherent tile decode (128-row m-tiles): m-tiles % 8 == 0.
#define TILE_DECODE(nn_)                         \
  const int bid = blockIdx.x;                    \
  const int xcd = bid & 7;                       \
  const int tt_ = bid >> 3;                      \
  const int n0 = (tt_ % (nn_)) * 128;            \
  const int m0 = ((tt_ / (nn_)) * 8 + xcd) * 128;

// ---------------- prep kernels ----------------
__global__ void k_zero_i(int* __restrict__ p, int n) {
  int i = blockIdx.x * 64 + threadIdx.x;
  if (i < n) p[i] = 0;
}
__global__ void k_zero_f4(float4* __restrict__ p, int n4) {
  int i = blockIdx.x * 256 + threadIdx.x;
  if (i < n4) p[i] = make_float4(0.f, 0.f, 0.f, 0.f);
}
__global__ void k_f32_to_bf4(const float* __restrict__ s, u16* __restrict__ d, int n4) {
  int i = blockIdx.x * 256 + threadIdx.x;
  if (i >= n4) return;
  float4 v = *(const float4*)(s + (size_t)i * 4);
  *(ushort4*)(d + (size_t)i * 4) = make_ushort4(f2b(v.x), f2b(v.y), f2b(v.z), f2b(v.w));
}
// f32 -> (hi, lo) bf16 pair
__global__ void k_split_x(const float* __restrict__ s, u16* __restrict__ dh,
                          u16* __restrict__ dl, int n4) {
  int i = blockIdx.x * 256 + threadIdx.x;
  if (i >= n4) return;
  float4 v = *(const float4*)(s + (size_t)i * 4);
  float a[4] = {v.x, v.y, v.z, v.w};
  ushort4 h, l;
  u16* hp = (u16*)&h; u16* lp = (u16*)&l;
#pragma unroll
  for (int j = 0; j < 4; ++j) {
    u16 hh = f2b(a[j]);
    hp[j] = hh;
    lp[j] = f2b(a[j] - b2f(hh));
  }
  *(ushort4*)(dh + (size_t)i * 4) = h;
  *(ushort4*)(dl + (size_t)i * 4) = l;
}
// combine two f32 K-split partials: pair = split(act(P0+P1+bias)). N pow2.
template<int ACT>
__global__ void k_comb2(const float* __restrict__ P0, const float* __restrict__ P1,
                        const float* __restrict__ bias, u16* __restrict__ Ch,
                        u16* __restrict__ Cl, int N, int n4) {
  int i = blockIdx.x * 256 + threadIdx.x;
  if (i >= n4) return;
  float4 a = *(const float4*)(P0 + (size_t)i * 4);
  float4 b = *(const float4*)(P1 + (size_t)i * 4);
  int col = (i * 4) & (N - 1);
  float r[4] = {a.x + b.x, a.y + b.y, a.z + b.z, a.w + b.w};
  ushort4 h, l;
  u16* hp = (u16*)&h; u16* lp = (u16*)&l;
#pragma unroll
  for (int j = 0; j < 4; ++j) {
    float v = r[j] + bias[col + j];
    if (ACT) v = silu_f(v);
    u16 hh = f2b(v);
    hp[j] = hh;
    lp[j] = f2b(v - b2f(hh));
  }
  *(ushort4*)(Ch + (size_t)i * 4) = h;
  *(ushort4*)(Cl + (size_t)i * 4) = l;
}
// concat [obs|hlat|z] -> hi/lo bf16 pair [4096][384]
__global__ void k_concat_split(const float* __restrict__ obs,
                               const float* __restrict__ hl,
                               const float* __restrict__ z,
                               u16* __restrict__ dh, u16* __restrict__ dl) {
  int idx = blockIdx.x * 256 + threadIdx.x;
  if (idx >= BATCH * 384) return;
  int b = idx / 384, c = idx - b * 384;
  float v;
  if (c < 256)      v = obs[(size_t)b * 256 + c];
  else if (c < 320) v = hl[(size_t)b * 64 + (c - 256)];
  else              v = z[(size_t)b * 64 + (c - 320)];
  u16 h = f2b(v);
  dh[idx] = h;
  dl[idx] = f2b(v - b2f(h));
}
// conv weight: [O][I][3] fp32 -> WT[o][k*CIN+i] bf16
__global__ void k_wt_conv(const float* __restrict__ w, u16* __restrict__ wt,
                          int CIN, int COUT) {
  int idx = blockIdx.x * 256 + threadIdx.x;
  int Kc = CIN * 3;
  if (idx >= COUT * Kc) return;
  int o = idx / Kc, c = idx - o * Kc;
  int k = c / CIN, i = c - k * CIN;
  wt[idx] = f2b(w[(size_t)o * Kc + i * 3 + k]);
}
// dense weight: W[K][N] fp32 -> WT[N][K] bf16
__global__ __launch_bounds__(256) void k_transpose_bf(const float* __restrict__ W,
                                                      u16* __restrict__ WT,
                                                      int K, int N) {
  __shared__ float t[32][33];
  int n0 = blockIdx.x * 32, k0 = blockIdx.y * 32;
  int lx = threadIdx.x & 31, ly = threadIdx.x >> 5;
#pragma unroll
  for (int r = 0; r < 32; r += 8)
    t[ly + r][lx] = W[(size_t)(k0 + ly + r) * N + n0 + lx];
  __syncthreads();
#pragma unroll
  for (int r = 0; r < 32; r += 8)
    WT[(size_t)(n0 + ly + r) * K + k0 + lx] = f2b(t[lx][ly + r]);
}
// padded transpose: W[K][N] -> WT[Npad][K] bf16, rows >= N zero. grid.x=Npad/32.
__global__ __launch_bounds__(256) void k_transpose_bf_pad(const float* __restrict__ W,
                                                          u16* __restrict__ WT,
                                                          int K, int N) {
  __shared__ float t[32][33];
  int n0 = blockIdx.x * 32, k0 = blockIdx.y * 32;
  int lx = threadIdx.x & 31, ly = threadIdx.x >> 5;
#pragma unroll
  for (int r = 0; r < 32; r += 8)
    t[ly + r][lx] = (n0 + lx < N) ? W[(size_t)(k0 + ly + r) * N + n0 + lx] : 0.f;
  __syncthreads();
#pragma unroll
  for (int r = 0; r < 32; r += 8)
    WT[(size_t)(n0 + ly + r) * K + k0 + lx] = f2b(t[lx][ly + r]);
}
// padded hi/lo transpose: grid.x=Npad/32, rows >= N zero.
__global__ __launch_bounds__(256) void k_transpose_hilo_pad(const float* __restrict__ W,
                                                            u16* __restrict__ WTh,
                                                            u16* __restrict__ WTl,
                                                            int K, int N) {
  __shared__ float t[32][33];
  int n0 = blockIdx.x * 32, k0 = blockIdx.y * 32;
  int lx = threadIdx.x & 31, ly = threadIdx.x >> 5;
#pragma unroll
  for (int r = 0; r < 32; r += 8)
    t[ly + r][lx] = (n0 + lx < N) ? W[(size_t)(k0 + ly + r) * N + n0 + lx] : 0.f;
  __syncthreads();
#pragma unroll
  for (int r = 0; r < 32; r += 8) {
    float f = t[lx][ly + r];
    u16 h = f2b(f);
    size_t o = (size_t)(n0 + ly + r) * K + k0 + lx;
    WTh[o] = h;
    WTl[o] = f2b(f - b2f(h));
  }
}
// batched per-expert transpose
__global__ __launch_bounds__(256) void k_transpose_bf_b(const float* __restrict__ W,
                                                        u16* __restrict__ WT,
                                                        int K, int N) {
  const size_t eo = (size_t)blockIdx.z * K * N;
  __shared__ float t[32][33];
  int n0 = blockIdx.x * 32, k0 = blockIdx.y * 32;
  int lx = threadIdx.x & 31, ly = threadIdx.x >> 5;
#pragma unroll
  for (int r = 0; r < 32; r += 8)
    t[ly + r][lx] = W[eo + (size_t)(k0 + ly + r) * N + n0 + lx];
  __syncthreads();
#pragma unroll
  for (int r = 0; r < 32; r += 8)
    WT[eo + (size_t)(n0 + ly + r) * K + k0 + lx] = f2b(t[lx][ly + r]);
}
// hi/lo split transpose
__global__ __launch_bounds__(256) void k_transpose_hilo(const float* __restrict__ W,
                                                        u16* __restrict__ WTh,
                                                        u16* __restrict__ WTl,
                                                        int K, int N) {
  __shared__ float t[32][33];
  int n0 = blockIdx.x * 32, k0 = blockIdx.y * 32;
  int lx = threadIdx.x & 31, ly = threadIdx.x >> 5;
#pragma unroll
  for (int r = 0; r < 32; r += 8)
    t[ly + r][lx] = W[(size_t)(k0 + ly + r) * N + n0 + lx];
  __syncthreads();
#pragma unroll
  for (int r = 0; r < 32; r += 8) {
    float f = t[lx][ly + r];
    u16 h = f2b(f);
    size_t o = (size_t)(n0 + ly + r) * K + k0 + lx;
    WTh[o] = h;
    WTl[o] = f2b(f - b2f(h));
  }
}

// ============================================================================
// 128x128 gll GEMM cores: BK=32, 4 waves (2x2 of 64x64).
// LDS per tensor tile: 4096 u16; slot swizzle f(r)=(r>>1)&3.
// ============================================================================
#define PRO128 \
  const int tid = threadIdx.x; \
  const int lane = tid & 63; \
  const int wid = tid >> 6; \
  const int wr = (wid >> 1) * 64, wc = (wid & 1) * 64; \
  const int l15 = lane & 15, lsub = lane >> 4;

#define MFMA_BF16(a, b, c) __builtin_amdgcn_mfma_f32_16x16x32_bf16(a, b, c, 0, 0, 0)

// AP/BP = hi/lo parts of A/B; EPI: 0 f32, 1 bf16, 2 f32 +=, 3 bf16 pair.
// Nout: output col guard + stride (Nout <= B-tile span).
template<int ACT, int EPI, int AP, int BP>
__global__ __launch_bounds__(256) void k_gg(
    const u16* __restrict__ A0, const u16* __restrict__ A1,
    const u16* __restrict__ B0, const u16* __restrict__ B1,
    const float* __restrict__ bias,
    float* __restrict__ Cf, u16* __restrict__ Ch, u16* __restrict__ Cl,
    int K, int lda, int ldb, int nn, int Nout) {
  constexpr int NT = AP + BP;
  __shared__ u16 lds[NT * 4096];
  PRO128
  TILE_DECODE(nn)
  const int r0 = wid * 32 + (lane >> 2);
  const int sl = ((lane & 3) ^ ((r0 >> 1) & 3)) * 8;
  const u16* sA0 = A0 + (size_t)(m0 + r0) * lda + sl;
  const u16* sA1 = (AP == 2) ? A1 + (size_t)(m0 + r0) * lda + sl : nullptr;
  const u16* sB0 = B0 + (size_t)(n0 + r0) * ldb + sl;
  const u16* sB1 = (BP == 2) ? B1 + (size_t)(n0 + r0) * ldb + sl : nullptr;
  const size_t stepA = (size_t)16 * lda, stepB = (size_t)16 * ldb;
  const int wb = wid * 1024;

  f32x4 acc[4][4];
  const f32x4 zf = {0.f, 0.f, 0.f, 0.f};
#pragma unroll
  for (int i = 0; i < 4; ++i)
#pragma unroll
    for (int j = 0; j < 4; ++j) acc[i][j] = zf;

  for (int k0 = 0; k0 < K; k0 += 32) {
    {
      int t = 0;
      gll16(sA0 + k0, &lds[t * 4096 + wb]);
      gll16(sA0 + stepA + k0, &lds[t * 4096 + wb + 512]);
      ++t;
      if (AP == 2) {
        gll16(sA1 + k0, &lds[t * 4096 + wb]);
        gll16(sA1 + stepA + k0, &lds[t * 4096 + wb + 512]);
        ++t;
      }
      gll16(sB0 + k0, &lds[t * 4096 + wb]);
      gll16(sB0 + stepB + k0, &lds[t * 4096 + wb + 512]);
      ++t;
      if (BP == 2) {
        gll16(sB1 + k0, &lds[t * 4096 + wb]);
        gll16(sB1 + stepB + k0, &lds[t * 4096 + wb + 512]);
      }
    }
    __syncthreads();
    U8 fah[4], fal[4];
#pragma unroll
    for (int i = 0; i < 4; ++i) {
      int ra = wr + i * 16 + l15;
      int ao = ra * 32 + ((lsub ^ ((ra >> 1) & 3))) * 8;
      fah[i].u = *(const uint4*)&lds[ao];
      if (AP == 2) fal[i].u = *(const uint4*)&lds[4096 + ao];
    }
#pragma unroll
    for (int ni = 0; ni < 4; ++ni) {
      int rb = wc + ni * 16 + l15;
      int bo = AP * 4096 + rb * 32 + ((lsub ^ ((rb >> 1) & 3))) * 8;
      U8 fbh, fbl;
      fbh.u = *(const uint4*)&lds[bo];
      if (BP == 2) fbl.u = *(const uint4*)&lds[4096 + bo];
#pragma unroll
      for (int mi = 0; mi < 4; ++mi) {
        acc[mi][ni] = MFMA_BF16(fah[mi].b, fbh.b, acc[mi][ni]);
        if (BP == 2) acc[mi][ni] = MFMA_BF16(fah[mi].b, fbl.b, acc[mi][ni]);
        if (AP == 2) acc[mi][ni] = MFMA_BF16(fal[mi].b, fbh.b, acc[mi][ni]);
      }
    }
    __syncthreads();
  }
  const int row4 = lsub * 4;
#pragma unroll
  for (int mi = 0; mi < 4; ++mi)
#pragma unroll
    for (int ni = 0; ni < 4; ++ni) {
      int col = n0 + wc + ni * 16 + l15;
      if (col >= Nout) continue;
      float bv = bias[col];
#pragma unroll
      for (int j = 0; j < 4; ++j) {
        int row = m0 + wr + mi * 16 + row4 + j;
        float v = acc[mi][ni][j] + bv;
        if (ACT) v = silu_f(v);
        if (EPI == 0) Cf[(size_t)row * Nout + col] = v;
        else if (EPI == 1) Ch[(size_t)row * Nout + col] = f2b(v);
        else if (EPI == 2) Cf[(size_t)row * Nout + col] += v;
        else {
          u16 vh = f2b(v);
          Ch[(size_t)row * Nout + col] = vh;
          Cl[(size_t)row * Nout + col] = f2b(v - b2f(vh));
        }
      }
    }
}

// BK=64 1-term GEMM (K%64==0): half the barriers. 8-slot swizzle f(r)=r&7.
// EPI: 0 f32, 1 bf16, 2 f32 +=, 3 bf16 pair.
template<int ACT, int EPI>
__global__ __launch_bounds__(256) void k_gg64(
    const u16* __restrict__ A0, const u16* __restrict__ B0,
    const float* __restrict__ bias,
    float* __restrict__ Cf, u16* __restrict__ Ch, u16* __restrict__ Cl,
    int K, int lda, int ldb, int nn, int Nout) {
  __shared__ u16 lds[2 * 8192];
  PRO128
  TILE_DECODE(nn)
  const int soff = ((lane & 7) ^ (lane >> 3)) * 8;
  const u16* sAb = A0 + (size_t)(m0 + wid * 32 + (lane >> 3)) * lda + soff;
  const u16* sBb = B0 + (size_t)(n0 + wid * 32 + (lane >> 3)) * ldb + soff;
  const int wb = wid * 2048;

  f32x4 acc[4][4];
  const f32x4 zf = {0.f, 0.f, 0.f, 0.f};
#pragma unroll
  for (int i = 0; i < 4; ++i)
#pragma unroll
    for (int j = 0; j < 4; ++j) acc[i][j] = zf;

  for (int k0 = 0; k0 < K; k0 += 64) {
#pragma unroll
    for (int c = 0; c < 4; ++c) {
      gll16(sAb + (size_t)c * 8 * lda + k0, &lds[wb + c * 512]);
      gll16(sBb + (size_t)c * 8 * ldb + k0, &lds[8192 + wb + c * 512]);
    }
    __syncthreads();
#pragma unroll
    for (int h = 0; h < 2; ++h) {
      U8 fa[4], fb[4];
#pragma unroll
      for (int i = 0; i < 4; ++i) {
        int ra = wr + i * 16 + l15;
        fa[i].u = *(const uint4*)&lds[ra * 64 + (((h * 4 + lsub) ^ (ra & 7))) * 8];
        int rb = wc + i * 16 + l15;
        fb[i].u = *(const uint4*)&lds[8192 + rb * 64 + (((h * 4 + lsub) ^ (rb & 7))) * 8];
      }
#pragma unroll
      for (int mi = 0; mi < 4; ++mi)
#pragma unroll
        for (int ni = 0; ni < 4; ++ni)
          acc[mi][ni] = MFMA_BF16(fa[mi].b, fb[ni].b, acc[mi][ni]);
    }
    __syncthreads();
  }
  const int row4 = lsub * 4;
#pragma unroll
  for (int mi = 0; mi < 4; ++mi)
#pragma unroll
    for (int ni = 0; ni < 4; ++ni) {
      int col = n0 + wc + ni * 16 + l15;
      if (col >= Nout) continue;
      float bv = bias[col];
#pragma unroll
      for (int j = 0; j < 4; ++j) {
        int row = m0 + wr + mi * 16 + row4 + j;
        float v = acc[mi][ni][j] + bv;
        if (ACT) v = silu_f(v);
        if (EPI == 0) Cf[(size_t)row * Nout + col] = v;
        else if (EPI == 1) Ch[(size_t)row * Nout + col] = f2b(v);
        else if (EPI == 2) Cf[(size_t)row * Nout + col] += v;
        else {
          u16 vh = f2b(v);
          Ch[(size_t)row * Nout + col] = vh;
          Cl[(size_t)row * Nout + col] = f2b(v - b2f(vh));
        }
      }
    }
}

// 3-term (2x2) K-split partial GEMM: writes raw f32 partials to P + kh*4096*N.
__global__ __launch_bounds__(256) void k_ggp(
    const u16* __restrict__ A0, const u16* __restrict__ A1,
    const u16* __restrict__ B0, const u16* __restrict__ B1,
    float* __restrict__ P, int N, int Kh, int lda, int ldb, int nn) {
  __shared__ u16 lds[4 * 4096];
  PRO128
  const int bid = blockIdx.x;
  const int xcd = bid & 7;
  int t = bid >> 3;
  const int kh = t & 1; t >>= 1;
  const int n0 = (t % nn) * 128;
  const int m0 = ((t / nn) * 8 + xcd) * 128;
  const int koff = kh * Kh;
  const int r0 = wid * 32 + (lane >> 2);
  const int sl = ((lane & 3) ^ ((r0 >> 1) & 3)) * 8;
  const u16* sA0 = A0 + (size_t)(m0 + r0) * lda + sl + koff;
  const u16* sA1 = A1 + (size_t)(m0 + r0) * lda + sl + koff;
  const u16* sB0 = B0 + (size_t)(n0 + r0) * ldb + sl + koff;
  const u16* sB1 = B1 + (size_t)(n0 + r0) * ldb + sl + koff;
  const size_t stepA = (size_t)16 * lda, stepB = (size_t)16 * ldb;
  const int wb = wid * 1024;

  f32x4 acc[4][4];
  const f32x4 zf = {0.f, 0.f, 0.f, 0.f};
#pragma unroll
  for (int i = 0; i < 4; ++i)
#pragma unroll
    for (int j = 0; j < 4; ++j) acc[i][j] = zf;

  for (int k0 = 0; k0 < Kh; k0 += 32) {
    gll16(sA0 + k0, &lds[wb]);
    gll16(sA0 + stepA + k0, &lds[wb + 512]);
    gll16(sA1 + k0, &lds[4096 + wb]);
    gll16(sA1 + stepA + k0, &lds[4096 + wb + 512]);
    gll16(sB0 + k0, &lds[2 * 4096 + wb]);
    gll16(sB0 + stepB + k0, &lds[2 * 4096 + wb + 512]);
    gll16(sB1 + k0, &lds[3 * 4096 + wb]);
    gll16(sB1 + stepB + k0, &lds[3 * 4096 + wb + 512]);
    __syncthreads();
    U8 fah[4], fal[4];
#pragma unroll
    for (int i = 0; i < 4; ++i) {
      int ra = wr + i * 16 + l15;
      int ao = ra * 32 + ((lsub ^ ((ra >> 1) & 3))) * 8;
      fah[i].u = *(const uint4*)&lds[ao];
      fal[i].u = *(const uint4*)&lds[4096 + ao];
    }
#pragma unroll
    for (int ni = 0; ni < 4; ++ni) {
      int rb = wc + ni * 16 + l15;
      int bo = 2 * 4096 + rb * 32 + ((lsub ^ ((rb >> 1) & 3))) * 8;
      U8 fbh, fbl;
      fbh.u = *(const uint4*)&lds[bo];
      fbl.u = *(const uint4*)&lds[4096 + bo];
#pragma unroll
      for (int mi = 0; mi < 4; ++mi) {
        acc[mi][ni] = MFMA_BF16(fah[mi].b, fbh.b, acc[mi][ni]);
        acc[mi][ni] = MFMA_BF16(fah[mi].b, fbl.b, acc[mi][ni]);
        acc[mi][ni] = MFMA_BF16(fal[mi].b, fbh.b, acc[mi][ni]);
      }
    }
    __syncthreads();
  }
  float* Pk = P + (size_t)kh * ((size_t)BATCH * N);
  const int row4 = lsub * 4;
#pragma unroll
  for (int mi = 0; mi < 4; ++mi)
#pragma unroll
    for (int ni = 0; ni < 4; ++ni) {
      int col = n0 + wc + ni * 16 + l15;
#pragma unroll
      for (int j = 0; j < 4; ++j) {
        int row = m0 + wr + mi * 16 + row4 + j;
        Pk[(size_t)row * N + col] = acc[mi][ni][j];
      }
    }
}

// shared-expert dual, pure bf16 1-term: C bf16 = silu(A@G+bg)*(A@U+bu)
__global__ __launch_bounds__(256) void k_gdual1(
    const u16* __restrict__ A0, const u16* __restrict__ G0,
    const u16* __restrict__ U0,
    const float* __restrict__ bg, const float* __restrict__ bu,
    u16* __restrict__ C, int N, int K, int lda, int ldb, int nn) {
  __shared__ u16 lds[3 * 4096];
  PRO128
  TILE_DECODE(nn)
  const int r0 = wid * 32 + (lane >> 2);
  const int sl = ((lane & 3) ^ ((r0 >> 1) & 3)) * 8;
  const u16* sA = A0 + (size_t)(m0 + r0) * lda + sl;
  const u16* sG = G0 + (size_t)(n0 + r0) * ldb + sl;
  const u16* sU = U0 + (size_t)(n0 + r0) * ldb + sl;
  const size_t stepA = (size_t)16 * lda, stepB = (size_t)16 * ldb;
  const int wb = wid * 1024;
  f32x4 ag[4][4], au[4][4];
  const f32x4 zf = {0.f, 0.f, 0.f, 0.f};
#pragma unroll
  for (int i = 0; i < 4; ++i)
#pragma unroll
    for (int j = 0; j < 4; ++j) { ag[i][j] = zf; au[i][j] = zf; }

  for (int k0 = 0; k0 < K; k0 += 32) {
    gll16(sA + k0, &lds[wb]);
    gll16(sA + stepA + k0, &lds[wb + 512]);
    gll16(sG + k0, &lds[4096 + wb]);
    gll16(sG + stepB + k0, &lds[4096 + wb + 512]);
    gll16(sU + k0, &lds[2 * 4096 + wb]);
    gll16(sU + stepB + k0, &lds[2 * 4096 + wb + 512]);
    __syncthreads();
    U8 fa[4];
#pragma unroll
    for (int i = 0; i < 4; ++i) {
      int ra = wr + i * 16 + l15;
      fa[i].u = *(const uint4*)&lds[ra * 32 + ((lsub ^ ((ra >> 1) & 3))) * 8];
    }
#pragma unroll
    for (int ni = 0; ni < 4; ++ni) {
      int rb = wc + ni * 16 + l15;
      int bo = rb * 32 + ((lsub ^ ((rb >> 1) & 3))) * 8;
      U8 fg, fu;
      fg.u = *(const uint4*)&lds[4096 + bo];
      fu.u = *(const uint4*)&lds[2 * 4096 + bo];
#pragma unroll
      for (int mi = 0; mi < 4; ++mi) {
        ag[mi][ni] = MFMA_BF16(fa[mi].b, fg.b, ag[mi][ni]);
        au[mi][ni] = MFMA_BF16(fa[mi].b, fu.b, au[mi][ni]);
      }
    }
    __syncthreads();
  }
  const int row4 = lsub * 4;
#pragma unroll
  for (int mi = 0; mi < 4; ++mi)
#pragma unroll
    for (int ni = 0; ni < 4; ++ni) {
      int col = n0 + wc + ni * 16 + l15;
      float bgv = bg[col], buv = bu[col];
#pragma unroll
      for (int j = 0; j < 4; ++j) {
        int row = m0 + wr + mi * 16 + row4 + j;
        float v = silu_f(ag[mi][ni][j] + bgv) * (au[mi][ni][j] + buv);
        C[(size_t)row * N + col] = f2b(v);
      }
    }
}

// conv as implicit-im2col gll GEMM, BK=32 (conv1: K not divisible by 64).
template<int CIN, int TIN, int TOUT, int STRIDE>
__global__ __launch_bounds__(256) void k_gconv32(
    const u16* __restrict__ X, const u16* __restrict__ WT,
    const float* __restrict__ bias, u16* __restrict__ Y,
    const u16* __restrict__ zp, int COUT, int nn) {
  constexpr int K = CIN * 3;
  __shared__ u16 lds[2 * 4096];
  PRO128
  TILE_DECODE(nn)
  int bA_[2], tb_[2], sl_[2];
  const u16* sB[2];
#pragma unroll
  for (int i = 0; i < 2; ++i) {
    int r = wid * 32 + i * 16 + (lane >> 2);
    int sl = ((lane & 3) ^ ((r >> 1) & 3)) * 8;
    sl_[i] = sl;
    int m = m0 + r;
    int bb = m / TOUT;
    int tt = m - bb * TOUT;
    bA_[i] = bb;
    tb_[i] = tt * STRIDE - 1;
    sB[i] = WT + (size_t)(n0 + r) * K + sl;
  }
  const int wb = wid * 1024;
  f32x4 acc[4][4];
  const f32x4 zf = {0.f, 0.f, 0.f, 0.f};
#pragma unroll
  for (int i = 0; i < 4; ++i)
#pragma unroll
    for (int j = 0; j < 4; ++j) acc[i][j] = zf;

  for (int k0 = 0; k0 < K; k0 += 32) {
#pragma unroll
    for (int i = 0; i < 2; ++i) {
      int kk = k0 + sl_[i];
      int ker = kk / CIN;
      int i0 = kk - ker * CIN;
      int tin = tb_[i] + ker;
      const u16* sa = (tin >= 0 && tin < TIN)
          ? X + ((size_t)bA_[i] * TIN + tin) * CIN + i0 : zp;
      gll16(sa, &lds[wb + i * 512]);
      gll16(sB[i] + k0, &lds[4096 + wb + i * 512]);
    }
    __syncthreads();
    U8 fa[4], fb[4];
#pragma unroll
    for (int i = 0; i < 4; ++i) {
      int ra = wr + i * 16 + l15;
      fa[i].u = *(const uint4*)&lds[ra * 32 + ((lsub ^ ((ra >> 1) & 3))) * 8];
      int rb = wc + i * 16 + l15;
      fb[i].u = *(const uint4*)&lds[4096 + rb * 32 + ((lsub ^ ((rb >> 1) & 3))) * 8];
    }
#pragma unroll
    for (int mi = 0; mi < 4; ++mi)
#pragma unroll
      for (int ni = 0; ni < 4; ++ni)
        acc[mi][ni] = MFMA_BF16(fa[mi].b, fb[ni].b, acc[mi][ni]);
    __syncthreads();
  }
  const int row4 = lsub * 4;
#pragma unroll
  for (int mi = 0; mi < 4; ++mi)
#pragma unroll
    for (int ni = 0; ni < 4; ++ni) {
      int col = n0 + wc + ni * 16 + l15;
      float bv = bias[col];
#pragma unroll
      for (int j = 0; j < 4; ++j) {
        int row = m0 + wr + mi * 16 + row4 + j;
        Y[(size_t)row * COUT + col] = f2b(silu_f(acc[mi][ni][j] + bv));
      }
    }
}

// conv as implicit-im2col gll GEMM, BK=64, bf16 output (conv2).
template<int CIN, int TIN, int TOUT, int STRIDE>
__global__ __launch_bounds__(256) void k_gconv64(
    const u16* __restrict__ X, const u16* __restrict__ WT,
    const float* __restrict__ bias, u16* __restrict__ Y,
    const u16* __restrict__ zp, int COUT, int nn) {
  constexpr int K = CIN * 3;
  __shared__ u16 lds[2 * 8192];
  PRO128
  TILE_DECODE(nn)
  const int soff = ((lane & 7) ^ (lane >> 3)) * 8;
  int bA_[4], tb_[4];
#pragma unroll
  for (int c = 0; c < 4; ++c) {
    int m = m0 + wid * 32 + c * 8 + (lane >> 3);
    int bb = m / TOUT;
    int tt = m - bb * TOUT;
    bA_[c] = bb;
    tb_[c] = tt * STRIDE - 1;
  }
  const u16* sBb = WT + (size_t)(n0 + wid * 32 + (lane >> 3)) * K + soff;
  const int wb = wid * 2048;

  f32x4 acc[4][4];
  const f32x4 zf = {0.f, 0.f, 0.f, 0.f};
#pragma unroll
  for (int i = 0; i < 4; ++i)
#pragma unroll
    for (int j = 0; j < 4; ++j) acc[i][j] = zf;

  for (int k0 = 0; k0 < K; k0 += 64) {
    int kk = k0 + soff;
    int ker = kk / CIN;
    int i0 = kk - ker * CIN;
#pragma unroll
    for (int c = 0; c < 4; ++c) {
      int tin = tb_[c] + ker;
      const u16* sa = (tin >= 0 && tin < TIN)
          ? X + ((size_t)bA_[c] * TIN + tin) * CIN + i0 : zp;
      gll16(sa, &lds[wb + c * 512]);
      gll16(sBb + (size_t)c * 8 * K + k0, &lds[8192 + wb + c * 512]);
    }
    __syncthreads();
#pragma unroll
    for (int h = 0; h < 2; ++h) {
      U8 fa[4], fb[4];
#pragma unroll
      for (int i = 0; i < 4; ++i) {
        int ra = wr + i * 16 + l15;
        fa[i].u = *(const uint4*)&lds[ra * 64 + (((h * 4 + lsub) ^ (ra & 7))) * 8];
        int rb = wc + i * 16 + l15;
        fb[i].u = *(const uint4*)&lds[8192 + rb * 64 + (((h * 4 + lsub) ^ (rb & 7))) * 8];
      }
#pragma unroll
      for (int mi = 0; mi < 4; ++mi)
#pragma unroll
        for (int ni = 0; ni < 4; ++ni)
          acc[mi][ni] = MFMA_BF16(fa[mi].b, fb[ni].b, acc[mi][ni]);
    }
    __syncthreads();
  }
  const int row4 = lsub * 4;
#pragma unroll
  for (int mi = 0; mi < 4; ++mi)
#pragma unroll
    for (int ni = 0; ni < 4; ++ni) {
      int col = n0 + wc + ni * 16 + l15;
      float bv = bias[col];
#pragma unroll
      for (int j = 0; j < 4; ++j) {
        int row = m0 + wr + mi * 16 + row4 + j;
        Y[(size_t)row * COUT + col] = f2b(silu_f(acc[mi][ni][j] + bv));
      }
    }
}

// conv3 with fused mean-pool: atomicAdd(silu(conv+bias)/TOUT) into h f32 [B][COUT].
template<int CIN, int TIN, int TOUT, int STRIDE>
__global__ __launch_bounds__(256) void k_gconv64m(
    const u16* __restrict__ X, const u16* __restrict__ WT,
    const float* __restrict__ bias, float* __restrict__ Hm,
    const u16* __restrict__ zp, int COUT, int nn) {
  constexpr int K = CIN * 3;
  __shared__ u16 lds[2 * 8192];
  PRO128
  TILE_DECODE(nn)
  const int soff = ((lane & 7) ^ (lane >> 3)) * 8;
  int bA_[4], tb_[4];
#pragma unroll
  for (int c = 0; c < 4; ++c) {
    int m = m0 + wid * 32 + c * 8 + (lane >> 3);
    int bb = m / TOUT;
    int tt = m - bb * TOUT;
    bA_[c] = bb;
    tb_[c] = tt * STRIDE - 1;
  }
  const u16* sBb = WT + (size_t)(n0 + wid * 32 + (lane >> 3)) * K + soff;
  const int wb = wid * 2048;

  f32x4 acc[4][4];
  const f32x4 zf = {0.f, 0.f, 0.f, 0.f};
#pragma unroll
  for (int i = 0; i < 4; ++i)
#pragma unroll
    for (int j = 0; j < 4; ++j) acc[i][j] = zf;

  for (int k0 = 0; k0 < K; k0 += 64) {
    int kk = k0 + soff;
    int ker = kk / CIN;
    int i0 = kk - ker * CIN;
#pragma unroll
    for (int c = 0; c < 4; ++c) {
      int tin = tb_[c] + ker;
      const u16* sa = (tin >= 0 && tin < TIN)
          ? X + ((size_t)bA_[c] * TIN + tin) * CIN + i0 : zp;
      gll16(sa, &lds[wb + c * 512]);
      gll16(sBb + (size_t)c * 8 * K + k0, &lds[8192 + wb + c * 512]);
    }
    __syncthreads();
#pragma unroll
    for (int h = 0; h < 2; ++h) {
      U8 fa[4], fb[4];
#pragma unroll
      for (int i = 0; i < 4; ++i) {
        int ra = wr + i * 16 + l15;
        fa[i].u = *(const uint4*)&lds[ra * 64 + (((h * 4 + lsub) ^ (ra & 7))) * 8];
        int rb = wc + i * 16 + l15;
        fb[i].u = *(const uint4*)&lds[8192 + rb * 64 + (((h * 4 + lsub) ^ (rb & 7))) * 8];
      }
#pragma unroll
      for (int mi = 0; mi < 4; ++mi)
#pragma unroll
        for (int ni = 0; ni < 4; ++ni)
          acc[mi][ni] = MFMA_BF16(fa[mi].b, fb[ni].b, acc[mi][ni]);
    }
    __syncthreads();
  }
  const float invT = 1.f / (float)TOUT;
  const int row4 = lsub * 4;
#pragma unroll
  for (int mi = 0; mi < 4; ++mi)
#pragma unroll
    for (int ni = 0; ni < 4; ++ni) {
      int col = n0 + wc + ni * 16 + l15;
      float bv = bias[col];
#pragma unroll
      for (int j = 0; j < 4; ++j) {
        int row = m0 + wr + mi * 16 + row4 + j;
        int b = row / TOUT;
        atomicAdd(&Hm[(size_t)b * COUT + col], silu_f(acc[mi][ni][j] + bv) * invT);
      }
    }
}

// MoE up: expert->XCD swizzled 1D grid; gathered bf16 (1-term) dual.
__global__ __launch_bounds__(256) void k_gmoeup(
    const u16* __restrict__ xh,
    const u16* __restrict__ WgT, const u16* __restrict__ WuT,
    const float* __restrict__ bg, const float* __restrict__ bu,
    const int* __restrict__ rowlist, const int* __restrict__ counts,
    const int* __restrict__ offs, const u16* __restrict__ zp,
    u16* __restrict__ t_moe) {
  const int bid = blockIdx.x;
  const int xcd = bid & 7, sidx = bid >> 3;
  const int eo = sidx >> 8, r2 = sidx & 255;
  const int mt = r2 >> 3, nt = r2 & 7;
  const int e = xcd + 8 * eo;
  const int ne = counts[e];
  const int m0 = mt * 128;
  if (m0 >= ne) return;
  const int n0 = nt * 128;
  const int base = offs[e];
  constexpr int K = 512, N = 1024;
  const u16* Wge = WgT + (size_t)e * N * K;
  const u16* Wue = WuT + (size_t)e * N * K;
  const float* bge = bg + (size_t)e * N;
  const float* bue = bu + (size_t)e * N;
  __shared__ u16 lds[3 * 4096];
  PRO128
  const u16* sA[2]; const u16* sG[2]; const u16* sU[2];
#pragma unroll
  for (int i = 0; i < 2; ++i) {
    int r = wid * 32 + i * 16 + (lane >> 2);
    int sl = ((lane & 3) ^ ((r >> 1) & 3)) * 8;
    int grow = m0 + r;
    int xr = (grow < ne) ? rowlist[base + grow] : -1;
    sA[i] = (xr >= 0) ? xh + (size_t)xr * K + sl : zp;
    sG[i] = Wge + (size_t)(n0 + r) * K + sl;
    sU[i] = Wue + (size_t)(n0 + r) * K + sl;
  }
  const int wb = wid * 1024;
  f32x4 ag[4][4], au[4][4];
  const f32x4 zf = {0.f, 0.f, 0.f, 0.f};
#pragma unroll
  for (int i = 0; i < 4; ++i)
#pragma unroll
    for (int j = 0; j < 4; ++j) { ag[i][j] = zf; au[i][j] = zf; }

  for (int k0 = 0; k0 < K; k0 += 32) {
#pragma unroll
    for (int i = 0; i < 2; ++i) {
      gll16(sA[i] + k0, &lds[0 * 4096 + wb + i * 512]);
      gll16(sG[i] + k0, &lds[1 * 4096 + wb + i * 512]);
      gll16(sU[i] + k0, &lds[2 * 4096 + wb + i * 512]);
    }
    __syncthreads();
    U8 fa[4];
#pragma unroll
    for (int i = 0; i < 4; ++i) {
      int ra = wr + i * 16 + l15;
      fa[i].u = *(const uint4*)&lds[ra * 32 + ((lsub ^ ((ra >> 1) & 3))) * 8];
    }
#pragma unroll
    for (int ni = 0; ni < 4; ++ni) {
      int rb = wc + ni * 16 + l15;
      int bo = rb * 32 + ((lsub ^ ((rb >> 1) & 3))) * 8;
      U8 fg, fu;
      fg.u = *(const uint4*)&lds[1 * 4096 + bo];
      fu.u = *(const uint4*)&lds[2 * 4096 + bo];
#pragma unroll
      for (int mi = 0; mi < 4; ++mi) {
        ag[mi][ni] = MFMA_BF16(fa[mi].b, fg.b, ag[mi][ni]);
        au[mi][ni] = MFMA_BF16(fa[mi].b, fu.b, au[mi][ni]);
      }
    }
    __syncthreads();
  }
  const int row4 = lsub * 4;
#pragma unroll
  for (int mi = 0; mi < 4; ++mi)
#pragma unroll
    for (int ni = 0; ni < 4; ++ni) {
      int col = n0 + wc + ni * 16 + l15;
      float bgv = bge[col], buv = bue[col];
#pragma unroll
      for (int j = 0; j < 4; ++j) {
        int row = m0 + wr + mi * 16 + row4 + j;
        if (row >= ne) continue;
        float v = silu_f(ag[mi][ni][j] + bgv) * (au[mi][ni][j] + buv);
        t_moe[(size_t)(base + row) * N + col] = f2b(v);
      }
    }
}

// MoE down, BK=64: t_moe x WdT -> weighted atomic scatter into h2.
__global__ __launch_bounds__(256) void k_gmoedown64(
    const u16* __restrict__ t_moe, const u16* __restrict__ WdT,
    const float* __restrict__ bd, const int* __restrict__ rowlist,
    const float* __restrict__ wlist, const int* __restrict__ counts,
    const int* __restrict__ offs, const u16* __restrict__ zp,
    float* __restrict__ h2) {
  const int bid = blockIdx.x;
  const int xcd = bid & 7, sidx = bid >> 3;
  const int eo = sidx >> 7, r2 = sidx & 127;
  const int mt = r2 >> 2, nt = r2 & 3;
  const int e = xcd + 8 * eo;
  const int ne = counts[e];
  const int m0 = mt * 128;
  if (m0 >= ne) return;
  const int n0 = nt * 128;
  const int base = offs[e];
  constexpr int K = 1024, N = 512;
  const u16* Wde = WdT + (size_t)e * N * K;
  const float* bde = bd + (size_t)e * N;
  __shared__ u16 lds[2 * 8192];
  PRO128
  const int soff = ((lane & 7) ^ (lane >> 3)) * 8;
  const u16* sA[4];
#pragma unroll
  for (int c = 0; c < 4; ++c) {
    int grow = m0 + wid * 32 + c * 8 + (lane >> 3);
    sA[c] = (grow < ne) ? t_moe + (size_t)(base + grow) * K + soff : zp;
  }
  const u16* sBb = Wde + (size_t)(n0 + wid * 32 + (lane >> 3)) * K + soff;
  const int wb = wid * 2048;

  f32x4 acc[4][4];
  const f32x4 zf = {0.f, 0.f, 0.f, 0.f};
#pragma unroll
  for (int i = 0; i < 4; ++i)
#pragma unroll
    for (int j = 0; j < 4; ++j) acc[i][j] = zf;

  for (int k0 = 0; k0 < K; k0 += 64) {
#pragma unroll
    for (int c = 0; c < 4; ++c) {
      gll16(sA[c] + k0, &lds[wb + c * 512]);
      gll16(sBb + (size_t)c * 8 * K + k0, &lds[8192 + wb + c * 512]);
    }
    __syncthreads();
#pragma unroll
    for (int h = 0; h < 2; ++h) {
      U8 fa[4], fb[4];
#pragma unroll
      for (int i = 0; i < 4; ++i) {
        int ra = wr + i * 16 + l15;
        fa[i].u = *(const uint4*)&lds[ra * 64 + (((h * 4 + lsub) ^ (ra & 7))) * 8];
        int rb = wc + i * 16 + l15;
        fb[i].u = *(const uint4*)&lds[8192 + rb * 64 + (((h * 4 + lsub) ^ (rb & 7))) * 8];
      }
#pragma unroll
      for (int mi = 0; mi < 4; ++mi)
#pragma unroll
        for (int ni = 0; ni < 4; ++ni)
          acc[mi][ni] = MFMA_BF16(fa[mi].b, fb[ni].b, acc[mi][ni]);
    }
    __syncthreads();
  }
  const int row4 = lsub * 4;
#pragma unroll
  for (int mi = 0; mi < 4; ++mi)
#pragma unroll
    for (int j = 0; j < 4; ++j) {
      int row = m0 + wr + mi * 16 + row4 + j;
      if (row >= ne) continue;
      int r = rowlist[base + row];
      float wl = wlist[base + row];
#pragma unroll
      for (int ni = 0; ni < 4; ++ni) {
        int col = n0 + wc + ni * 16 + l15;
        atomicAdd(&h2[(size_t)r * 512 + col], wl * (acc[mi][ni][j] + bde[col]));
      }
    }
}

// ---------------- fp32 64x64 GEMM (router only) ----------------
template<int ACT, bool NG, typename TA>
__global__ __launch_bounds__(256) void k_gemm(const TA* __restrict__ A,
                                              const float* __restrict__ W,
                                              const float* __restrict__ bias,
                                              float* __restrict__ C,
                                              int N, int K) {
  __shared__ float As[16][64];
  __shared__ float Bs[16][64];
  const int tid = threadIdx.x;
  const int m0 = blockIdx.x * 64;
  const int n0 = blockIdx.y * 64;
  const int tr = tid >> 4, tc = tid & 15;
  const int lm = tid >> 2, lk = (tid & 3) * 4;
  const int ln = tid & 63, lkb = (tid >> 6) * 4;
  float acc[4][4] = {};
  for (int k0 = 0; k0 < K; k0 += 16) {
    float4 av = ld4(A + (size_t)(m0 + lm) * K + k0 + lk);
    As[lk + 0][lm] = av.x; As[lk + 1][lm] = av.y;
    As[lk + 2][lm] = av.z; As[lk + 3][lm] = av.w;
#pragma unroll
    for (int s = 0; s < 4; ++s) {
      int kk = lkb + s;
      float v = 0.f;
      if (!NG || (n0 + ln) < N) v = W[(size_t)(k0 + kk) * N + n0 + ln];
      Bs[kk][ln] = v;
    }
    __syncthreads();
#pragma unroll
    for (int kk = 0; kk < 16; ++kk) {
      float4 a4 = *(const float4*)&As[kk][tr * 4];
      float4 b4 = *(const float4*)&Bs[kk][tc * 4];
      float a[4] = {a4.x, a4.y, a4.z, a4.w};
      float b[4] = {b4.x, b4.y, b4.z, b4.w};
#pragma unroll
      for (int i = 0; i < 4; ++i)
#pragma unroll
        for (int j = 0; j < 4; ++j) acc[i][j] = fmaf(a[i], b[j], acc[i][j]);
    }
    __syncthreads();
  }
#pragma unroll
  for (int i = 0; i < 4; ++i) {
    int m = m0 + tr * 4 + i;
#pragma unroll
    for (int j = 0; j < 4; ++j) {
      int n = n0 + tc * 4 + j;
      if (NG && n >= N) continue;
      float v = acc[i][j] + bias[n];
      if (ACT == 1) v = silu_f(v);
      C[(size_t)m * N + n] = v;
    }
  }
}

// ---------------- small elementwise / router kernels ----------------
__global__ void k_z(const float* __restrict__ e3, const float* __restrict__ noise,
                    float* __restrict__ z) {
  int idx = blockIdx.x * 256 + threadIdx.x;
  if (idx >= BATCH * 64) return;
  int b = idx >> 6, j = idx & 63;
  float mu = e3[(size_t)b * 128 + j];
  float lv = e3[(size_t)b * 128 + 64 + j];
  z[idx] = mu + expf(0.5f * lv) * noise[idx];
}

__global__ void k_router(const float* __restrict__ logits, int* __restrict__ tidA,
                         float* __restrict__ twA, int* __restrict__ posA,
                         int* __restrict__ counts) {
  int b = blockIdx.x * 256 + threadIdx.x;
  if (b >= BATCH) return;
  float s[16];
#pragma unroll
  for (int e = 0; e < 16; ++e)
    s[e] = 1.f / (1.f + expf(-logits[(size_t)b * 16 + e]));
  float gsc[4];
#pragma unroll
  for (int g = 0; g < 4; ++g) {
    float m1 = -1e30f; int i1 = -1;
    for (int i = 0; i < 4; ++i) { float v = s[g * 4 + i]; if (v > m1) { m1 = v; i1 = i; } }
    float m2 = -1e30f;
    for (int i = 0; i < 4; ++i) { if (i == i1) continue; float v = s[g * 4 + i]; if (v > m2) m2 = v; }
    gsc[g] = m1 + m2;
  }
  int g1 = 0; float b1 = gsc[0];
  for (int g = 1; g < 4; ++g) if (gsc[g] > b1) { b1 = gsc[g]; g1 = g; }
  int g2 = -1; float b2 = -1e30f;
  for (int g = 0; g < 4; ++g) { if (g == g1) continue; if (gsc[g] > b2) { b2 = gsc[g]; g2 = g; } }
  float ms[16]; bool used[16];
#pragma unroll
  for (int e = 0; e < 16; ++e) {
    int g = e >> 2;
    ms[e] = (g == g1 || g == g2) ? s[e] : 0.f;
    used[e] = false;
  }
  int te[4]; float tv[4]; float tsum = 0.f;
  for (int t = 0; t < 4; ++t) {
    float best = -1.f; int bi = 0;
    for (int e = 0; e < 16; ++e)
      if (!used[e] && ms[e] > best) { best = ms[e]; bi = e; }
    used[bi] = true;
    te[t] = bi;
    tv[t] = s[bi];
    tsum += s[bi];
  }
  float inv = 1.f / (tsum + 1e-20f);
  for (int t = 0; t < 4; ++t) {
    int e = te[t];
    tidA[b * 4 + t] = e;
    twA[b * 4 + t] = tv[t] * inv;  // ROUTE_SCALE = 1.0
    posA[b * 4 + t] = atomicAdd(&counts[e], 1);
  }
}

__global__ void k_offsets(const int* __restrict__ counts, int* __restrict__ offs) {
  if (threadIdx.x == 0 && blockIdx.x == 0) {
    int a = 0;
    for (int e = 0; e < 16; ++e) { offs[e] = a; a += counts[e]; }
    offs[16] = a;
  }
}

__global__ void k_build(const int* __restrict__ tidA, const float* __restrict__ twA,
                        const int* __restrict__ posA, const int* __restrict__ offs,
                        int* __restrict__ rowlist, float* __restrict__ wlist) {
  int idx = blockIdx.x * 256 + threadIdx.x;
  if (idx >= BATCH * 4) return;
  int e = tidA[idx];
  int p = offs[e] + posA[idx];
  rowlist[p] = idx >> 2;
  wlist[p] = twA[idx];
}

// ============================================================================
extern "C" void kernel_launch(void* const* d_in, const int* in_sizes, int n_in,
                              void* d_out, int out_size, void* d_ws, size_t ws_size,
                              hipStream_t stream) {
  const float* cur_obs  = (const float*)d_in[0];
  const float* hist_seq = (const float*)d_in[1];
  const float* fut_ref  = (const float*)d_in[2];
  const float* noise    = (const float*)d_in[3];
  const float* conv1_w  = (const float*)d_in[4];
  const float* conv1_b  = (const float*)d_in[5];
  const float* conv2_w  = (const float*)d_in[6];
  const float* conv2_b  = (const float*)d_in[7];
  const float* conv3_w  = (const float*)d_in[8];
  const float* conv3_b  = (const float*)d_in[9];
  const float* hlin1_w  = (const float*)d_in[10];
  const float* hlin1_b  = (const float*)d_in[11];
  const float* hlin2_w  = (const float*)d_in[12];
  const float* hlin2_b  = (const float*)d_in[13];
  const float* enc1_w   = (const float*)d_in[14];
  const float* enc1_b   = (const float*)d_in[15];
  const float* enc2_w   = (const float*)d_in[16];
  const float* enc2_b   = (const float*)d_in[17];
  const float* enc3_w   = (const float*)d_in[18];
  const float* enc3_b   = (const float*)d_in[19];
  const float* proj_w   = (const float*)d_in[20];
  const float* proj_b   = (const float*)d_in[21];
  const float* router_w = (const float*)d_in[22];
  const float* router_b = (const float*)d_in[23];
  const float* Wg       = (const float*)d_in[24];
  const float* bg       = (const float*)d_in[25];
  const float* Wu       = (const float*)d_in[26];
  const float* bu       = (const float*)d_in[27];
  const float* Wd       = (const float*)d_in[28];
  const float* bd       = (const float*)d_in[29];
  const float* shg_w    = (const float*)d_in[30];
  const float* shg_b    = (const float*)d_in[31];
  const float* shu_w    = (const float*)d_in[32];
  const float* shu_b    = (const float*)d_in[33];
  const float* shd_w    = (const float*)d_in[34];
  const float* shd_b    = (const float*)d_in[35];
  const float* out1_w   = (const float*)d_in[36];
  const float* out1_b   = (const float*)d_in[37];
  const float* out2_w   = (const float*)d_in[38];
  const float* out2_b   = (const float*)d_in[39];
  const float* head_w   = (const float*)d_in[40];
  const float* head_b   = (const float*)d_in[41];
  (void)in_sizes; (void)n_in; (void)out_size; (void)ws_size;

  char* wsb = (char*)d_ws;
  u16* wt1T  = (u16*)(wsb + WT1T_B);
  u16* wt2T  = (u16*)(wsb + WT2T_B);
  u16* wt3T  = (u16*)(wsb + WT3T_B);
  u16* hl1T  = (u16*)(wsb + HL1T_B);
  u16* frh   = (u16*)(wsb + FRH_B);
  u16* frl   = (u16*)(wsb + FRL_B);
  u16* e1h   = (u16*)(wsb + E1H_B);
  u16* e1l   = (u16*)(wsb + E1L_B);
  u16* e2h   = (u16*)(wsb + E2H_B);
  u16* e2l   = (u16*)(wsb + E2L_B);
  u16* y1b   = (u16*)(wsb + Y1_B);
  u16* y2b   = (u16*)(wsb + Y2_B);
  float* hM  = (float*)(wsb + H_B);
  u16* wgT   = (u16*)(wsb + WGT_B);
  u16* wuT   = (u16*)(wsb + WUT_B);
  u16* wdT   = (u16*)(wsb + WDT_B);
  float* x   = (float*)(wsb + X_B);
  u16* shgT  = (u16*)(wsb + SHGT_B);
  u16* shuT  = (u16*)(wsb + SHUT_B);
  u16* shdT  = (u16*)(wsb + SHDT_B);
  u16* o1T   = (u16*)(wsb + O1T_B);
  u16* o2T   = (u16*)(wsb + O2T_B);
  float* h2  = (float*)(wsb + H2_B);
  u16* h2b   = (u16*)(wsb + H2B_B);
  u16* e1Th  = (u16*)(wsb + E1TH_B);
  u16* e1Tl  = (u16*)(wsb + E1TL_B);
  u16* e2Th  = (u16*)(wsb + E2TH_B);
  u16* e2Tl  = (u16*)(wsb + E2TL_B);
  float* Penc = (float*)(wsb + PENC_B);
  u16* hsb   = (u16*)(wsb + HSB_B);
  u16* hb    = (u16*)(wsb + HB_B);
  u16* hi1b  = (u16*)(wsb + HI1_B);
  u16* xch   = (u16*)(wsb + XCH_B);
  u16* xcl   = (u16*)(wsb + XCL_B);
  u16* xh    = (u16*)(wsb + XH_B);
  u16* tmoeb = (u16*)(wsb + TM_B);
  u16* stb   = (u16*)(wsb + STB_B);
  u16* o1b   = (u16*)(wsb + O1B_B);
  u16* o2h   = (u16*)(wsb + O2H_B);
  u16* o2l   = (u16*)(wsb + O2L_B);
  float* hlat = (float*)(wsb + HLAT_B);
  float* e3   = (float*)(wsb + E3P_B);
  float* z    = (float*)(wsb + Z_B);
  float* logitsb = (float*)(wsb + LOG_B);
  int*   tidA  = (int*)(wsb + TID_B);
  float* twA   = (float*)(wsb + TW_B);
  int*   posA  = (int*)(wsb + POS_B);
  int*   counts = (int*)(wsb + CNT_B);
  int*   offs  = (int*)(wsb + OFS_B);
  int*   rowlist = (int*)(wsb + ROWL_B);
  float* wlist = (float*)(wsb + WL_B);
  u16*   zp    = (u16*)(wsb + ZP_B);
  u16* prjTh = (u16*)(wsb + PRJH_B);
  u16* prjTl = (u16*)(wsb + PRJL_B);
  u16* e3Th  = (u16*)(wsb + E3TH_B);
  u16* e3Tl  = (u16*)(wsb + E3TL_B);
  u16* hl2P  = (u16*)(wsb + HL2P_B);
  u16* hdTh  = (u16*)(wsb + HDH_B);
  u16* hdTl  = (u16*)(wsb + HDL_B);

  k_zero_i<<<dim3(1), 64, 0, stream>>>(counts, 16);
  k_zero_i<<<dim3(16), 64, 0, stream>>>((int*)zp, 1024);

  // ---- weight prep ----
  k_wt_conv<<<dim3(288), 256, 0, stream>>>(conv1_w, wt1T, 96, 256);
  k_wt_conv<<<dim3(1536), 256, 0, stream>>>(conv2_w, wt2T, 256, 512);
  k_wt_conv<<<dim3(6144), 256, 0, stream>>>(conv3_w, wt3T, 512, 1024);
  k_transpose_bf<<<dim3(32, 32), 256, 0, stream>>>(hlin1_w, hl1T, 1024, 1024);
  k_transpose_hilo<<<dim3(32, 80), 256, 0, stream>>>(enc1_w, e1Th, e1Tl, 2560, 1024);
  k_transpose_hilo<<<dim3(32, 32), 256, 0, stream>>>(enc2_w, e2Th, e2Tl, 1024, 1024);
  k_transpose_hilo<<<dim3(4, 32), 256, 0, stream>>>(enc3_w, e3Th, e3Tl, 1024, 128);
  k_transpose_hilo<<<dim3(16, 12), 256, 0, stream>>>(proj_w, prjTh, prjTl, 384, 512);
  k_transpose_bf_pad<<<dim3(4, 32), 256, 0, stream>>>(hlin2_w, hl2P, 1024, 64);
  k_transpose_hilo_pad<<<dim3(4, 32), 256, 0, stream>>>(head_w, hdTh, hdTl, 1024, 23);

  // ---- VAE encoder (hi/lo 3-term, K-split x2) + reparameterize ----
  k_split_x<<<dim3(10240), 256, 0, stream>>>(fut_ref, frh, frl, BATCH * 2560 / 4);
  k_ggp<<<dim3(512), 256, 0, stream>>>(frh, frl, e1Th, e1Tl, Penc,
                                       1024, 1280, 2560, 2560, 8);
  k_comb2<1><<<dim3(4096), 256, 0, stream>>>(Penc, Penc + (size_t)BATCH * 1024,
                                             enc1_b, e1h, e1l, 1024, BATCH * 1024 / 4);
  k_ggp<<<dim3(512), 256, 0, stream>>>(e1h, e1l, e2Th, e2Tl, Penc,
                                       1024, 512, 1024, 1024, 8);
  k_comb2<1><<<dim3(4096), 256, 0, stream>>>(Penc, Penc + (size_t)BATCH * 1024,
                                             enc2_b, e2h, e2l, 1024, BATCH * 1024 / 4);
  k_gg<0, 0, 2, 2><<<dim3(32), 256, 0, stream>>>(e2h, e2l, e3Th, e3Tl, enc3_b,
      e3, nullptr, nullptr, 1024, 1024, 1024, 1, 128);
  k_z<<<dim3(1024), 256, 0, stream>>>(e3, noise, z);

  // ---- history conv encoder (conv3 fuses mean-pool via atomics) ----
  k_f32_to_bf4<<<dim3(9600), 256, 0, stream>>>(hist_seq, hsb, BATCH * 25 * 96 / 4);
  k_gconv32<96, 25, 25, 1><<<dim3(1600), 256, 0, stream>>>(hsb, wt1T, conv1_b, y1b, zp, 256, 2);
  k_gconv64<256, 25, 13, 2><<<dim3(1664), 256, 0, stream>>>(y1b, wt2T, conv2_b, y2b, zp, 512, 4);
  k_zero_f4<<<dim3(4096), 256, 0, stream>>>((float4*)hM, BATCH * 1024 / 4);
  k_gconv64m<512, 13, 7, 2><<<dim3(1792), 256, 0, stream>>>(y2b, wt3T, conv3_b, hM, zp, 1024, 8);
  k_f32_to_bf4<<<dim3(4096), 256, 0, stream>>>(hM, hb, BATCH * 1024 / 4);
  k_gg64<1, 1><<<dim3(256), 256, 0, stream>>>(hb, hl1T, hlin1_b,
      nullptr, hi1b, nullptr, 1024, 1024, 1024, 8, 1024);
  k_gg64<0, 0><<<dim3(32), 256, 0, stream>>>(hi1b, hl2P, hlin2_b,
      hlat, nullptr, nullptr, 1024, 1024, 1024, 1, 64);

  // ---- expert weight transposes (hM dead) ----
  k_transpose_bf_b<<<dim3(32, 16, 16), 256, 0, stream>>>(Wg, wgT, 512, 1024);
  k_transpose_bf_b<<<dim3(32, 16, 16), 256, 0, stream>>>(Wu, wuT, 512, 1024);
  k_transpose_bf_b<<<dim3(16, 32, 16), 256, 0, stream>>>(Wd, wdT, 1024, 512);

  // ---- projection (3-term hi/lo MFMA) + router (fp32) ----
  k_concat_split<<<dim3(6144), 256, 0, stream>>>(cur_obs, hlat, z, xch, xcl);
  k_gg<0, 0, 2, 2><<<dim3(128), 256, 0, stream>>>(xch, xcl, prjTh, prjTl, proj_b,
      x, nullptr, nullptr, 384, 384, 384, 4, 512);
  k_gemm<0, true, float><<<dim3(64, 1), 256, 0, stream>>>(x, router_w, router_b, logitsb, 16, 512);
  k_router<<<dim3(16), 256, 0, stream>>>(logitsb, tidA, twA, posA, counts);
  k_offsets<<<dim3(1), 64, 0, stream>>>(counts, offs);
  k_build<<<dim3(64), 256, 0, stream>>>(tidA, twA, posA, offs, rowlist, wlist);
  k_f32_to_bf4<<<dim3(2048), 256, 0, stream>>>(x, xh, BATCH * 512 / 4);

  // ---- MoE up (expert->XCD swizzled, pure bf16) ----
  k_gmoeup<<<dim3(4096), 256, 0, stream>>>(xh, wgT, wuT, bg, bu,
                                           rowlist, counts, offs, zp, tmoeb);

  // ---- sh/out bf16 weights into dead wg/wu region; zero h2 ----
  k_transpose_bf<<<dim3(64, 16), 256, 0, stream>>>(shg_w, shgT, 512, 2048);
  k_transpose_bf<<<dim3(64, 16), 256, 0, stream>>>(shu_w, shuT, 512, 2048);
  k_transpose_bf<<<dim3(16, 64), 256, 0, stream>>>(shd_w, shdT, 2048, 512);
  k_transpose_bf<<<dim3(32, 16), 256, 0, stream>>>(out1_w, o1T, 512, 1024);
  k_transpose_bf<<<dim3(32, 32), 256, 0, stream>>>(out2_w, o2T, 1024, 1024);
  k_zero_f4<<<dim3(2048), 256, 0, stream>>>((float4*)h2, BATCH * 512 / 4);

  // ---- MoE down (BK=64, atomic scatter into h2) ----
  k_gmoedown64<<<dim3(2048), 256, 0, stream>>>(tmoeb, wdT, bd, rowlist, wlist,
                                               counts, offs, zp, h2);

  // ---- shared experts (1-term dual), += into h2 (1-term BK=64 down) ----
  k_gdual1<<<dim3(512), 256, 0, stream>>>(xh, shgT, shuT, shg_b, shu_b,
                                          stb, 2048, 512, 512, 512, 16);
  k_gg64<0, 2><<<dim3(128), 256, 0, stream>>>(stb, shdT, shd_b,
      h2, nullptr, nullptr, 2048, 2048, 2048, 4, 512);

  // ---- output MLP (1-term bf16, BK=64; out2 emits pair) + head (3-term MFMA) ----
  k_f32_to_bf4<<<dim3(2048), 256, 0, stream>>>(h2, h2b, BATCH * 512 / 4);
  k_gg64<1, 1><<<dim3(256), 256, 0, stream>>>(h2b, o1T, out1_b,
      nullptr, o1b, nullptr, 512, 512, 512, 8, 1024);
  k_gg64<0, 3><<<dim3(256), 256, 0, stream>>>(o1b, o2T, out2_b,
      nullptr, o2h, o2l, 1024, 1024, 1024, 8, 1024);
  k_gg<0, 0, 2, 2><<<dim3(32), 256, 0, stream>>>(o2h, o2l, hdTh, hdTl, head_b,
      (float*)d_out, nullptr, nullptr, 1024, 1024, 1024, 1, 23);
}

// Round 15
// 1059.860 us; speedup vs baseline: 1.1361x; 1.1361x over previous
//
#include <hip/hip_runtime.h>
#include <hip/hip_bf16.h>

// ============================================================================
// EstVAEStudent forward, round 15: r14 minus the fused mean-pool regression
// (atomicAdd mean caused 2.7x write traffic; reverted to y3 store + k_mean7).
// Keeps: hlin2 bf16 MFMA (padded N), head 3-term hi/lo MFMA, o2 pair epilogue.
// ============================================================================

#define BATCH 4096
typedef unsigned short u16;
typedef unsigned int u32;
using bf16x8 = __attribute__((ext_vector_type(8))) __bf16;
using f32x4  = __attribute__((ext_vector_type(4))) float;

__device__ __forceinline__ float silu_f(float v) { return v / (1.f + __expf(-v)); }

__device__ __forceinline__ float b2f(u16 u) {
  union { u32 i; float f; } c; c.i = ((u32)u) << 16; return c.f;
}
__device__ __forceinline__ u16 f2b(float f) {
  union { float f; u32 i; } c; c.f = f;
  u32 r = c.i + 0x7FFFu + ((c.i >> 16) & 1u);
  return (u16)(r >> 16);
}
__device__ __forceinline__ float4 ld4(const float* p) { return *(const float4*)p; }
__device__ __forceinline__ float4 ld4(const u16* p) {
  ushort4 v = *(const ushort4*)p;
  return make_float4(b2f(v.x), b2f(v.y), b2f(v.z), b2f(v.w));
}

// global_load_lds, 16B per lane, wave-uniform LDS base (lane l -> base+l*16B).
__device__ __forceinline__ void gll16(const u16* g, u16* l) {
  __attribute__((address_space(3))) u32* lp =
      reinterpret_cast<__attribute__((address_space(3))) u32*>(
          reinterpret_cast<uintptr_t>(l));
  __builtin_amdgcn_global_load_lds(reinterpret_cast<const u32*>(g), lp, 16, 0, 0);
}

union U8 { uint4 u; bf16x8 b; };

// ---------------- workspace layout (BYTE offsets) ----------------
static constexpr size_t WT1T_B = 0;               // 256x288 bf16
static constexpr size_t WT2T_B = 147456;          // 512x768
static constexpr size_t WT3T_B = 933888;          // 1024x1536
static constexpr size_t HL1T_B = 4079616;         // 1024x1024 -> ends 6176768
static constexpr size_t RA_B   = 6176768;         // 58,720,256 B
static constexpr size_t RB_B   = 64897024;        // 54,525,952 B
static constexpr size_t P_B    = 119422976;
// RA phases:
static constexpr size_t FRH_B  = RA_B;                    // fut_ref hi bf16 20,971,520
static constexpr size_t FRL_B  = RA_B + 20971520;
static constexpr size_t E1H_B  = RA_B + 41943040;         // e1 pair bf16 8,388,608 ea
static constexpr size_t E1L_B  = RA_B + 50331648;
static constexpr size_t E2H_B  = RA_B;                    // e2 pair (fr dead) 8,388,608 ea
static constexpr size_t E2L_B  = RA_B + 8388608;
static constexpr size_t Y1_B   = RA_B;                    // conv1 out (52,428,800)
static constexpr size_t Y3_B   = RA_B;                    // conv3 out bf16 58,720,256 (y1 dead)
static constexpr size_t WGT_B  = RA_B;                    // experts bf16 (y3 dead)
static constexpr size_t WUT_B  = RA_B + 16777216;
static constexpr size_t WDT_B  = RA_B + 33554432;
static constexpr size_t X_B    = RA_B + 50331648;         // x f32 8,388,608
static constexpr size_t SHGT_B = RA_B;                    // after moe_up (wg/wu dead)
static constexpr size_t SHUT_B = RA_B + 2097152;
static constexpr size_t SHDT_B = RA_B + 4194304;
static constexpr size_t O1T_B  = RA_B + 6291456;
static constexpr size_t O2T_B  = RA_B + 7340032;          // ends RA+9,437,184
static constexpr size_t H2_B   = RA_B + 25165824;         // f32 8,388,608
static constexpr size_t H2B_B  = RA_B + 33554432;         // h2 bf16 4,194,304 (wdT dead)
// RB phases:
static constexpr size_t E1TH_B = RB_B;                    // enc1 WT pair 5,242,880 ea
static constexpr size_t E1TL_B = RB_B + 5242880;
static constexpr size_t E2TH_B = RB_B + 10485760;         // enc2 WT pair 2,097,152 ea
static constexpr size_t E2TL_B = RB_B + 12582912;         // ends 14,680,064
static constexpr size_t PENC_B = RB_B + 14680064;         // K-split partials f32 2x16,777,216
static constexpr size_t HSB_B  = RB_B;                    // hist_seq bf16 (enc dead)
static constexpr size_t Y2_B   = RB_B;                    // conv2 out
static constexpr size_t HB_B   = RB_B;                    // hb bf16 8,388,608 (y2 dead)
static constexpr size_t HI1_B  = RB_B + 8388608;          // hi1b bf16 8,388,608
static constexpr size_t XCH_B  = RB_B + 16777216;         // concat pair bf16 3,145,728 ea
static constexpr size_t XCL_B  = RB_B + 19922944;
static constexpr size_t XH_B   = RB_B;                    // x bf16 4,194,304 (hb dead)
static constexpr size_t TM_B   = RB_B + 8388608;          // t_moe bf16 33,554,432
static constexpr size_t STB_B  = RB_B + 8388608;          // stb bf16 16,777,216 (tm dead)
static constexpr size_t O1B_B  = RB_B;                    // o1 bf16 8,388,608 (xh dead)
static constexpr size_t O2H_B  = RB_B + 16777216;         // o2 pair bf16 8,388,608 ea
static constexpr size_t O2L_B  = RB_B + 25165824;
// P smalls:
static constexpr size_t HLAT_B = P_B;
static constexpr size_t E3P_B  = P_B + 1048576;
static constexpr size_t Z_B    = P_B + 3145728;
static constexpr size_t LOG_B  = P_B + 4194304;
static constexpr size_t TID_B  = P_B + 4456448;
static constexpr size_t TW_B   = P_B + 4521984;
static constexpr size_t POS_B  = P_B + 4587520;
static constexpr size_t CNT_B  = P_B + 4653056;
static constexpr size_t OFS_B  = P_B + 4653184;
static constexpr size_t ROWL_B = P_B + 4653312;
static constexpr size_t WL_B   = P_B + 4718848;
static constexpr size_t ZP_B   = P_B + 4784384;           // 4096 B zero page
static constexpr size_t PRJH_B = P_B + 4788480;           // proj WT pair 393,216 ea
static constexpr size_t PRJL_B = P_B + 5181696;
static constexpr size_t E3TH_B = P_B + 5574912;           // enc3 WT pair 262,144 ea
static constexpr size_t E3TL_B = P_B + 5837056;           // ends P+6,099,200
static constexpr size_t HL2P_B = P_B + 6099200;           // hlin2 padded WT 262,144
static constexpr size_t HDH_B  = P_B + 6361344;           // head padded WT pair 262,144 ea
static constexpr size_t HDL_B  = P_B + 6623488;           // ends P+6,885,632

// XCD-coherent tile decode (128-row m-tiles): m-tiles % 8 == 0.
#define TILE_DECODE(nn_)                         \
  const int bid = blockIdx.x;                    \
  const int xcd = bid & 7;                       \
  const int tt_ = bid >> 3;                      \
  const int n0 = (tt_ % (nn_)) * 128;            \
  const int m0 = ((tt_ / (nn_)) * 8 + xcd) * 128;

// ---------------- prep kernels ----------------
__global__ void k_zero_i(int* __restrict__ p, int n) {
  int i = blockIdx.x * 64 + threadIdx.x;
  if (i < n) p[i] = 0;
}
__global__ void k_zero_f4(float4* __restrict__ p, int n4) {
  int i = blockIdx.x * 256 + threadIdx.x;
  if (i < n4) p[i] = make_float4(0.f, 0.f, 0.f, 0.f);
}
__global__ void k_f32_to_bf4(const float* __restrict__ s, u16* __restrict__ d, int n4) {
  int i = blockIdx.x * 256 + threadIdx.x;
  if (i >= n4) return;
  float4 v = *(const float4*)(s + (size_t)i * 4);
  *(ushort4*)(d + (size_t)i * 4) = make_ushort4(f2b(v.x), f2b(v.y), f2b(v.z), f2b(v.w));
}
// f32 -> (hi, lo) bf16 pair
__global__ void k_split_x(const float* __restrict__ s, u16* __restrict__ dh,
                          u16* __restrict__ dl, int n4) {
  int i = blockIdx.x * 256 + threadIdx.x;
  if (i >= n4) return;
  float4 v = *(const float4*)(s + (size_t)i * 4);
  float a[4] = {v.x, v.y, v.z, v.w};
  ushort4 h, l;
  u16* hp = (u16*)&h; u16* lp = (u16*)&l;
#pragma unroll
  for (int j = 0; j < 4; ++j) {
    u16 hh = f2b(a[j]);
    hp[j] = hh;
    lp[j] = f2b(a[j] - b2f(hh));
  }
  *(ushort4*)(dh + (size_t)i * 4) = h;
  *(ushort4*)(dl + (size_t)i * 4) = l;
}
// combine two f32 K-split partials: pair = split(act(P0+P1+bias)). N pow2.
template<int ACT>
__global__ void k_comb2(const float* __restrict__ P0, const float* __restrict__ P1,
                        const float* __restrict__ bias, u16* __restrict__ Ch,
                        u16* __restrict__ Cl, int N, int n4) {
  int i = blockIdx.x * 256 + threadIdx.x;
  if (i >= n4) return;
  float4 a = *(const float4*)(P0 + (size_t)i * 4);
  float4 b = *(const float4*)(P1 + (size_t)i * 4);
  int col = (i * 4) & (N - 1);
  float r[4] = {a.x + b.x, a.y + b.y, a.z + b.z, a.w + b.w};
  ushort4 h, l;
  u16* hp = (u16*)&h; u16* lp = (u16*)&l;
#pragma unroll
  for (int j = 0; j < 4; ++j) {
    float v = r[j] + bias[col + j];
    if (ACT) v = silu_f(v);
    u16 hh = f2b(v);
    hp[j] = hh;
    lp[j] = f2b(v - b2f(hh));
  }
  *(ushort4*)(Ch + (size_t)i * 4) = h;
  *(ushort4*)(Cl + (size_t)i * 4) = l;
}
// concat [obs|hlat|z] -> hi/lo bf16 pair [4096][384]
__global__ void k_concat_split(const float* __restrict__ obs,
                               const float* __restrict__ hl,
                               const float* __restrict__ z,
                               u16* __restrict__ dh, u16* __restrict__ dl) {
  int idx = blockIdx.x * 256 + threadIdx.x;
  if (idx >= BATCH * 384) return;
  int b = idx / 384, c = idx - b * 384;
  float v;
  if (c < 256)      v = obs[(size_t)b * 256 + c];
  else if (c < 320) v = hl[(size_t)b * 64 + (c - 256)];
  else              v = z[(size_t)b * 64 + (c - 320)];
  u16 h = f2b(v);
  dh[idx] = h;
  dl[idx] = f2b(v - b2f(h));
}
// conv weight: [O][I][3] fp32 -> WT[o][k*CIN+i] bf16
__global__ void k_wt_conv(const float* __restrict__ w, u16* __restrict__ wt,
                          int CIN, int COUT) {
  int idx = blockIdx.x * 256 + threadIdx.x;
  int Kc = CIN * 3;
  if (idx >= COUT * Kc) return;
  int o = idx / Kc, c = idx - o * Kc;
  int k = c / CIN, i = c - k * CIN;
  wt[idx] = f2b(w[(size_t)o * Kc + i * 3 + k]);
}
// dense weight: W[K][N] fp32 -> WT[N][K] bf16
__global__ __launch_bounds__(256) void k_transpose_bf(const float* __restrict__ W,
                                                      u16* __restrict__ WT,
                                                      int K, int N) {
  __shared__ float t[32][33];
  int n0 = blockIdx.x * 32, k0 = blockIdx.y * 32;
  int lx = threadIdx.x & 31, ly = threadIdx.x >> 5;
#pragma unroll
  for (int r = 0; r < 32; r += 8)
    t[ly + r][lx] = W[(size_t)(k0 + ly + r) * N + n0 + lx];
  __syncthreads();
#pragma unroll
  for (int r = 0; r < 32; r += 8)
    WT[(size_t)(n0 + ly + r) * K + k0 + lx] = f2b(t[lx][ly + r]);
}
// padded transpose: W[K][N] -> WT[Npad][K] bf16, rows >= N zero. grid.x=Npad/32.
__global__ __launch_bounds__(256) void k_transpose_bf_pad(const float* __restrict__ W,
                                                          u16* __restrict__ WT,
                                                          int K, int N) {
  __shared__ float t[32][33];
  int n0 = blockIdx.x * 32, k0 = blockIdx.y * 32;
  int lx = threadIdx.x & 31, ly = threadIdx.x >> 5;
#pragma unroll
  for (int r = 0; r < 32; r += 8)
    t[ly + r][lx] = (n0 + lx < N) ? W[(size_t)(k0 + ly + r) * N + n0 + lx] : 0.f;
  __syncthreads();
#pragma unroll
  for (int r = 0; r < 32; r += 8)
    WT[(size_t)(n0 + ly + r) * K + k0 + lx] = f2b(t[lx][ly + r]);
}
// padded hi/lo transpose: grid.x=Npad/32, rows >= N zero.
__global__ __launch_bounds__(256) void k_transpose_hilo_pad(const float* __restrict__ W,
                                                            u16* __restrict__ WTh,
                                                            u16* __restrict__ WTl,
                                                            int K, int N) {
  __shared__ float t[32][33];
  int n0 = blockIdx.x * 32, k0 = blockIdx.y * 32;
  int lx = threadIdx.x & 31, ly = threadIdx.x >> 5;
#pragma unroll
  for (int r = 0; r < 32; r += 8)
    t[ly + r][lx] = (n0 + lx < N) ? W[(size_t)(k0 + ly + r) * N + n0 + lx] : 0.f;
  __syncthreads();
#pragma unroll
  for (int r = 0; r < 32; r += 8) {
    float f = t[lx][ly + r];
    u16 h = f2b(f);
    size_t o = (size_t)(n0 + ly + r) * K + k0 + lx;
    WTh[o] = h;
    WTl[o] = f2b(f - b2f(h));
  }
}
// batched per-expert transpose
__global__ __launch_bounds__(256) void k_transpose_bf_b(const float* __restrict__ W,
                                                        u16* __restrict__ WT,
                                                        int K, int N) {
  const size_t eo = (size_t)blockIdx.z * K * N;
  __shared__ float t[32][33];
  int n0 = blockIdx.x * 32, k0 = blockIdx.y * 32;
  int lx = threadIdx.x & 31, ly = threadIdx.x >> 5;
#pragma unroll
  for (int r = 0; r < 32; r += 8)
    t[ly + r][lx] = W[eo + (size_t)(k0 + ly + r) * N + n0 + lx];
  __syncthreads();
#pragma unroll
  for (int r = 0; r < 32; r += 8)
    WT[eo + (size_t)(n0 + ly + r) * K + k0 + lx] = f2b(t[lx][ly + r]);
}
// hi/lo split transpose
__global__ __launch_bounds__(256) void k_transpose_hilo(const float* __restrict__ W,
                                                        u16* __restrict__ WTh,
                                                        u16* __restrict__ WTl,
                                                        int K, int N) {
  __shared__ float t[32][33];
  int n0 = blockIdx.x * 32, k0 = blockIdx.y * 32;
  int lx = threadIdx.x & 31, ly = threadIdx.x >> 5;
#pragma unroll
  for (int r = 0; r < 32; r += 8)
    t[ly + r][lx] = W[(size_t)(k0 + ly + r) * N + n0 + lx];
  __syncthreads();
#pragma unroll
  for (int r = 0; r < 32; r += 8) {
    float f = t[lx][ly + r];
    u16 h = f2b(f);
    size_t o = (size_t)(n0 + ly + r) * K + k0 + lx;
    WTh[o] = h;
    WTl[o] = f2b(f - b2f(h));
  }
}

// ============================================================================
// 128x128 gll GEMM cores: BK=32, 4 waves (2x2 of 64x64).
// LDS per tensor tile: 4096 u16; slot swizzle f(r)=(r>>1)&3.
// ============================================================================
#define PRO128 \
  const int tid = threadIdx.x; \
  const int lane = tid & 63; \
  const int wid = tid >> 6; \
  const int wr = (wid >> 1) * 64, wc = (wid & 1) * 64; \
  const int l15 = lane & 15, lsub = lane >> 4;

#define MFMA_BF16(a, b, c) __builtin_amdgcn_mfma_f32_16x16x32_bf16(a, b, c, 0, 0, 0)

// AP/BP = hi/lo parts of A/B; EPI: 0 f32, 1 bf16, 2 f32 +=, 3 bf16 pair.
// Nout: output col guard + stride.
template<int ACT, int EPI, int AP, int BP>
__global__ __launch_bounds__(256) void k_gg(
    const u16* __restrict__ A0, const u16* __restrict__ A1,
    const u16* __restrict__ B0, const u16* __restrict__ B1,
    const float* __restrict__ bias,
    float* __restrict__ Cf, u16* __restrict__ Ch, u16* __restrict__ Cl,
    int K, int lda, int ldb, int nn, int Nout) {
  constexpr int NT = AP + BP;
  __shared__ u16 lds[NT * 4096];
  PRO128
  TILE_DECODE(nn)
  const int r0 = wid * 32 + (lane >> 2);
  const int sl = ((lane & 3) ^ ((r0 >> 1) & 3)) * 8;
  const u16* sA0 = A0 + (size_t)(m0 + r0) * lda + sl;
  const u16* sA1 = (AP == 2) ? A1 + (size_t)(m0 + r0) * lda + sl : nullptr;
  const u16* sB0 = B0 + (size_t)(n0 + r0) * ldb + sl;
  const u16* sB1 = (BP == 2) ? B1 + (size_t)(n0 + r0) * ldb + sl : nullptr;
  const size_t stepA = (size_t)16 * lda, stepB = (size_t)16 * ldb;
  const int wb = wid * 1024;

  f32x4 acc[4][4];
  const f32x4 zf = {0.f, 0.f, 0.f, 0.f};
#pragma unroll
  for (int i = 0; i < 4; ++i)
#pragma unroll
    for (int j = 0; j < 4; ++j) acc[i][j] = zf;

  for (int k0 = 0; k0 < K; k0 += 32) {
    {
      int t = 0;
      gll16(sA0 + k0, &lds[t * 4096 + wb]);
      gll16(sA0 + stepA + k0, &lds[t * 4096 + wb + 512]);
      ++t;
      if (AP == 2) {
        gll16(sA1 + k0, &lds[t * 4096 + wb]);
        gll16(sA1 + stepA + k0, &lds[t * 4096 + wb + 512]);
        ++t;
      }
      gll16(sB0 + k0, &lds[t * 4096 + wb]);
      gll16(sB0 + stepB + k0, &lds[t * 4096 + wb + 512]);
      ++t;
      if (BP == 2) {
        gll16(sB1 + k0, &lds[t * 4096 + wb]);
        gll16(sB1 + stepB + k0, &lds[t * 4096 + wb + 512]);
      }
    }
    __syncthreads();
    U8 fah[4], fal[4];
#pragma unroll
    for (int i = 0; i < 4; ++i) {
      int ra = wr + i * 16 + l15;
      int ao = ra * 32 + ((lsub ^ ((ra >> 1) & 3))) * 8;
      fah[i].u = *(const uint4*)&lds[ao];
      if (AP == 2) fal[i].u = *(const uint4*)&lds[4096 + ao];
    }
#pragma unroll
    for (int ni = 0; ni < 4; ++ni) {
      int rb = wc + ni * 16 + l15;
      int bo = AP * 4096 + rb * 32 + ((lsub ^ ((rb >> 1) & 3))) * 8;
      U8 fbh, fbl;
      fbh.u = *(const uint4*)&lds[bo];
      if (BP == 2) fbl.u = *(const uint4*)&lds[4096 + bo];
#pragma unroll
      for (int mi = 0; mi < 4; ++mi) {
        acc[mi][ni] = MFMA_BF16(fah[mi].b, fbh.b, acc[mi][ni]);
        if (BP == 2) acc[mi][ni] = MFMA_BF16(fah[mi].b, fbl.b, acc[mi][ni]);
        if (AP == 2) acc[mi][ni] = MFMA_BF16(fal[mi].b, fbh.b, acc[mi][ni]);
      }
    }
    __syncthreads();
  }
  const int row4 = lsub * 4;
#pragma unroll
  for (int mi = 0; mi < 4; ++mi)
#pragma unroll
    for (int ni = 0; ni < 4; ++ni) {
      int col = n0 + wc + ni * 16 + l15;
      if (col >= Nout) continue;
      float bv = bias[col];
#pragma unroll
      for (int j = 0; j < 4; ++j) {
        int row = m0 + wr + mi * 16 + row4 + j;
        float v = acc[mi][ni][j] + bv;
        if (ACT) v = silu_f(v);
        if (EPI == 0) Cf[(size_t)row * Nout + col] = v;
        else if (EPI == 1) Ch[(size_t)row * Nout + col] = f2b(v);
        else if (EPI == 2) Cf[(size_t)row * Nout + col] += v;
        else {
          u16 vh = f2b(v);
          Ch[(size_t)row * Nout + col] = vh;
          Cl[(size_t)row * Nout + col] = f2b(v - b2f(vh));
        }
      }
    }
}

// BK=64 1-term GEMM (K%64==0): half the barriers. 8-slot swizzle f(r)=r&7.
template<int ACT, int EPI>
__global__ __launch_bounds__(256) void k_gg64(
    const u16* __restrict__ A0, const u16* __restrict__ B0,
    const float* __restrict__ bias,
    float* __restrict__ Cf, u16* __restrict__ Ch, u16* __restrict__ Cl,
    int K, int lda, int ldb, int nn, int Nout) {
  __shared__ u16 lds[2 * 8192];
  PRO128
  TILE_DECODE(nn)
  const int soff = ((lane & 7) ^ (lane >> 3)) * 8;
  const u16* sAb = A0 + (size_t)(m0 + wid * 32 + (lane >> 3)) * lda + soff;
  const u16* sBb = B0 + (size_t)(n0 + wid * 32 + (lane >> 3)) * ldb + soff;
  const int wb = wid * 2048;

  f32x4 acc[4][4];
  const f32x4 zf = {0.f, 0.f, 0.f, 0.f};
#pragma unroll
  for (int i = 0; i < 4; ++i)
#pragma unroll
    for (int j = 0; j < 4; ++j) acc[i][j] = zf;

  for (int k0 = 0; k0 < K; k0 += 64) {
#pragma unroll
    for (int c = 0; c < 4; ++c) {
      gll16(sAb + (size_t)c * 8 * lda + k0, &lds[wb + c * 512]);
      gll16(sBb + (size_t)c * 8 * ldb + k0, &lds[8192 + wb + c * 512]);
    }
    __syncthreads();
#pragma unroll
    for (int h = 0; h < 2; ++h) {
      U8 fa[4], fb[4];
#pragma unroll
      for (int i = 0; i < 4; ++i) {
        int ra = wr + i * 16 + l15;
        fa[i].u = *(const uint4*)&lds[ra * 64 + (((h * 4 + lsub) ^ (ra & 7))) * 8];
        int rb = wc + i * 16 + l15;
        fb[i].u = *(const uint4*)&lds[8192 + rb * 64 + (((h * 4 + lsub) ^ (rb & 7))) * 8];
      }
#pragma unroll
      for (int mi = 0; mi < 4; ++mi)
#pragma unroll
        for (int ni = 0; ni < 4; ++ni)
          acc[mi][ni] = MFMA_BF16(fa[mi].b, fb[ni].b, acc[mi][ni]);
    }
    __syncthreads();
  }
  const int row4 = lsub * 4;
#pragma unroll
  for (int mi = 0; mi < 4; ++mi)
#pragma unroll
    for (int ni = 0; ni < 4; ++ni) {
      int col = n0 + wc + ni * 16 + l15;
      if (col >= Nout) continue;
      float bv = bias[col];
#pragma unroll
      for (int j = 0; j < 4; ++j) {
        int row = m0 + wr + mi * 16 + row4 + j;
        float v = acc[mi][ni][j] + bv;
        if (ACT) v = silu_f(v);
        if (EPI == 0) Cf[(size_t)row * Nout + col] = v;
        else if (EPI == 1) Ch[(size_t)row * Nout + col] = f2b(v);
        else if (EPI == 2) Cf[(size_t)row * Nout + col] += v;
        else {
          u16 vh = f2b(v);
          Ch[(size_t)row * Nout + col] = vh;
          Cl[(size_t)row * Nout + col] = f2b(v - b2f(vh));
        }
      }
    }
}

// 3-term (2x2) K-split partial GEMM: writes raw f32 partials to P + kh*4096*N.
__global__ __launch_bounds__(256) void k_ggp(
    const u16* __restrict__ A0, const u16* __restrict__ A1,
    const u16* __restrict__ B0, const u16* __restrict__ B1,
    float* __restrict__ P, int N, int Kh, int lda, int ldb, int nn) {
  __shared__ u16 lds[4 * 4096];
  PRO128
  const int bid = blockIdx.x;
  const int xcd = bid & 7;
  int t = bid >> 3;
  const int kh = t & 1; t >>= 1;
  const int n0 = (t % nn) * 128;
  const int m0 = ((t / nn) * 8 + xcd) * 128;
  const int koff = kh * Kh;
  const int r0 = wid * 32 + (lane >> 2);
  const int sl = ((lane & 3) ^ ((r0 >> 1) & 3)) * 8;
  const u16* sA0 = A0 + (size_t)(m0 + r0) * lda + sl + koff;
  const u16* sA1 = A1 + (size_t)(m0 + r0) * lda + sl + koff;
  const u16* sB0 = B0 + (size_t)(n0 + r0) * ldb + sl + koff;
  const u16* sB1 = B1 + (size_t)(n0 + r0) * ldb + sl + koff;
  const size_t stepA = (size_t)16 * lda, stepB = (size_t)16 * ldb;
  const int wb = wid * 1024;

  f32x4 acc[4][4];
  const f32x4 zf = {0.f, 0.f, 0.f, 0.f};
#pragma unroll
  for (int i = 0; i < 4; ++i)
#pragma unroll
    for (int j = 0; j < 4; ++j) acc[i][j] = zf;

  for (int k0 = 0; k0 < Kh; k0 += 32) {
    gll16(sA0 + k0, &lds[wb]);
    gll16(sA0 + stepA + k0, &lds[wb + 512]);
    gll16(sA1 + k0, &lds[4096 + wb]);
    gll16(sA1 + stepA + k0, &lds[4096 + wb + 512]);
    gll16(sB0 + k0, &lds[2 * 4096 + wb]);
    gll16(sB0 + stepB + k0, &lds[2 * 4096 + wb + 512]);
    gll16(sB1 + k0, &lds[3 * 4096 + wb]);
    gll16(sB1 + stepB + k0, &lds[3 * 4096 + wb + 512]);
    __syncthreads();
    U8 fah[4], fal[4];
#pragma unroll
    for (int i = 0; i < 4; ++i) {
      int ra = wr + i * 16 + l15;
      int ao = ra * 32 + ((lsub ^ ((ra >> 1) & 3))) * 8;
      fah[i].u = *(const uint4*)&lds[ao];
      fal[i].u = *(const uint4*)&lds[4096 + ao];
    }
#pragma unroll
    for (int ni = 0; ni < 4; ++ni) {
      int rb = wc + ni * 16 + l15;
      int bo = 2 * 4096 + rb * 32 + ((lsub ^ ((rb >> 1) & 3))) * 8;
      U8 fbh, fbl;
      fbh.u = *(const uint4*)&lds[bo];
      fbl.u = *(const uint4*)&lds[4096 + bo];
#pragma unroll
      for (int mi = 0; mi < 4; ++mi) {
        acc[mi][ni] = MFMA_BF16(fah[mi].b, fbh.b, acc[mi][ni]);
        acc[mi][ni] = MFMA_BF16(fah[mi].b, fbl.b, acc[mi][ni]);
        acc[mi][ni] = MFMA_BF16(fal[mi].b, fbh.b, acc[mi][ni]);
      }
    }
    __syncthreads();
  }
  float* Pk = P + (size_t)kh * ((size_t)BATCH * N);
  const int row4 = lsub * 4;
#pragma unroll
  for (int mi = 0; mi < 4; ++mi)
#pragma unroll
    for (int ni = 0; ni < 4; ++ni) {
      int col = n0 + wc + ni * 16 + l15;
#pragma unroll
      for (int j = 0; j < 4; ++j) {
        int row = m0 + wr + mi * 16 + row4 + j;
        Pk[(size_t)row * N + col] = acc[mi][ni][j];
      }
    }
}

// shared-expert dual, pure bf16 1-term: C bf16 = silu(A@G+bg)*(A@U+bu)
__global__ __launch_bounds__(256) void k_gdual1(
    const u16* __restrict__ A0, const u16* __restrict__ G0,
    const u16* __restrict__ U0,
    const float* __restrict__ bg, const float* __restrict__ bu,
    u16* __restrict__ C, int N, int K, int lda, int ldb, int nn) {
  __shared__ u16 lds[3 * 4096];
  PRO128
  TILE_DECODE(nn)
  const int r0 = wid * 32 + (lane >> 2);
  const int sl = ((lane & 3) ^ ((r0 >> 1) & 3)) * 8;
  const u16* sA = A0 + (size_t)(m0 + r0) * lda + sl;
  const u16* sG = G0 + (size_t)(n0 + r0) * ldb + sl;
  const u16* sU = U0 + (size_t)(n0 + r0) * ldb + sl;
  const size_t stepA = (size_t)16 * lda, stepB = (size_t)16 * ldb;
  const int wb = wid * 1024;
  f32x4 ag[4][4], au[4][4];
  const f32x4 zf = {0.f, 0.f, 0.f, 0.f};
#pragma unroll
  for (int i = 0; i < 4; ++i)
#pragma unroll
    for (int j = 0; j < 4; ++j) { ag[i][j] = zf; au[i][j] = zf; }

  for (int k0 = 0; k0 < K; k0 += 32) {
    gll16(sA + k0, &lds[wb]);
    gll16(sA + stepA + k0, &lds[wb + 512]);
    gll16(sG + k0, &lds[4096 + wb]);
    gll16(sG + stepB + k0, &lds[4096 + wb + 512]);
    gll16(sU + k0, &lds[2 * 4096 + wb]);
    gll16(sU + stepB + k0, &lds[2 * 4096 + wb + 512]);
    __syncthreads();
    U8 fa[4];
#pragma unroll
    for (int i = 0; i < 4; ++i) {
      int ra = wr + i * 16 + l15;
      fa[i].u = *(const uint4*)&lds[ra * 32 + ((lsub ^ ((ra >> 1) & 3))) * 8];
    }
#pragma unroll
    for (int ni = 0; ni < 4; ++ni) {
      int rb = wc + ni * 16 + l15;
      int bo = rb * 32 + ((lsub ^ ((rb >> 1) & 3))) * 8;
      U8 fg, fu;
      fg.u = *(const uint4*)&lds[4096 + bo];
      fu.u = *(const uint4*)&lds[2 * 4096 + bo];
#pragma unroll
      for (int mi = 0; mi < 4; ++mi) {
        ag[mi][ni] = MFMA_BF16(fa[mi].b, fg.b, ag[mi][ni]);
        au[mi][ni] = MFMA_BF16(fa[mi].b, fu.b, au[mi][ni]);
      }
    }
    __syncthreads();
  }
  const int row4 = lsub * 4;
#pragma unroll
  for (int mi = 0; mi < 4; ++mi)
#pragma unroll
    for (int ni = 0; ni < 4; ++ni) {
      int col = n0 + wc + ni * 16 + l15;
      float bgv = bg[col], buv = bu[col];
#pragma unroll
      for (int j = 0; j < 4; ++j) {
        int row = m0 + wr + mi * 16 + row4 + j;
        float v = silu_f(ag[mi][ni][j] + bgv) * (au[mi][ni][j] + buv);
        C[(size_t)row * N + col] = f2b(v);
      }
    }
}

// conv as implicit-im2col gll GEMM, BK=32 (conv1: K not divisible by 64).
template<int CIN, int TIN, int TOUT, int STRIDE>
__global__ __launch_bounds__(256) void k_gconv32(
    const u16* __restrict__ X, const u16* __restrict__ WT,
    const float* __restrict__ bias, u16* __restrict__ Y,
    const u16* __restrict__ zp, int COUT, int nn) {
  constexpr int K = CIN * 3;
  __shared__ u16 lds[2 * 4096];
  PRO128
  TILE_DECODE(nn)
  int bA_[2], tb_[2], sl_[2];
  const u16* sB[2];
#pragma unroll
  for (int i = 0; i < 2; ++i) {
    int r = wid * 32 + i * 16 + (lane >> 2);
    int sl = ((lane & 3) ^ ((r >> 1) & 3)) * 8;
    sl_[i] = sl;
    int m = m0 + r;
    int bb = m / TOUT;
    int tt = m - bb * TOUT;
    bA_[i] = bb;
    tb_[i] = tt * STRIDE - 1;
    sB[i] = WT + (size_t)(n0 + r) * K + sl;
  }
  const int wb = wid * 1024;
  f32x4 acc[4][4];
  const f32x4 zf = {0.f, 0.f, 0.f, 0.f};
#pragma unroll
  for (int i = 0; i < 4; ++i)
#pragma unroll
    for (int j = 0; j < 4; ++j) acc[i][j] = zf;

  for (int k0 = 0; k0 < K; k0 += 32) {
#pragma unroll
    for (int i = 0; i < 2; ++i) {
      int kk = k0 + sl_[i];
      int ker = kk / CIN;
      int i0 = kk - ker * CIN;
      int tin = tb_[i] + ker;
      const u16* sa = (tin >= 0 && tin < TIN)
          ? X + ((size_t)bA_[i] * TIN + tin) * CIN + i0 : zp;
      gll16(sa, &lds[wb + i * 512]);
      gll16(sB[i] + k0, &lds[4096 + wb + i * 512]);
    }
    __syncthreads();
    U8 fa[4], fb[4];
#pragma unroll
    for (int i = 0; i < 4; ++i) {
      int ra = wr + i * 16 + l15;
      fa[i].u = *(const uint4*)&lds[ra * 32 + ((lsub ^ ((ra >> 1) & 3))) * 8];
      int rb = wc + i * 16 + l15;
      fb[i].u = *(const uint4*)&lds[4096 + rb * 32 + ((lsub ^ ((rb >> 1) & 3))) * 8];
    }
#pragma unroll
    for (int mi = 0; mi < 4; ++mi)
#pragma unroll
      for (int ni = 0; ni < 4; ++ni)
        acc[mi][ni] = MFMA_BF16(fa[mi].b, fb[ni].b, acc[mi][ni]);
    __syncthreads();
  }
  const int row4 = lsub * 4;
#pragma unroll
  for (int mi = 0; mi < 4; ++mi)
#pragma unroll
    for (int ni = 0; ni < 4; ++ni) {
      int col = n0 + wc + ni * 16 + l15;
      float bv = bias[col];
#pragma unroll
      for (int j = 0; j < 4; ++j) {
        int row = m0 + wr + mi * 16 + row4 + j;
        Y[(size_t)row * COUT + col] = f2b(silu_f(acc[mi][ni][j] + bv));
      }
    }
}

// conv as implicit-im2col gll GEMM, BK=64, bf16 output (conv2/conv3).
template<int CIN, int TIN, int TOUT, int STRIDE>
__global__ __launch_bounds__(256) void k_gconv64(
    const u16* __restrict__ X, const u16* __restrict__ WT,
    const float* __restrict__ bias, u16* __restrict__ Y,
    const u16* __restrict__ zp, int COUT, int nn) {
  constexpr int K = CIN * 3;
  __shared__ u16 lds[2 * 8192];
  PRO128
  TILE_DECODE(nn)
  const int soff = ((lane & 7) ^ (lane >> 3)) * 8;
  int bA_[4], tb_[4];
#pragma unroll
  for (int c = 0; c < 4; ++c) {
    int m = m0 + wid * 32 + c * 8 + (lane >> 3);
    int bb = m / TOUT;
    int tt = m - bb * TOUT;
    bA_[c] = bb;
    tb_[c] = tt * STRIDE - 1;
  }
  const u16* sBb = WT + (size_t)(n0 + wid * 32 + (lane >> 3)) * K + soff;
  const int wb = wid * 2048;

  f32x4 acc[4][4];
  const f32x4 zf = {0.f, 0.f, 0.f, 0.f};
#pragma unroll
  for (int i = 0; i < 4; ++i)
#pragma unroll
    for (int j = 0; j < 4; ++j) acc[i][j] = zf;

  for (int k0 = 0; k0 < K; k0 += 64) {
    int kk = k0 + soff;
    int ker = kk / CIN;
    int i0 = kk - ker * CIN;
#pragma unroll
    for (int c = 0; c < 4; ++c) {
      int tin = tb_[c] + ker;
      const u16* sa = (tin >= 0 && tin < TIN)
          ? X + ((size_t)bA_[c] * TIN + tin) * CIN + i0 : zp;
      gll16(sa, &lds[wb + c * 512]);
      gll16(sBb + (size_t)c * 8 * K + k0, &lds[8192 + wb + c * 512]);
    }
    __syncthreads();
#pragma unroll
    for (int h = 0; h < 2; ++h) {
      U8 fa[4], fb[4];
#pragma unroll
      for (int i = 0; i < 4; ++i) {
        int ra = wr + i * 16 + l15;
        fa[i].u = *(const uint4*)&lds[ra * 64 + (((h * 4 + lsub) ^ (ra & 7))) * 8];
        int rb = wc + i * 16 + l15;
        fb[i].u = *(const uint4*)&lds[8192 + rb * 64 + (((h * 4 + lsub) ^ (rb & 7))) * 8];
      }
#pragma unroll
      for (int mi = 0; mi < 4; ++mi)
#pragma unroll
        for (int ni = 0; ni < 4; ++ni)
          acc[mi][ni] = MFMA_BF16(fa[mi].b, fb[ni].b, acc[mi][ni]);
    }
    __syncthreads();
  }
  const int row4 = lsub * 4;
#pragma unroll
  for (int mi = 0; mi < 4; ++mi)
#pragma unroll
    for (int ni = 0; ni < 4; ++ni) {
      int col = n0 + wc + ni * 16 + l15;
      float bv = bias[col];
#pragma unroll
      for (int j = 0; j < 4; ++j) {
        int row = m0 + wr + mi * 16 + row4 + j;
        Y[(size_t)row * COUT + col] = f2b(silu_f(acc[mi][ni][j] + bv));
      }
    }
}

// MoE up: expert->XCD swizzled 1D grid; gathered bf16 (1-term) dual.
__global__ __launch_bounds__(256) void k_gmoeup(
    const u16* __restrict__ xh,
    const u16* __restrict__ WgT, const u16* __restrict__ WuT,
    const float* __restrict__ bg, const float* __restrict__ bu,
    const int* __restrict__ rowlist, const int* __restrict__ counts,
    const int* __restrict__ offs, const u16* __restrict__ zp,
    u16* __restrict__ t_moe) {
  const int bid = blockIdx.x;
  const int xcd = bid & 7, sidx = bid >> 3;
  const int eo = sidx >> 8, r2 = sidx & 255;
  const int mt = r2 >> 3, nt = r2 & 7;
  const int e = xcd + 8 * eo;
  const int ne = counts[e];
  const int m0 = mt * 128;
  if (m0 >= ne) return;
  const int n0 = nt * 128;
  const int base = offs[e];
  constexpr int K = 512, N = 1024;
  const u16* Wge = WgT + (size_t)e * N * K;
  const u16* Wue = WuT + (size_t)e * N * K;
  const float* bge = bg + (size_t)e * N;
  const float* bue = bu + (size_t)e * N;
  __shared__ u16 lds[3 * 4096];
  PRO128
  const u16* sA[2]; const u16* sG[2]; const u16* sU[2];
#pragma unroll
  for (int i = 0; i < 2; ++i) {
    int r = wid * 32 + i * 16 + (lane >> 2);
    int sl = ((lane & 3) ^ ((r >> 1) & 3)) * 8;
    int grow = m0 + r;
    int xr = (grow < ne) ? rowlist[base + grow] : -1;
    sA[i] = (xr >= 0) ? xh + (size_t)xr * K + sl : zp;
    sG[i] = Wge + (size_t)(n0 + r) * K + sl;
    sU[i] = Wue + (size_t)(n0 + r) * K + sl;
  }
  const int wb = wid * 1024;
  f32x4 ag[4][4], au[4][4];
  const f32x4 zf = {0.f, 0.f, 0.f, 0.f};
#pragma unroll
  for (int i = 0; i < 4; ++i)
#pragma unroll
    for (int j = 0; j < 4; ++j) { ag[i][j] = zf; au[i][j] = zf; }

  for (int k0 = 0; k0 < K; k0 += 32) {
#pragma unroll
    for (int i = 0; i < 2; ++i) {
      gll16(sA[i] + k0, &lds[0 * 4096 + wb + i * 512]);
      gll16(sG[i] + k0, &lds[1 * 4096 + wb + i * 512]);
      gll16(sU[i] + k0, &lds[2 * 4096 + wb + i * 512]);
    }
    __syncthreads();
    U8 fa[4];
#pragma unroll
    for (int i = 0; i < 4; ++i) {
      int ra = wr + i * 16 + l15;
      fa[i].u = *(const uint4*)&lds[ra * 32 + ((lsub ^ ((ra >> 1) & 3))) * 8];
    }
#pragma unroll
    for (int ni = 0; ni < 4; ++ni) {
      int rb = wc + ni * 16 + l15;
      int bo = rb * 32 + ((lsub ^ ((rb >> 1) & 3))) * 8;
      U8 fg, fu;
      fg.u = *(const uint4*)&lds[1 * 4096 + bo];
      fu.u = *(const uint4*)&lds[2 * 4096 + bo];
#pragma unroll
      for (int mi = 0; mi < 4; ++mi) {
        ag[mi][ni] = MFMA_BF16(fa[mi].b, fg.b, ag[mi][ni]);
        au[mi][ni] = MFMA_BF16(fa[mi].b, fu.b, au[mi][ni]);
      }
    }
    __syncthreads();
  }
  const int row4 = lsub * 4;
#pragma unroll
  for (int mi = 0; mi < 4; ++mi)
#pragma unroll
    for (int ni = 0; ni < 4; ++ni) {
      int col = n0 + wc + ni * 16 + l15;
      float bgv = bge[col], buv = bue[col];
#pragma unroll
      for (int j = 0; j < 4; ++j) {
        int row = m0 + wr + mi * 16 + row4 + j;
        if (row >= ne) continue;
        float v = silu_f(ag[mi][ni][j] + bgv) * (au[mi][ni][j] + buv);
        t_moe[(size_t)(base + row) * N + col] = f2b(v);
      }
    }
}

// MoE down, BK=64: t_moe x WdT -> weighted atomic scatter into h2.
__global__ __launch_bounds__(256) void k_gmoedown64(
    const u16* __restrict__ t_moe, const u16* __restrict__ WdT,
    const float* __restrict__ bd, const int* __restrict__ rowlist,
    const float* __restrict__ wlist, const int* __restrict__ counts,
    const int* __restrict__ offs, const u16* __restrict__ zp,
    float* __restrict__ h2) {
  const int bid = blockIdx.x;
  const int xcd = bid & 7, sidx = bid >> 3;
  const int eo = sidx >> 7, r2 = sidx & 127;
  const int mt = r2 >> 2, nt = r2 & 3;
  const int e = xcd + 8 * eo;
  const int ne = counts[e];
  const int m0 = mt * 128;
  if (m0 >= ne) return;
  const int n0 = nt * 128;
  const int base = offs[e];
  constexpr int K = 1024, N = 512;
  const u16* Wde = WdT + (size_t)e * N * K;
  const float* bde = bd + (size_t)e * N;
  __shared__ u16 lds[2 * 8192];
  PRO128
  const int soff = ((lane & 7) ^ (lane >> 3)) * 8;
  const u16* sA[4];
#pragma unroll
  for (int c = 0; c < 4; ++c) {
    int grow = m0 + wid * 32 + c * 8 + (lane >> 3);
    sA[c] = (grow < ne) ? t_moe + (size_t)(base + grow) * K + soff : zp;
  }
  const u16* sBb = Wde + (size_t)(n0 + wid * 32 + (lane >> 3)) * K + soff;
  const int wb = wid * 2048;

  f32x4 acc[4][4];
  const f32x4 zf = {0.f, 0.f, 0.f, 0.f};
#pragma unroll
  for (int i = 0; i < 4; ++i)
#pragma unroll
    for (int j = 0; j < 4; ++j) acc[i][j] = zf;

  for (int k0 = 0; k0 < K; k0 += 64) {
#pragma unroll
    for (int c = 0; c < 4; ++c) {
      gll16(sA[c] + k0, &lds[wb + c * 512]);
      gll16(sBb + (size_t)c * 8 * K + k0, &lds[8192 + wb + c * 512]);
    }
    __syncthreads();
#pragma unroll
    for (int h = 0; h < 2; ++h) {
      U8 fa[4], fb[4];
#pragma unroll
      for (int i = 0; i < 4; ++i) {
        int ra = wr + i * 16 + l15;
        fa[i].u = *(const uint4*)&lds[ra * 64 + (((h * 4 + lsub) ^ (ra & 7))) * 8];
        int rb = wc + i * 16 + l15;
        fb[i].u = *(const uint4*)&lds[8192 + rb * 64 + (((h * 4 + lsub) ^ (rb & 7))) * 8];
      }
#pragma unroll
      for (int mi = 0; mi < 4; ++mi)
#pragma unroll
        for (int ni = 0; ni < 4; ++ni)
          acc[mi][ni] = MFMA_BF16(fa[mi].b, fb[ni].b, acc[mi][ni]);
    }
    __syncthreads();
  }
  const int row4 = lsub * 4;
#pragma unroll
  for (int mi = 0; mi < 4; ++mi)
#pragma unroll
    for (int j = 0; j < 4; ++j) {
      int row = m0 + wr + mi * 16 + row4 + j;
      if (row >= ne) continue;
      int r = rowlist[base + row];
      float wl = wlist[base + row];
#pragma unroll
      for (int ni = 0; ni < 4; ++ni) {
        int col = n0 + wc + ni * 16 + l15;
        atomicAdd(&h2[(size_t)r * 512 + col], wl * (acc[mi][ni][j] + bde[col]));
      }
    }
}

// ---------------- fp32 64x64 GEMM (router only) ----------------
template<int ACT, bool NG, typename TA>
__global__ __launch_bounds__(256) void k_gemm(const TA* __restrict__ A,
                                              const float* __restrict__ W,
                                              const float* __restrict__ bias,
                                              float* __restrict__ C,
                                              int N, int K) {
  __shared__ float As[16][64];
  __shared__ float Bs[16][64];
  const int tid = threadIdx.x;
  const int m0 = blockIdx.x * 64;
  const int n0 = blockIdx.y * 64;
  const int tr = tid >> 4, tc = tid & 15;
  const int lm = tid >> 2, lk = (tid & 3) * 4;
  const int ln = tid & 63, lkb = (tid >> 6) * 4;
  float acc[4][4] = {};
  for (int k0 = 0; k0 < K; k0 += 16) {
    float4 av = ld4(A + (size_t)(m0 + lm) * K + k0 + lk);
    As[lk + 0][lm] = av.x; As[lk + 1][lm] = av.y;
    As[lk + 2][lm] = av.z; As[lk + 3][lm] = av.w;
#pragma unroll
    for (int s = 0; s < 4; ++s) {
      int kk = lkb + s;
      float v = 0.f;
      if (!NG || (n0 + ln) < N) v = W[(size_t)(k0 + kk) * N + n0 + ln];
      Bs[kk][ln] = v;
    }
    __syncthreads();
#pragma unroll
    for (int kk = 0; kk < 16; ++kk) {
      float4 a4 = *(const float4*)&As[kk][tr * 4];
      float4 b4 = *(const float4*)&Bs[kk][tc * 4];
      float a[4] = {a4.x, a4.y, a4.z, a4.w};
      float b[4] = {b4.x, b4.y, b4.z, b4.w};
#pragma unroll
      for (int i = 0; i < 4; ++i)
#pragma unroll
        for (int j = 0; j < 4; ++j) acc[i][j] = fmaf(a[i], b[j], acc[i][j]);
    }
    __syncthreads();
  }
#pragma unroll
  for (int i = 0; i < 4; ++i) {
    int m = m0 + tr * 4 + i;
#pragma unroll
    for (int j = 0; j < 4; ++j) {
      int n = n0 + tc * 4 + j;
      if (NG && n >= N) continue;
      float v = acc[i][j] + bias[n];
      if (ACT == 1) v = silu_f(v);
      C[(size_t)m * N + n] = v;
    }
  }
}

// ---------------- small elementwise / router kernels ----------------
__global__ void k_mean7(const u16* __restrict__ y3, u16* __restrict__ hb) {
  int idx = blockIdx.x * 256 + threadIdx.x;
  if (idx >= BATCH * 1024) return;
  int b = idx >> 10, o = idx & 1023;
  const u16* p = y3 + (size_t)b * 7 * 1024 + o;
  float s = 0.f;
#pragma unroll
  for (int t = 0; t < 7; ++t) s += b2f(p[(size_t)t * 1024]);
  hb[idx] = f2b(s * (1.f / 7.f));
}

__global__ void k_z(const float* __restrict__ e3, const float* __restrict__ noise,
                    float* __restrict__ z) {
  int idx = blockIdx.x * 256 + threadIdx.x;
  if (idx >= BATCH * 64) return;
  int b = idx >> 6, j = idx & 63;
  float mu = e3[(size_t)b * 128 + j];
  float lv = e3[(size_t)b * 128 + 64 + j];
  z[idx] = mu + expf(0.5f * lv) * noise[idx];
}

__global__ void k_router(const float* __restrict__ logits, int* __restrict__ tidA,
                         float* __restrict__ twA, int* __restrict__ posA,
                         int* __restrict__ counts) {
  int b = blockIdx.x * 256 + threadIdx.x;
  if (b >= BATCH) return;
  float s[16];
#pragma unroll
  for (int e = 0; e < 16; ++e)
    s[e] = 1.f / (1.f + expf(-logits[(size_t)b * 16 + e]));
  float gsc[4];
#pragma unroll
  for (int g = 0; g < 4; ++g) {
    float m1 = -1e30f; int i1 = -1;
    for (int i = 0; i < 4; ++i) { float v = s[g * 4 + i]; if (v > m1) { m1 = v; i1 = i; } }
    float m2 = -1e30f;
    for (int i = 0; i < 4; ++i) { if (i == i1) continue; float v = s[g * 4 + i]; if (v > m2) m2 = v; }
    gsc[g] = m1 + m2;
  }
  int g1 = 0; float b1 = gsc[0];
  for (int g = 1; g < 4; ++g) if (gsc[g] > b1) { b1 = gsc[g]; g1 = g; }
  int g2 = -1; float b2 = -1e30f;
  for (int g = 0; g < 4; ++g) { if (g == g1) continue; if (gsc[g] > b2) { b2 = gsc[g]; g2 = g; } }
  float ms[16]; bool used[16];
#pragma unroll
  for (int e = 0; e < 16; ++e) {
    int g = e >> 2;
    ms[e] = (g == g1 || g == g2) ? s[e] : 0.f;
    used[e] = false;
  }
  int te[4]; float tv[4]; float tsum = 0.f;
  for (int t = 0; t < 4; ++t) {
    float best = -1.f; int bi = 0;
    for (int e = 0; e < 16; ++e)
      if (!used[e] && ms[e] > best) { best = ms[e]; bi = e; }
    used[bi] = true;
    te[t] = bi;
    tv[t] = s[bi];
    tsum += s[bi];
  }
  float inv = 1.f / (tsum + 1e-20f);
  for (int t = 0; t < 4; ++t) {
    int e = te[t];
    tidA[b * 4 + t] = e;
    twA[b * 4 + t] = tv[t] * inv;  // ROUTE_SCALE = 1.0
    posA[b * 4 + t] = atomicAdd(&counts[e], 1);
  }
}

__global__ void k_offsets(const int* __restrict__ counts, int* __restrict__ offs) {
  if (threadIdx.x == 0 && blockIdx.x == 0) {
    int a = 0;
    for (int e = 0; e < 16; ++e) { offs[e] = a; a += counts[e]; }
    offs[16] = a;
  }
}

__global__ void k_build(const int* __restrict__ tidA, const float* __restrict__ twA,
                        const int* __restrict__ posA, const int* __restrict__ offs,
                        int* __restrict__ rowlist, float* __restrict__ wlist) {
  int idx = blockIdx.x * 256 + threadIdx.x;
  if (idx >= BATCH * 4) return;
  int e = tidA[idx];
  int p = offs[e] + posA[idx];
  rowlist[p] = idx >> 2;
  wlist[p] = twA[idx];
}

// ============================================================================
extern "C" void kernel_launch(void* const* d_in, const int* in_sizes, int n_in,
                              void* d_out, int out_size, void* d_ws, size_t ws_size,
                              hipStream_t stream) {
  const float* cur_obs  = (const float*)d_in[0];
  const float* hist_seq = (const float*)d_in[1];
  const float* fut_ref  = (const float*)d_in[2];
  const float* noise    = (const float*)d_in[3];
  const float* conv1_w  = (const float*)d_in[4];
  const float* conv1_b  = (const float*)d_in[5];
  const float* conv2_w  = (const float*)d_in[6];
  const float* conv2_b  = (const float*)d_in[7];
  const float* conv3_w  = (const float*)d_in[8];
  const float* conv3_b  = (const float*)d_in[9];
  const float* hlin1_w  = (const float*)d_in[10];
  const float* hlin1_b  = (const float*)d_in[11];
  const float* hlin2_w  = (const float*)d_in[12];
  const float* hlin2_b  = (const float*)d_in[13];
  const float* enc1_w   = (const float*)d_in[14];
  const float* enc1_b   = (const float*)d_in[15];
  const float* enc2_w   = (const float*)d_in[16];
  const float* enc2_b   = (const float*)d_in[17];
  const float* enc3_w   = (const float*)d_in[18];
  const float* enc3_b   = (const float*)d_in[19];
  const float* proj_w   = (const float*)d_in[20];
  const float* proj_b   = (const float*)d_in[21];
  const float* router_w = (const float*)d_in[22];
  const float* router_b = (const float*)d_in[23];
  const float* Wg       = (const float*)d_in[24];
  const float* bg       = (const float*)d_in[25];
  const float* Wu       = (const float*)d_in[26];
  const float* bu       = (const float*)d_in[27];
  const float* Wd       = (const float*)d_in[28];
  const float* bd       = (const float*)d_in[29];
  const float* shg_w    = (const float*)d_in[30];
  const float* shg_b    = (const float*)d_in[31];
  const float* shu_w    = (const float*)d_in[32];
  const float* shu_b    = (const float*)d_in[33];
  const float* shd_w    = (const float*)d_in[34];
  const float* shd_b    = (const float*)d_in[35];
  const float* out1_w   = (const float*)d_in[36];
  const float* out1_b   = (const float*)d_in[37];
  const float* out2_w   = (const float*)d_in[38];
  const float* out2_b   = (const float*)d_in[39];
  const float* head_w   = (const float*)d_in[40];
  const float* head_b   = (const float*)d_in[41];
  (void)in_sizes; (void)n_in; (void)out_size; (void)ws_size;

  char* wsb = (char*)d_ws;
  u16* wt1T  = (u16*)(wsb + WT1T_B);
  u16* wt2T  = (u16*)(wsb + WT2T_B);
  u16* wt3T  = (u16*)(wsb + WT3T_B);
  u16* hl1T  = (u16*)(wsb + HL1T_B);
  u16* frh   = (u16*)(wsb + FRH_B);
  u16* frl   = (u16*)(wsb + FRL_B);
  u16* e1h   = (u16*)(wsb + E1H_B);
  u16* e1l   = (u16*)(wsb + E1L_B);
  u16* e2h   = (u16*)(wsb + E2H_B);
  u16* e2l   = (u16*)(wsb + E2L_B);
  u16* y1b   = (u16*)(wsb + Y1_B);
  u16* y2b   = (u16*)(wsb + Y2_B);
  u16* y3b   = (u16*)(wsb + Y3_B);
  u16* wgT   = (u16*)(wsb + WGT_B);
  u16* wuT   = (u16*)(wsb + WUT_B);
  u16* wdT   = (u16*)(wsb + WDT_B);
  float* x   = (float*)(wsb + X_B);
  u16* shgT  = (u16*)(wsb + SHGT_B);
  u16* shuT  = (u16*)(wsb + SHUT_B);
  u16* shdT  = (u16*)(wsb + SHDT_B);
  u16* o1T   = (u16*)(wsb + O1T_B);
  u16* o2T   = (u16*)(wsb + O2T_B);
  float* h2  = (float*)(wsb + H2_B);
  u16* h2b   = (u16*)(wsb + H2B_B);
  u16* e1Th  = (u16*)(wsb + E1TH_B);
  u16* e1Tl  = (u16*)(wsb + E1TL_B);
  u16* e2Th  = (u16*)(wsb + E2TH_B);
  u16* e2Tl  = (u16*)(wsb + E2TL_B);
  float* Penc = (float*)(wsb + PENC_B);
  u16* hsb   = (u16*)(wsb + HSB_B);
  u16* hb    = (u16*)(wsb + HB_B);
  u16* hi1b  = (u16*)(wsb + HI1_B);
  u16* xch   = (u16*)(wsb + XCH_B);
  u16* xcl   = (u16*)(wsb + XCL_B);
  u16* xh    = (u16*)(wsb + XH_B);
  u16* tmoeb = (u16*)(wsb + TM_B);
  u16* stb   = (u16*)(wsb + STB_B);
  u16* o1b   = (u16*)(wsb + O1B_B);
  u16* o2h   = (u16*)(wsb + O2H_B);
  u16* o2l   = (u16*)(wsb + O2L_B);
  float* hlat = (float*)(wsb + HLAT_B);
  float* e3   = (float*)(wsb + E3P_B);
  float* z    = (float*)(wsb + Z_B);
  float* logitsb = (float*)(wsb + LOG_B);
  int*   tidA  = (int*)(wsb + TID_B);
  float* twA   = (float*)(wsb + TW_B);
  int*   posA  = (int*)(wsb + POS_B);
  int*   counts = (int*)(wsb + CNT_B);
  int*   offs  = (int*)(wsb + OFS_B);
  int*   rowlist = (int*)(wsb + ROWL_B);
  float* wlist = (float*)(wsb + WL_B);
  u16*   zp    = (u16*)(wsb + ZP_B);
  u16* prjTh = (u16*)(wsb + PRJH_B);
  u16* prjTl = (u16*)(wsb + PRJL_B);
  u16* e3Th  = (u16*)(wsb + E3TH_B);
  u16* e3Tl  = (u16*)(wsb + E3TL_B);
  u16* hl2P  = (u16*)(wsb + HL2P_B);
  u16* hdTh  = (u16*)(wsb + HDH_B);
  u16* hdTl  = (u16*)(wsb + HDL_B);

  k_zero_i<<<dim3(1), 64, 0, stream>>>(counts, 16);
  k_zero_i<<<dim3(16), 64, 0, stream>>>((int*)zp, 1024);

  // ---- weight prep ----
  k_wt_conv<<<dim3(288), 256, 0, stream>>>(conv1_w, wt1T, 96, 256);
  k_wt_conv<<<dim3(1536), 256, 0, stream>>>(conv2_w, wt2T, 256, 512);
  k_wt_conv<<<dim3(6144), 256, 0, stream>>>(conv3_w, wt3T, 512, 1024);
  k_transpose_bf<<<dim3(32, 32), 256, 0, stream>>>(hlin1_w, hl1T, 1024, 1024);
  k_transpose_hilo<<<dim3(32, 80), 256, 0, stream>>>(enc1_w, e1Th, e1Tl, 2560, 1024);
  k_transpose_hilo<<<dim3(32, 32), 256, 0, stream>>>(enc2_w, e2Th, e2Tl, 1024, 1024);
  k_transpose_hilo<<<dim3(4, 32), 256, 0, stream>>>(enc3_w, e3Th, e3Tl, 1024, 128);
  k_transpose_hilo<<<dim3(16, 12), 256, 0, stream>>>(proj_w, prjTh, prjTl, 384, 512);
  k_transpose_bf_pad<<<dim3(4, 32), 256, 0, stream>>>(hlin2_w, hl2P, 1024, 64);
  k_transpose_hilo_pad<<<dim3(4, 32), 256, 0, stream>>>(head_w, hdTh, hdTl, 1024, 23);

  // ---- VAE encoder (hi/lo 3-term, K-split x2) + reparameterize ----
  k_split_x<<<dim3(10240), 256, 0, stream>>>(fut_ref, frh, frl, BATCH * 2560 / 4);
  k_ggp<<<dim3(512), 256, 0, stream>>>(frh, frl, e1Th, e1Tl, Penc,
                                       1024, 1280, 2560, 2560, 8);
  k_comb2<1><<<dim3(4096), 256, 0, stream>>>(Penc, Penc + (size_t)BATCH * 1024,
                                             enc1_b, e1h, e1l, 1024, BATCH * 1024 / 4);
  k_ggp<<<dim3(512), 256, 0, stream>>>(e1h, e1l, e2Th, e2Tl, Penc,
                                       1024, 512, 1024, 1024, 8);
  k_comb2<1><<<dim3(4096), 256, 0, stream>>>(Penc, Penc + (size_t)BATCH * 1024,
                                             enc2_b, e2h, e2l, 1024, BATCH * 1024 / 4);
  k_gg<0, 0, 2, 2><<<dim3(32), 256, 0, stream>>>(e2h, e2l, e3Th, e3Tl, enc3_b,
      e3, nullptr, nullptr, 1024, 1024, 1024, 1, 128);
  k_z<<<dim3(1024), 256, 0, stream>>>(e3, noise, z);

  // ---- history conv encoder (y3 store + mean7, r13-proven) ----
  k_f32_to_bf4<<<dim3(9600), 256, 0, stream>>>(hist_seq, hsb, BATCH * 25 * 96 / 4);
  k_gconv32<96, 25, 25, 1><<<dim3(1600), 256, 0, stream>>>(hsb, wt1T, conv1_b, y1b, zp, 256, 2);
  k_gconv64<256, 25, 13, 2><<<dim3(1664), 256, 0, stream>>>(y1b, wt2T, conv2_b, y2b, zp, 512, 4);
  k_gconv64<512, 13, 7, 2><<<dim3(1792), 256, 0, stream>>>(y2b, wt3T, conv3_b, y3b, zp, 1024, 8);
  k_mean7<<<dim3(16384), 256, 0, stream>>>(y3b, hb);
  k_gg64<1, 1><<<dim3(256), 256, 0, stream>>>(hb, hl1T, hlin1_b,
      nullptr, hi1b, nullptr, 1024, 1024, 1024, 8, 1024);
  k_gg64<0, 0><<<dim3(32), 256, 0, stream>>>(hi1b, hl2P, hlin2_b,
      hlat, nullptr, nullptr, 1024, 1024, 1024, 1, 64);

  // ---- expert weight transposes (y3 dead) ----
  k_transpose_bf_b<<<dim3(32, 16, 16), 256, 0, stream>>>(Wg, wgT, 512, 1024);
  k_transpose_bf_b<<<dim3(32, 16, 16), 256, 0, stream>>>(Wu, wuT, 512, 1024);
  k_transpose_bf_b<<<dim3(16, 32, 16), 256, 0, stream>>>(Wd, wdT, 1024, 512);

  // ---- projection (3-term hi/lo MFMA) + router (fp32) ----
  k_concat_split<<<dim3(6144), 256, 0, stream>>>(cur_obs, hlat, z, xch, xcl);
  k_gg<0, 0, 2, 2><<<dim3(128), 256, 0, stream>>>(xch, xcl, prjTh, prjTl, proj_b,
      x, nullptr, nullptr, 384, 384, 384, 4, 512);
  k_gemm<0, true, float><<<dim3(64, 1), 256, 0, stream>>>(x, router_w, router_b, logitsb, 16, 512);
  k_router<<<dim3(16), 256, 0, stream>>>(logitsb, tidA, twA, posA, counts);
  k_offsets<<<dim3(1), 64, 0, stream>>>(counts, offs);
  k_build<<<dim3(64), 256, 0, stream>>>(tidA, twA, posA, offs, rowlist, wlist);
  k_f32_to_bf4<<<dim3(2048), 256, 0, stream>>>(x, xh, BATCH * 512 / 4);

  // ---- MoE up (expert->XCD swizzled, pure bf16) ----
  k_gmoeup<<<dim3(4096), 256, 0, stream>>>(xh, wgT, wuT, bg, bu,
                                           rowlist, counts, offs, zp, tmoeb);

  // ---- sh/out bf16 weights into dead wg/wu region; zero h2 ----
  k_transpose_bf<<<dim3(64, 16), 256, 0, stream>>>(shg_w, shgT, 512, 2048);
  k_transpose_bf<<<dim3(64, 16), 256, 0, stream>>>(shu_w, shuT, 512, 2048);
  k_transpose_bf<<<dim3(16, 64), 256, 0, stream>>>(shd_w, shdT, 2048, 512);
  k_transpose_bf<<<dim3(32, 16), 256, 0, stream>>>(out1_w, o1T, 512, 1024);
  k_transpose_bf<<<dim3(32, 32), 256, 0, stream>>>(out2_w, o2T, 1024, 1024);
  k_zero_f4<<<dim3(2048), 256, 0, stream>>>((float4*)h2, BATCH * 512 / 4);

  // ---- MoE down (BK=64, atomic scatter into h2) ----
  k_gmoedown64<<<dim3(2048), 256, 0, stream>>>(tmoeb, wdT, bd, rowlist, wlist,
                                               counts, offs, zp, h2);

  // ---- shared experts (1-term dual), += into h2 (1-term BK=64 down) ----
  k_gdual1<<<dim3(512), 256, 0, stream>>>(xh, shgT, shuT, shg_b, shu_b,
                                          stb, 2048, 512, 512, 512, 16);
  k_gg64<0, 2><<<dim3(128), 256, 0, stream>>>(stb, shdT, shd_b,
      h2, nullptr, nullptr, 2048, 2048, 2048, 4, 512);

  // ---- output MLP (1-term bf16, BK=64; out2 emits pair) + head (3-term MFMA) ----
  k_f32_to_bf4<<<dim3(2048), 256, 0, stream>>>(h2, h2b, BATCH * 512 / 4);
  k_gg64<1, 1><<<dim3(256), 256, 0, stream>>>(h2b, o1T, out1_b,
      nullptr, o1b, nullptr, 512, 512, 512, 8, 1024);
  k_gg64<0, 3><<<dim3(256), 256, 0, stream>>>(o1b, o2T, out2_b,
      nullptr, o2h, o2l, 1024, 1024, 1024, 8, 1024);
  k_gg<0, 0, 2, 2><<<dim3(32), 256, 0, stream>>>(o2h, o2l, hdTh, hdTl, head_b,
      (float*)d_out, nullptr, nullptr, 1024, 1024, 1024, 1, 23);
}

// Round 16
// 991.425 us; speedup vs baseline: 1.2145x; 1.0690x over previous
//
#include <hip/hip_runtime.h>
#include <hip/hip_bf16.h>

// ============================================================================
// EstVAEStudent forward, round 16: round 15 +
//  (a) K-split for grid-starved tails: enc3/hlin2/head (32 blocks -> 128,
//      S=4) and shared-down (128 -> 256, S=2), via proven partial+combine.
//  (b) launch fusion: zero kernels -> 1, conv weight preps -> 1.
// ============================================================================

#define BATCH 4096
typedef unsigned short u16;
typedef unsigned int u32;
using bf16x8 = __attribute__((ext_vector_type(8))) __bf16;
using f32x4  = __attribute__((ext_vector_type(4))) float;

__device__ __forceinline__ float silu_f(float v) { return v / (1.f + __expf(-v)); }

__device__ __forceinline__ float b2f(u16 u) {
  union { u32 i; float f; } c; c.i = ((u32)u) << 16; return c.f;
}
__device__ __forceinline__ u16 f2b(float f) {
  union { float f; u32 i; } c; c.f = f;
  u32 r = c.i + 0x7FFFu + ((c.i >> 16) & 1u);
  return (u16)(r >> 16);
}
__device__ __forceinline__ float4 ld4(const float* p) { return *(const float4*)p; }
__device__ __forceinline__ float4 ld4(const u16* p) {
  ushort4 v = *(const ushort4*)p;
  return make_float4(b2f(v.x), b2f(v.y), b2f(v.z), b2f(v.w));
}

// global_load_lds, 16B per lane, wave-uniform LDS base (lane l -> base+l*16B).
__device__ __forceinline__ void gll16(const u16* g, u16* l) {
  __attribute__((address_space(3))) u32* lp =
      reinterpret_cast<__attribute__((address_space(3))) u32*>(
          reinterpret_cast<uintptr_t>(l));
  __builtin_amdgcn_global_load_lds(reinterpret_cast<const u32*>(g), lp, 16, 0, 0);
}

union U8 { uint4 u; bf16x8 b; };

// ---------------- workspace layout (BYTE offsets) ----------------
static constexpr size_t WT1T_B = 0;               // 256x288 bf16
static constexpr size_t WT2T_B = 147456;          // 512x768
static constexpr size_t WT3T_B = 933888;          // 1024x1536
static constexpr size_t HL1T_B = 4079616;         // 1024x1024 -> ends 6176768
static constexpr size_t RA_B   = 6176768;         // 58,720,256 B
static constexpr size_t RB_B   = 64897024;        // 54,525,952 B
static constexpr size_t P_B    = 119422976;
// RA phases:
static constexpr size_t FRH_B  = RA_B;                    // fut_ref hi bf16 20,971,520
static constexpr size_t FRL_B  = RA_B + 20971520;
static constexpr size_t E1H_B  = RA_B + 41943040;         // e1 pair bf16 8,388,608 ea
static constexpr size_t E1L_B  = RA_B + 50331648;
static constexpr size_t E2H_B  = RA_B;                    // e2 pair (fr dead) 8,388,608 ea
static constexpr size_t E2L_B  = RA_B + 8388608;
static constexpr size_t Y1_B   = RA_B;                    // conv1 out (52,428,800)
static constexpr size_t Y3_B   = RA_B;                    // conv3 out bf16 (y1 dead)
static constexpr size_t WGT_B  = RA_B;                    // experts bf16 (y3 dead)
static constexpr size_t WUT_B  = RA_B + 16777216;
static constexpr size_t WDT_B  = RA_B + 33554432;
static constexpr size_t X_B    = RA_B + 50331648;         // x f32 8,388,608
static constexpr size_t SHGT_B = RA_B;                    // after moe_up (wg/wu dead)
static constexpr size_t SHUT_B = RA_B + 2097152;
static constexpr size_t SHDT_B = RA_B + 4194304;
static constexpr size_t O1T_B  = RA_B + 6291456;
static constexpr size_t O2T_B  = RA_B + 7340032;          // ends RA+9,437,184
static constexpr size_t H2_B   = RA_B + 25165824;         // f32 8,388,608
static constexpr size_t H2B_B  = RA_B + 33554432;         // h2 bf16 4,194,304 (wdT dead)
// RB phases:
static constexpr size_t E1TH_B = RB_B;                    // enc1 WT pair 5,242,880 ea
static constexpr size_t E1TL_B = RB_B + 5242880;
static constexpr size_t E2TH_B = RB_B + 10485760;         // enc2 WT pair 2,097,152 ea
static constexpr size_t E2TL_B = RB_B + 12582912;         // ends 14,680,064
static constexpr size_t PENC_B = RB_B + 14680064;         // K-split partials f32 (32MB)
static constexpr size_t HSB_B  = RB_B;                    // hist_seq bf16 (enc dead)
static constexpr size_t Y2_B   = RB_B;                    // conv2 out
static constexpr size_t HB_B   = RB_B;                    // hb bf16 8,388,608 (y2 dead)
static constexpr size_t HI1_B  = RB_B + 8388608;          // hi1b bf16 8,388,608
static constexpr size_t PHL2_B = RB_B + 16777216;         // hlin2 partials f32 4x2MB
static constexpr size_t XCH_B  = RB_B + 16777216;         // concat pair bf16 (after hlin2)
static constexpr size_t XCL_B  = RB_B + 19922944;
static constexpr size_t XH_B   = RB_B;                    // x bf16 4,194,304 (hb dead)
static constexpr size_t TM_B   = RB_B + 8388608;          // t_moe bf16 33,554,432
static constexpr size_t STB_B  = RB_B + 8388608;          // stb bf16 16,777,216 (tm dead)
static constexpr size_t PSH_B  = RB_B + 25165824;         // shdown partials f32 2x8MB
static constexpr size_t O1B_B  = RB_B;                    // o1 bf16 8,388,608 (xh dead)
static constexpr size_t O2H_B  = RB_B + 16777216;         // o2 pair bf16 8,388,608 ea
static constexpr size_t O2L_B  = RB_B + 25165824;
static constexpr size_t PHD_B  = RB_B + 33554432;         // head partials f32 4x2MB
// P smalls:
static constexpr size_t HLAT_B = P_B;
static constexpr size_t E3P_B  = P_B + 1048576;
static constexpr size_t Z_B    = P_B + 3145728;
static constexpr size_t LOG_B  = P_B + 4194304;
static constexpr size_t TID_B  = P_B + 4456448;
static constexpr size_t TW_B   = P_B + 4521984;
static constexpr size_t POS_B  = P_B + 4587520;
static constexpr size_t CNT_B  = P_B + 4653056;
static constexpr size_t OFS_B  = P_B + 4653184;
static constexpr size_t ROWL_B = P_B + 4653312;
static constexpr size_t WL_B   = P_B + 4718848;
static constexpr size_t ZP_B   = P_B + 4784384;           // 4096 B zero page
static constexpr size_t PRJH_B = P_B + 4788480;           // proj WT pair 393,216 ea
static constexpr size_t PRJL_B = P_B + 5181696;
static constexpr size_t E3TH_B = P_B + 5574912;           // enc3 WT pair 262,144 ea
static constexpr size_t E3TL_B = P_B + 5837056;
static constexpr size_t HL2P_B = P_B + 6099200;           // hlin2 padded WT 262,144
static constexpr size_t HDH_B  = P_B + 6361344;           // head padded WT pair 262,144 ea
static constexpr size_t HDL_B  = P_B + 6623488;           // ends P+6,885,632

// XCD-coherent tile decode (128-row m-tiles): m-tiles % 8 == 0.
#define TILE_DECODE(nn_)                         \
  const int bid = blockIdx.x;                    \
  const int xcd = bid & 7;                       \
  const int tt_ = bid >> 3;                      \
  const int n0 = (tt_ % (nn_)) * 128;            \
  const int m0 = ((tt_ / (nn_)) * 8 + xcd) * 128;

// ---------------- prep kernels ----------------
__global__ void k_zero2(int* __restrict__ a, int na, int* __restrict__ b, int nb) {
  int i = blockIdx.x * 256 + threadIdx.x;
  if (i < na) a[i] = 0;
  else if (i < na + nb) b[i - na] = 0;
}
__global__ void k_zero_f4(float4* __restrict__ p, int n4) {
  int i = blockIdx.x * 256 + threadIdx.x;
  if (i < n4) p[i] = make_float4(0.f, 0.f, 0.f, 0.f);
}
__global__ void k_f32_to_bf4(const float* __restrict__ s, u16* __restrict__ d, int n4) {
  int i = blockIdx.x * 256 + threadIdx.x;
  if (i >= n4) return;
  float4 v = *(const float4*)(s + (size_t)i * 4);
  *(ushort4*)(d + (size_t)i * 4) = make_ushort4(f2b(v.x), f2b(v.y), f2b(v.z), f2b(v.w));
}
// f32 -> (hi, lo) bf16 pair
__global__ void k_split_x(const float* __restrict__ s, u16* __restrict__ dh,
                          u16* __restrict__ dl, int n4) {
  int i = blockIdx.x * 256 + threadIdx.x;
  if (i >= n4) return;
  float4 v = *(const float4*)(s + (size_t)i * 4);
  float a[4] = {v.x, v.y, v.z, v.w};
  ushort4 h, l;
  u16* hp = (u16*)&h; u16* lp = (u16*)&l;
#pragma unroll
  for (int j = 0; j < 4; ++j) {
    u16 hh = f2b(a[j]);
    hp[j] = hh;
    lp[j] = f2b(a[j] - b2f(hh));
  }
  *(ushort4*)(dh + (size_t)i * 4) = h;
  *(ushort4*)(dl + (size_t)i * 4) = l;
}
// combine two f32 K-split partials (vectorized, full-width N pow2).
template<int ACT>
__global__ void k_comb2(const float* __restrict__ P0, const float* __restrict__ P1,
                        const float* __restrict__ bias, u16* __restrict__ Ch,
                        u16* __restrict__ Cl, int N, int n4) {
  int i = blockIdx.x * 256 + threadIdx.x;
  if (i >= n4) return;
  float4 a = *(const float4*)(P0 + (size_t)i * 4);
  float4 b = *(const float4*)(P1 + (size_t)i * 4);
  int col = (i * 4) & (N - 1);
  float r[4] = {a.x + b.x, a.y + b.y, a.z + b.z, a.w + b.w};
  ushort4 h, l;
  u16* hp = (u16*)&h; u16* lp = (u16*)&l;
#pragma unroll
  for (int j = 0; j < 4; ++j) {
    float v = r[j] + bias[col + j];
    if (ACT) v = silu_f(v);
    u16 hh = f2b(v);
    hp[j] = hh;
    lp[j] = f2b(v - b2f(hh));
  }
  *(ushort4*)(Ch + (size_t)i * 4) = h;
  *(ushort4*)(Cl + (size_t)i * 4) = l;
}
// generic scalar S-way combine; partial stride Np=2^lgNp; out stride/guard Nout.
// EPI: 0 f32 store, 2 f32 +=.
template<int ACT, int EPI>
__global__ void k_combS(const float* __restrict__ P, const float* __restrict__ bias,
                        float* __restrict__ Cf, int S, int lgNp, int Nout, int total) {
  int idx = blockIdx.x * 256 + threadIdx.x;
  if (idx >= total) return;
  int row = idx >> lgNp;
  int col = idx & ((1 << lgNp) - 1);
  if (col >= Nout) return;
  float s = 0.f;
  for (int si = 0; si < S; ++si) s += P[(size_t)si * total + idx];
  s += bias[col];
  if (ACT) s = silu_f(s);
  if (EPI == 0) Cf[(size_t)row * Nout + col] = s;
  else Cf[(size_t)row * Nout + col] += s;
}
// concat [obs|hlat|z] -> hi/lo bf16 pair [4096][384]
__global__ void k_concat_split(const float* __restrict__ obs,
                               const float* __restrict__ hl,
                               const float* __restrict__ z,
                               u16* __restrict__ dh, u16* __restrict__ dl) {
  int idx = blockIdx.x * 256 + threadIdx.x;
  if (idx >= BATCH * 384) return;
  int b = idx / 384, c = idx - b * 384;
  float v;
  if (c < 256)      v = obs[(size_t)b * 256 + c];
  else if (c < 320) v = hl[(size_t)b * 64 + (c - 256)];
  else              v = z[(size_t)b * 64 + (c - 320)];
  u16 h = f2b(v);
  dh[idx] = h;
  dl[idx] = f2b(v - b2f(h));
}
// fused conv weight prep: [O][I][3] fp32 -> WT[o][k*CIN+i] bf16, all 3 convs.
__global__ void k_wt_conv3(const float* __restrict__ w1, u16* __restrict__ t1,
                           const float* __restrict__ w2, u16* __restrict__ t2,
                           const float* __restrict__ w3, u16* __restrict__ t3) {
  int idx = blockIdx.x * 256 + threadIdx.x;
  const float* w; u16* t; int CIN;
  if (idx < 73728)        { w = w1; t = t1; CIN = 96; }
  else if (idx < 466944)  { idx -= 73728;  w = w2; t = t2; CIN = 256; }
  else if (idx < 2039808) { idx -= 466944; w = w3; t = t3; CIN = 512; }
  else return;
  int Kc = CIN * 3;
  int o = idx / Kc, c = idx - o * Kc;
  int k = c / CIN, i = c - k * CIN;
  t[idx] = f2b(w[(size_t)o * Kc + i * 3 + k]);
}
// dense weight: W[K][N] fp32 -> WT[N][K] bf16
__global__ __launch_bounds__(256) void k_transpose_bf(const float* __restrict__ W,
                                                      u16* __restrict__ WT,
                                                      int K, int N) {
  __shared__ float t[32][33];
  int n0 = blockIdx.x * 32, k0 = blockIdx.y * 32;
  int lx = threadIdx.x & 31, ly = threadIdx.x >> 5;
#pragma unroll
  for (int r = 0; r < 32; r += 8)
    t[ly + r][lx] = W[(size_t)(k0 + ly + r) * N + n0 + lx];
  __syncthreads();
#pragma unroll
  for (int r = 0; r < 32; r += 8)
    WT[(size_t)(n0 + ly + r) * K + k0 + lx] = f2b(t[lx][ly + r]);
}
// padded transpose: W[K][N] -> WT[Npad][K] bf16, rows >= N zero.
__global__ __launch_bounds__(256) void k_transpose_bf_pad(const float* __restrict__ W,
                                                          u16* __restrict__ WT,
                                                          int K, int N) {
  __shared__ float t[32][33];
  int n0 = blockIdx.x * 32, k0 = blockIdx.y * 32;
  int lx = threadIdx.x & 31, ly = threadIdx.x >> 5;
#pragma unroll
  for (int r = 0; r < 32; r += 8)
    t[ly + r][lx] = (n0 + lx < N) ? W[(size_t)(k0 + ly + r) * N + n0 + lx] : 0.f;
  __syncthreads();
#pragma unroll
  for (int r = 0; r < 32; r += 8)
    WT[(size_t)(n0 + ly + r) * K + k0 + lx] = f2b(t[lx][ly + r]);
}
// padded hi/lo transpose
__global__ __launch_bounds__(256) void k_transpose_hilo_pad(const float* __restrict__ W,
                                                            u16* __restrict__ WTh,
                                                            u16* __restrict__ WTl,
                                                            int K, int N) {
  __shared__ float t[32][33];
  int n0 = blockIdx.x * 32, k0 = blockIdx.y * 32;
  int lx = threadIdx.x & 31, ly = threadIdx.x >> 5;
#pragma unroll
  for (int r = 0; r < 32; r += 8)
    t[ly + r][lx] = (n0 + lx < N) ? W[(size_t)(k0 + ly + r) * N + n0 + lx] : 0.f;
  __syncthreads();
#pragma unroll
  for (int r = 0; r < 32; r += 8) {
    float f = t[lx][ly + r];
    u16 h = f2b(f);
    size_t o = (size_t)(n0 + ly + r) * K + k0 + lx;
    WTh[o] = h;
    WTl[o] = f2b(f - b2f(h));
  }
}
// batched per-expert transpose
__global__ __launch_bounds__(256) void k_transpose_bf_b(const float* __restrict__ W,
                                                        u16* __restrict__ WT,
                                                        int K, int N) {
  const size_t eo = (size_t)blockIdx.z * K * N;
  __shared__ float t[32][33];
  int n0 = blockIdx.x * 32, k0 = blockIdx.y * 32;
  int lx = threadIdx.x & 31, ly = threadIdx.x >> 5;
#pragma unroll
  for (int r = 0; r < 32; r += 8)
    t[ly + r][lx] = W[eo + (size_t)(k0 + ly + r) * N + n0 + lx];
  __syncthreads();
#pragma unroll
  for (int r = 0; r < 32; r += 8)
    WT[eo + (size_t)(n0 + ly + r) * K + k0 + lx] = f2b(t[lx][ly + r]);
}
// hi/lo split transpose
__global__ __launch_bounds__(256) void k_transpose_hilo(const float* __restrict__ W,
                                                        u16* __restrict__ WTh,
                                                        u16* __restrict__ WTl,
                                                        int K, int N) {
  __shared__ float t[32][33];
  int n0 = blockIdx.x * 32, k0 = blockIdx.y * 32;
  int lx = threadIdx.x & 31, ly = threadIdx.x >> 5;
#pragma unroll
  for (int r = 0; r < 32; r += 8)
    t[ly + r][lx] = W[(size_t)(k0 + ly + r) * N + n0 + lx];
  __syncthreads();
#pragma unroll
  for (int r = 0; r < 32; r += 8) {
    float f = t[lx][ly + r];
    u16 h = f2b(f);
    size_t o = (size_t)(n0 + ly + r) * K + k0 + lx;
    WTh[o] = h;
    WTl[o] = f2b(f - b2f(h));
  }
}

// ============================================================================
// 128x128 gll GEMM cores: BK=32, 4 waves (2x2 of 64x64).
// LDS per tensor tile: 4096 u16; slot swizzle f(r)=(r>>1)&3.
// ============================================================================
#define PRO128 \
  const int tid = threadIdx.x; \
  const int lane = tid & 63; \
  const int wid = tid >> 6; \
  const int wr = (wid >> 1) * 64, wc = (wid & 1) * 64; \
  const int l15 = lane & 15, lsub = lane >> 4;

#define MFMA_BF16(a, b, c) __builtin_amdgcn_mfma_f32_16x16x32_bf16(a, b, c, 0, 0, 0)

// AP/BP = hi/lo parts of A/B; EPI: 0 f32, 1 bf16, 2 f32 +=, 3 bf16 pair.
template<int ACT, int EPI, int AP, int BP>
__global__ __launch_bounds__(256) void k_gg(
    const u16* __restrict__ A0, const u16* __restrict__ A1,
    const u16* __restrict__ B0, const u16* __restrict__ B1,
    const float* __restrict__ bias,
    float* __restrict__ Cf, u16* __restrict__ Ch, u16* __restrict__ Cl,
    int K, int lda, int ldb, int nn, int Nout) {
  constexpr int NT = AP + BP;
  __shared__ u16 lds[NT * 4096];
  PRO128
  TILE_DECODE(nn)
  const int r0 = wid * 32 + (lane >> 2);
  const int sl = ((lane & 3) ^ ((r0 >> 1) & 3)) * 8;
  const u16* sA0 = A0 + (size_t)(m0 + r0) * lda + sl;
  const u16* sA1 = (AP == 2) ? A1 + (size_t)(m0 + r0) * lda + sl : nullptr;
  const u16* sB0 = B0 + (size_t)(n0 + r0) * ldb + sl;
  const u16* sB1 = (BP == 2) ? B1 + (size_t)(n0 + r0) * ldb + sl : nullptr;
  const size_t stepA = (size_t)16 * lda, stepB = (size_t)16 * ldb;
  const int wb = wid * 1024;

  f32x4 acc[4][4];
  const f32x4 zf = {0.f, 0.f, 0.f, 0.f};
#pragma unroll
  for (int i = 0; i < 4; ++i)
#pragma unroll
    for (int j = 0; j < 4; ++j) acc[i][j] = zf;

  for (int k0 = 0; k0 < K; k0 += 32) {
    {
      int t = 0;
      gll16(sA0 + k0, &lds[t * 4096 + wb]);
      gll16(sA0 + stepA + k0, &lds[t * 4096 + wb + 512]);
      ++t;
      if (AP == 2) {
        gll16(sA1 + k0, &lds[t * 4096 + wb]);
        gll16(sA1 + stepA + k0, &lds[t * 4096 + wb + 512]);
        ++t;
      }
      gll16(sB0 + k0, &lds[t * 4096 + wb]);
      gll16(sB0 + stepB + k0, &lds[t * 4096 + wb + 512]);
      ++t;
      if (BP == 2) {
        gll16(sB1 + k0, &lds[t * 4096 + wb]);
        gll16(sB1 + stepB + k0, &lds[t * 4096 + wb + 512]);
      }
    }
    __syncthreads();
    U8 fah[4], fal[4];
#pragma unroll
    for (int i = 0; i < 4; ++i) {
      int ra = wr + i * 16 + l15;
      int ao = ra * 32 + ((lsub ^ ((ra >> 1) & 3))) * 8;
      fah[i].u = *(const uint4*)&lds[ao];
      if (AP == 2) fal[i].u = *(const uint4*)&lds[4096 + ao];
    }
#pragma unroll
    for (int ni = 0; ni < 4; ++ni) {
      int rb = wc + ni * 16 + l15;
      int bo = AP * 4096 + rb * 32 + ((lsub ^ ((rb >> 1) & 3))) * 8;
      U8 fbh, fbl;
      fbh.u = *(const uint4*)&lds[bo];
      if (BP == 2) fbl.u = *(const uint4*)&lds[4096 + bo];
#pragma unroll
      for (int mi = 0; mi < 4; ++mi) {
        acc[mi][ni] = MFMA_BF16(fah[mi].b, fbh.b, acc[mi][ni]);
        if (BP == 2) acc[mi][ni] = MFMA_BF16(fah[mi].b, fbl.b, acc[mi][ni]);
        if (AP == 2) acc[mi][ni] = MFMA_BF16(fal[mi].b, fbh.b, acc[mi][ni]);
      }
    }
    __syncthreads();
  }
  const int row4 = lsub * 4;
#pragma unroll
  for (int mi = 0; mi < 4; ++mi)
#pragma unroll
    for (int ni = 0; ni < 4; ++ni) {
      int col = n0 + wc + ni * 16 + l15;
      if (col >= Nout) continue;
      float bv = bias[col];
#pragma unroll
      for (int j = 0; j < 4; ++j) {
        int row = m0 + wr + mi * 16 + row4 + j;
        float v = acc[mi][ni][j] + bv;
        if (ACT) v = silu_f(v);
        if (EPI == 0) Cf[(size_t)row * Nout + col] = v;
        else if (EPI == 1) Ch[(size_t)row * Nout + col] = f2b(v);
        else if (EPI == 2) Cf[(size_t)row * Nout + col] += v;
        else {
          u16 vh = f2b(v);
          Ch[(size_t)row * Nout + col] = vh;
          Cl[(size_t)row * Nout + col] = f2b(v - b2f(vh));
        }
      }
    }
}

// generic K-split partial GEMM: grid = base*S; kh = bid/base; writes raw f32
// partials (no bias/act) to P + kh*BATCH*Nt. K arg = Kh (per-split).
template<int AP, int BP>
__global__ __launch_bounds__(256) void k_ggps(
    const u16* __restrict__ A0, const u16* __restrict__ A1,
    const u16* __restrict__ B0, const u16* __restrict__ B1,
    float* __restrict__ P, int Kh, int lda, int ldb, int nn, int Nt, int base) {
  constexpr int NT = AP + BP;
  __shared__ u16 lds[NT * 4096];
  PRO128
  const int bidx = blockIdx.x;
  const int kh = bidx / base;
  const int b2 = bidx - kh * base;
  const int xcd = b2 & 7;
  const int tt_ = b2 >> 3;
  const int n0 = (tt_ % nn) * 128;
  const int m0 = ((tt_ / nn) * 8 + xcd) * 128;
  const int koff = kh * Kh;
  const int r0 = wid * 32 + (lane >> 2);
  const int sl = ((lane & 3) ^ ((r0 >> 1) & 3)) * 8;
  const u16* sA0 = A0 + (size_t)(m0 + r0) * lda + sl + koff;
  const u16* sA1 = (AP == 2) ? A1 + (size_t)(m0 + r0) * lda + sl + koff : nullptr;
  const u16* sB0 = B0 + (size_t)(n0 + r0) * ldb + sl + koff;
  const u16* sB1 = (BP == 2) ? B1 + (size_t)(n0 + r0) * ldb + sl + koff : nullptr;
  const size_t stepA = (size_t)16 * lda, stepB = (size_t)16 * ldb;
  const int wb = wid * 1024;

  f32x4 acc[4][4];
  const f32x4 zf = {0.f, 0.f, 0.f, 0.f};
#pragma unroll
  for (int i = 0; i < 4; ++i)
#pragma unroll
    for (int j = 0; j < 4; ++j) acc[i][j] = zf;

  for (int k0 = 0; k0 < Kh; k0 += 32) {
    {
      int t = 0;
      gll16(sA0 + k0, &lds[t * 4096 + wb]);
      gll16(sA0 + stepA + k0, &lds[t * 4096 + wb + 512]);
      ++t;
      if (AP == 2) {
        gll16(sA1 + k0, &lds[t * 4096 + wb]);
        gll16(sA1 + stepA + k0, &lds[t * 4096 + wb + 512]);
        ++t;
      }
      gll16(sB0 + k0, &lds[t * 4096 + wb]);
      gll16(sB0 + stepB + k0, &lds[t * 4096 + wb + 512]);
      ++t;
      if (BP == 2) {
        gll16(sB1 + k0, &lds[t * 4096 + wb]);
        gll16(sB1 + stepB + k0, &lds[t * 4096 + wb + 512]);
      }
    }
    __syncthreads();
    U8 fah[4], fal[4];
#pragma unroll
    for (int i = 0; i < 4; ++i) {
      int ra = wr + i * 16 + l15;
      int ao = ra * 32 + ((lsub ^ ((ra >> 1) & 3))) * 8;
      fah[i].u = *(const uint4*)&lds[ao];
      if (AP == 2) fal[i].u = *(const uint4*)&lds[4096 + ao];
    }
#pragma unroll
    for (int ni = 0; ni < 4; ++ni) {
      int rb = wc + ni * 16 + l15;
      int bo = AP * 4096 + rb * 32 + ((lsub ^ ((rb >> 1) & 3))) * 8;
      U8 fbh, fbl;
      fbh.u = *(const uint4*)&lds[bo];
      if (BP == 2) fbl.u = *(const uint4*)&lds[4096 + bo];
#pragma unroll
      for (int mi = 0; mi < 4; ++mi) {
        acc[mi][ni] = MFMA_BF16(fah[mi].b, fbh.b, acc[mi][ni]);
        if (BP == 2) acc[mi][ni] = MFMA_BF16(fah[mi].b, fbl.b, acc[mi][ni]);
        if (AP == 2) acc[mi][ni] = MFMA_BF16(fal[mi].b, fbh.b, acc[mi][ni]);
      }
    }
    __syncthreads();
  }
  float* Pk = P + (size_t)kh * ((size_t)BATCH * Nt);
  const int row4 = lsub * 4;
#pragma unroll
  for (int mi = 0; mi < 4; ++mi)
#pragma unroll
    for (int ni = 0; ni < 4; ++ni) {
      int col = n0 + wc + ni * 16 + l15;
#pragma unroll
      for (int j = 0; j < 4; ++j) {
        int row = m0 + wr + mi * 16 + row4 + j;
        Pk[(size_t)row * Nt + col] = acc[mi][ni][j];
      }
    }
}

// BK=64 1-term GEMM (K%64==0): half the barriers. 8-slot swizzle f(r)=r&7.
template<int ACT, int EPI>
__global__ __launch_bounds__(256) void k_gg64(
    const u16* __restrict__ A0, const u16* __restrict__ B0,
    const float* __restrict__ bias,
    float* __restrict__ Cf, u16* __restrict__ Ch, u16* __restrict__ Cl,
    int K, int lda, int ldb, int nn, int Nout) {
  __shared__ u16 lds[2 * 8192];
  PRO128
  TILE_DECODE(nn)
  const int soff = ((lane & 7) ^ (lane >> 3)) * 8;
  const u16* sAb = A0 + (size_t)(m0 + wid * 32 + (lane >> 3)) * lda + soff;
  const u16* sBb = B0 + (size_t)(n0 + wid * 32 + (lane >> 3)) * ldb + soff;
  const int wb = wid * 2048;

  f32x4 acc[4][4];
  const f32x4 zf = {0.f, 0.f, 0.f, 0.f};
#pragma unroll
  for (int i = 0; i < 4; ++i)
#pragma unroll
    for (int j = 0; j < 4; ++j) acc[i][j] = zf;

  for (int k0 = 0; k0 < K; k0 += 64) {
#pragma unroll
    for (int c = 0; c < 4; ++c) {
      gll16(sAb + (size_t)c * 8 * lda + k0, &lds[wb + c * 512]);
      gll16(sBb + (size_t)c * 8 * ldb + k0, &lds[8192 + wb + c * 512]);
    }
    __syncthreads();
#pragma unroll
    for (int h = 0; h < 2; ++h) {
      U8 fa[4], fb[4];
#pragma unroll
      for (int i = 0; i < 4; ++i) {
        int ra = wr + i * 16 + l15;
        fa[i].u = *(const uint4*)&lds[ra * 64 + (((h * 4 + lsub) ^ (ra & 7))) * 8];
        int rb = wc + i * 16 + l15;
        fb[i].u = *(const uint4*)&lds[8192 + rb * 64 + (((h * 4 + lsub) ^ (rb & 7))) * 8];
      }
#pragma unroll
      for (int mi = 0; mi < 4; ++mi)
#pragma unroll
        for (int ni = 0; ni < 4; ++ni)
          acc[mi][ni] = MFMA_BF16(fa[mi].b, fb[ni].b, acc[mi][ni]);
    }
    __syncthreads();
  }
  const int row4 = lsub * 4;
#pragma unroll
  for (int mi = 0; mi < 4; ++mi)
#pragma unroll
    for (int ni = 0; ni < 4; ++ni) {
      int col = n0 + wc + ni * 16 + l15;
      if (col >= Nout) continue;
      float bv = bias[col];
#pragma unroll
      for (int j = 0; j < 4; ++j) {
        int row = m0 + wr + mi * 16 + row4 + j;
        float v = acc[mi][ni][j] + bv;
        if (ACT) v = silu_f(v);
        if (EPI == 0) Cf[(size_t)row * Nout + col] = v;
        else if (EPI == 1) Ch[(size_t)row * Nout + col] = f2b(v);
        else if (EPI == 2) Cf[(size_t)row * Nout + col] += v;
        else {
          u16 vh = f2b(v);
          Ch[(size_t)row * Nout + col] = vh;
          Cl[(size_t)row * Nout + col] = f2b(v - b2f(vh));
        }
      }
    }
}

// shared-expert dual, pure bf16 1-term: C bf16 = silu(A@G+bg)*(A@U+bu)
__global__ __launch_bounds__(256) void k_gdual1(
    const u16* __restrict__ A0, const u16* __restrict__ G0,
    const u16* __restrict__ U0,
    const float* __restrict__ bg, const float* __restrict__ bu,
    u16* __restrict__ C, int N, int K, int lda, int ldb, int nn) {
  __shared__ u16 lds[3 * 4096];
  PRO128
  TILE_DECODE(nn)
  const int r0 = wid * 32 + (lane >> 2);
  const int sl = ((lane & 3) ^ ((r0 >> 1) & 3)) * 8;
  const u16* sA = A0 + (size_t)(m0 + r0) * lda + sl;
  const u16* sG = G0 + (size_t)(n0 + r0) * ldb + sl;
  const u16* sU = U0 + (size_t)(n0 + r0) * ldb + sl;
  const size_t stepA = (size_t)16 * lda, stepB = (size_t)16 * ldb;
  const int wb = wid * 1024;
  f32x4 ag[4][4], au[4][4];
  const f32x4 zf = {0.f, 0.f, 0.f, 0.f};
#pragma unroll
  for (int i = 0; i < 4; ++i)
#pragma unroll
    for (int j = 0; j < 4; ++j) { ag[i][j] = zf; au[i][j] = zf; }

  for (int k0 = 0; k0 < K; k0 += 32) {
    gll16(sA + k0, &lds[wb]);
    gll16(sA + stepA + k0, &lds[wb + 512]);
    gll16(sG + k0, &lds[4096 + wb]);
    gll16(sG + stepB + k0, &lds[4096 + wb + 512]);
    gll16(sU + k0, &lds[2 * 4096 + wb]);
    gll16(sU + stepB + k0, &lds[2 * 4096 + wb + 512]);
    __syncthreads();
    U8 fa[4];
#pragma unroll
    for (int i = 0; i < 4; ++i) {
      int ra = wr + i * 16 + l15;
      fa[i].u = *(const uint4*)&lds[ra * 32 + ((lsub ^ ((ra >> 1) & 3))) * 8];
    }
#pragma unroll
    for (int ni = 0; ni < 4; ++ni) {
      int rb = wc + ni * 16 + l15;
      int bo = rb * 32 + ((lsub ^ ((rb >> 1) & 3))) * 8;
      U8 fg, fu;
      fg.u = *(const uint4*)&lds[4096 + bo];
      fu.u = *(const uint4*)&lds[2 * 4096 + bo];
#pragma unroll
      for (int mi = 0; mi < 4; ++mi) {
        ag[mi][ni] = MFMA_BF16(fa[mi].b, fg.b, ag[mi][ni]);
        au[mi][ni] = MFMA_BF16(fa[mi].b, fu.b, au[mi][ni]);
      }
    }
    __syncthreads();
  }
  const int row4 = lsub * 4;
#pragma unroll
  for (int mi = 0; mi < 4; ++mi)
#pragma unroll
    for (int ni = 0; ni < 4; ++ni) {
      int col = n0 + wc + ni * 16 + l15;
      float bgv = bg[col], buv = bu[col];
#pragma unroll
      for (int j = 0; j < 4; ++j) {
        int row = m0 + wr + mi * 16 + row4 + j;
        float v = silu_f(ag[mi][ni][j] + bgv) * (au[mi][ni][j] + buv);
        C[(size_t)row * N + col] = f2b(v);
      }
    }
}

// conv as implicit-im2col gll GEMM, BK=32 (conv1).
template<int CIN, int TIN, int TOUT, int STRIDE>
__global__ __launch_bounds__(256) void k_gconv32(
    const u16* __restrict__ X, const u16* __restrict__ WT,
    const float* __restrict__ bias, u16* __restrict__ Y,
    const u16* __restrict__ zp, int COUT, int nn) {
  constexpr int K = CIN * 3;
  __shared__ u16 lds[2 * 4096];
  PRO128
  TILE_DECODE(nn)
  int bA_[2], tb_[2], sl_[2];
  const u16* sB[2];
#pragma unroll
  for (int i = 0; i < 2; ++i) {
    int r = wid * 32 + i * 16 + (lane >> 2);
    int sl = ((lane & 3) ^ ((r >> 1) & 3)) * 8;
    sl_[i] = sl;
    int m = m0 + r;
    int bb = m / TOUT;
    int tt = m - bb * TOUT;
    bA_[i] = bb;
    tb_[i] = tt * STRIDE - 1;
    sB[i] = WT + (size_t)(n0 + r) * K + sl;
  }
  const int wb = wid * 1024;
  f32x4 acc[4][4];
  const f32x4 zf = {0.f, 0.f, 0.f, 0.f};
#pragma unroll
  for (int i = 0; i < 4; ++i)
#pragma unroll
    for (int j = 0; j < 4; ++j) acc[i][j] = zf;

  for (int k0 = 0; k0 < K; k0 += 32) {
#pragma unroll
    for (int i = 0; i < 2; ++i) {
      int kk = k0 + sl_[i];
      int ker = kk / CIN;
      int i0 = kk - ker * CIN;
      int tin = tb_[i] + ker;
      const u16* sa = (tin >= 0 && tin < TIN)
          ? X + ((size_t)bA_[i] * TIN + tin) * CIN + i0 : zp;
      gll16(sa, &lds[wb + i * 512]);
      gll16(sB[i] + k0, &lds[4096 + wb + i * 512]);
    }
    __syncthreads();
    U8 fa[4], fb[4];
#pragma unroll
    for (int i = 0; i < 4; ++i) {
      int ra = wr + i * 16 + l15;
      fa[i].u = *(const uint4*)&lds[ra * 32 + ((lsub ^ ((ra >> 1) & 3))) * 8];
      int rb = wc + i * 16 + l15;
      fb[i].u = *(const uint4*)&lds[4096 + rb * 32 + ((lsub ^ ((rb >> 1) & 3))) * 8];
    }
#pragma unroll
    for (int mi = 0; mi < 4; ++mi)
#pragma unroll
      for (int ni = 0; ni < 4; ++ni)
        acc[mi][ni] = MFMA_BF16(fa[mi].b, fb[ni].b, acc[mi][ni]);
    __syncthreads();
  }
  const int row4 = lsub * 4;
#pragma unroll
  for (int mi = 0; mi < 4; ++mi)
#pragma unroll
    for (int ni = 0; ni < 4; ++ni) {
      int col = n0 + wc + ni * 16 + l15;
      float bv = bias[col];
#pragma unroll
      for (int j = 0; j < 4; ++j) {
        int row = m0 + wr + mi * 16 + row4 + j;
        Y[(size_t)row * COUT + col] = f2b(silu_f(acc[mi][ni][j] + bv));
      }
    }
}

// conv as implicit-im2col gll GEMM, BK=64, bf16 output (conv2/conv3).
template<int CIN, int TIN, int TOUT, int STRIDE>
__global__ __launch_bounds__(256) void k_gconv64(
    const u16* __restrict__ X, const u16* __restrict__ WT,
    const float* __restrict__ bias, u16* __restrict__ Y,
    const u16* __restrict__ zp, int COUT, int nn) {
  constexpr int K = CIN * 3;
  __shared__ u16 lds[2 * 8192];
  PRO128
  TILE_DECODE(nn)
  const int soff = ((lane & 7) ^ (lane >> 3)) * 8;
  int bA_[4], tb_[4];
#pragma unroll
  for (int c = 0; c < 4; ++c) {
    int m = m0 + wid * 32 + c * 8 + (lane >> 3);
    int bb = m / TOUT;
    int tt = m - bb * TOUT;
    bA_[c] = bb;
    tb_[c] = tt * STRIDE - 1;
  }
  const u16* sBb = WT + (size_t)(n0 + wid * 32 + (lane >> 3)) * K + soff;
  const int wb = wid * 2048;

  f32x4 acc[4][4];
  const f32x4 zf = {0.f, 0.f, 0.f, 0.f};
#pragma unroll
  for (int i = 0; i < 4; ++i)
#pragma unroll
    for (int j = 0; j < 4; ++j) acc[i][j] = zf;

  for (int k0 = 0; k0 < K; k0 += 64) {
    int kk = k0 + soff;
    int ker = kk / CIN;
    int i0 = kk - ker * CIN;
#pragma unroll
    for (int c = 0; c < 4; ++c) {
      int tin = tb_[c] + ker;
      const u16* sa = (tin >= 0 && tin < TIN)
          ? X + ((size_t)bA_[c] * TIN + tin) * CIN + i0 : zp;
      gll16(sa, &lds[wb + c * 512]);
      gll16(sBb + (size_t)c * 8 * K + k0, &lds[8192 + wb + c * 512]);
    }
    __syncthreads();
#pragma unroll
    for (int h = 0; h < 2; ++h) {
      U8 fa[4], fb[4];
#pragma unroll
      for (int i = 0; i < 4; ++i) {
        int ra = wr + i * 16 + l15;
        fa[i].u = *(const uint4*)&lds[ra * 64 + (((h * 4 + lsub) ^ (ra & 7))) * 8];
        int rb = wc + i * 16 + l15;
        fb[i].u = *(const uint4*)&lds[8192 + rb * 64 + (((h * 4 + lsub) ^ (rb & 7))) * 8];
      }
#pragma unroll
      for (int mi = 0; mi < 4; ++mi)
#pragma unroll
        for (int ni = 0; ni < 4; ++ni)
          acc[mi][ni] = MFMA_BF16(fa[mi].b, fb[ni].b, acc[mi][ni]);
    }
    __syncthreads();
  }
  const int row4 = lsub * 4;
#pragma unroll
  for (int mi = 0; mi < 4; ++mi)
#pragma unroll
    for (int ni = 0; ni < 4; ++ni) {
      int col = n0 + wc + ni * 16 + l15;
      float bv = bias[col];
#pragma unroll
      for (int j = 0; j < 4; ++j) {
        int row = m0 + wr + mi * 16 + row4 + j;
        Y[(size_t)row * COUT + col] = f2b(silu_f(acc[mi][ni][j] + bv));
      }
    }
}

// MoE up: expert->XCD swizzled 1D grid; gathered bf16 (1-term) dual.
__global__ __launch_bounds__(256) void k_gmoeup(
    const u16* __restrict__ xh,
    const u16* __restrict__ WgT, const u16* __restrict__ WuT,
    const float* __restrict__ bg, const float* __restrict__ bu,
    const int* __restrict__ rowlist, const int* __restrict__ counts,
    const int* __restrict__ offs, const u16* __restrict__ zp,
    u16* __restrict__ t_moe) {
  const int bid = blockIdx.x;
  const int xcd = bid & 7, sidx = bid >> 3;
  const int eo = sidx >> 8, r2 = sidx & 255;
  const int mt = r2 >> 3, nt = r2 & 7;
  const int e = xcd + 8 * eo;
  const int ne = counts[e];
  const int m0 = mt * 128;
  if (m0 >= ne) return;
  const int n0 = nt * 128;
  const int base = offs[e];
  constexpr int K = 512, N = 1024;
  const u16* Wge = WgT + (size_t)e * N * K;
  const u16* Wue = WuT + (size_t)e * N * K;
  const float* bge = bg + (size_t)e * N;
  const float* bue = bu + (size_t)e * N;
  __shared__ u16 lds[3 * 4096];
  PRO128
  const u16* sA[2]; const u16* sG[2]; const u16* sU[2];
#pragma unroll
  for (int i = 0; i < 2; ++i) {
    int r = wid * 32 + i * 16 + (lane >> 2);
    int sl = ((lane & 3) ^ ((r >> 1) & 3)) * 8;
    int grow = m0 + r;
    int xr = (grow < ne) ? rowlist[base + grow] : -1;
    sA[i] = (xr >= 0) ? xh + (size_t)xr * K + sl : zp;
    sG[i] = Wge + (size_t)(n0 + r) * K + sl;
    sU[i] = Wue + (size_t)(n0 + r) * K + sl;
  }
  const int wb = wid * 1024;
  f32x4 ag[4][4], au[4][4];
  const f32x4 zf = {0.f, 0.f, 0.f, 0.f};
#pragma unroll
  for (int i = 0; i < 4; ++i)
#pragma unroll
    for (int j = 0; j < 4; ++j) { ag[i][j] = zf; au[i][j] = zf; }

  for (int k0 = 0; k0 < K; k0 += 32) {
#pragma unroll
    for (int i = 0; i < 2; ++i) {
      gll16(sA[i] + k0, &lds[0 * 4096 + wb + i * 512]);
      gll16(sG[i] + k0, &lds[1 * 4096 + wb + i * 512]);
      gll16(sU[i] + k0, &lds[2 * 4096 + wb + i * 512]);
    }
    __syncthreads();
    U8 fa[4];
#pragma unroll
    for (int i = 0; i < 4; ++i) {
      int ra = wr + i * 16 + l15;
      fa[i].u = *(const uint4*)&lds[ra * 32 + ((lsub ^ ((ra >> 1) & 3))) * 8];
    }
#pragma unroll
    for (int ni = 0; ni < 4; ++ni) {
      int rb = wc + ni * 16 + l15;
      int bo = rb * 32 + ((lsub ^ ((rb >> 1) & 3))) * 8;
      U8 fg, fu;
      fg.u = *(const uint4*)&lds[1 * 4096 + bo];
      fu.u = *(const uint4*)&lds[2 * 4096 + bo];
#pragma unroll
      for (int mi = 0; mi < 4; ++mi) {
        ag[mi][ni] = MFMA_BF16(fa[mi].b, fg.b, ag[mi][ni]);
        au[mi][ni] = MFMA_BF16(fa[mi].b, fu.b, au[mi][ni]);
      }
    }
    __syncthreads();
  }
  const int row4 = lsub * 4;
#pragma unroll
  for (int mi = 0; mi < 4; ++mi)
#pragma unroll
    for (int ni = 0; ni < 4; ++ni) {
      int col = n0 + wc + ni * 16 + l15;
      float bgv = bge[col], buv = bue[col];
#pragma unroll
      for (int j = 0; j < 4; ++j) {
        int row = m0 + wr + mi * 16 + row4 + j;
        if (row >= ne) continue;
        float v = silu_f(ag[mi][ni][j] + bgv) * (au[mi][ni][j] + buv);
        t_moe[(size_t)(base + row) * N + col] = f2b(v);
      }
    }
}

// MoE down, BK=64: t_moe x WdT -> weighted atomic scatter into h2.
__global__ __launch_bounds__(256) void k_gmoedown64(
    const u16* __restrict__ t_moe, const u16* __restrict__ WdT,
    const float* __restrict__ bd, const int* __restrict__ rowlist,
    const float* __restrict__ wlist, const int* __restrict__ counts,
    const int* __restrict__ offs, const u16* __restrict__ zp,
    float* __restrict__ h2) {
  const int bid = blockIdx.x;
  const int xcd = bid & 7, sidx = bid >> 3;
  const int eo = sidx >> 7, r2 = sidx & 127;
  const int mt = r2 >> 2, nt = r2 & 3;
  const int e = xcd + 8 * eo;
  const int ne = counts[e];
  const int m0 = mt * 128;
  if (m0 >= ne) return;
  const int n0 = nt * 128;
  const int base = offs[e];
  constexpr int K = 1024, N = 512;
  const u16* Wde = WdT + (size_t)e * N * K;
  const float* bde = bd + (size_t)e * N;
  __shared__ u16 lds[2 * 8192];
  PRO128
  const int soff = ((lane & 7) ^ (lane >> 3)) * 8;
  const u16* sA[4];
#pragma unroll
  for (int c = 0; c < 4; ++c) {
    int grow = m0 + wid * 32 + c * 8 + (lane >> 3);
    sA[c] = (grow < ne) ? t_moe + (size_t)(base + grow) * K + soff : zp;
  }
  const u16* sBb = Wde + (size_t)(n0 + wid * 32 + (lane >> 3)) * K + soff;
  const int wb = wid * 2048;

  f32x4 acc[4][4];
  const f32x4 zf = {0.f, 0.f, 0.f, 0.f};
#pragma unroll
  for (int i = 0; i < 4; ++i)
#pragma unroll
    for (int j = 0; j < 4; ++j) acc[i][j] = zf;

  for (int k0 = 0; k0 < K; k0 += 64) {
#pragma unroll
    for (int c = 0; c < 4; ++c) {
      gll16(sA[c] + k0, &lds[wb + c * 512]);
      gll16(sBb + (size_t)c * 8 * K + k0, &lds[8192 + wb + c * 512]);
    }
    __syncthreads();
#pragma unroll
    for (int h = 0; h < 2; ++h) {
      U8 fa[4], fb[4];
#pragma unroll
      for (int i = 0; i < 4; ++i) {
        int ra = wr + i * 16 + l15;
        fa[i].u = *(const uint4*)&lds[ra * 64 + (((h * 4 + lsub) ^ (ra & 7))) * 8];
        int rb = wc + i * 16 + l15;
        fb[i].u = *(const uint4*)&lds[8192 + rb * 64 + (((h * 4 + lsub) ^ (rb & 7))) * 8];
      }
#pragma unroll
      for (int mi = 0; mi < 4; ++mi)
#pragma unroll
        for (int ni = 0; ni < 4; ++ni)
          acc[mi][ni] = MFMA_BF16(fa[mi].b, fb[ni].b, acc[mi][ni]);
    }
    __syncthreads();
  }
  const int row4 = lsub * 4;
#pragma unroll
  for (int mi = 0; mi < 4; ++mi)
#pragma unroll
    for (int j = 0; j < 4; ++j) {
      int row = m0 + wr + mi * 16 + row4 + j;
      if (row >= ne) continue;
      int r = rowlist[base + row];
      float wl = wlist[base + row];
#pragma unroll
      for (int ni = 0; ni < 4; ++ni) {
        int col = n0 + wc + ni * 16 + l15;
        atomicAdd(&h2[(size_t)r * 512 + col], wl * (acc[mi][ni][j] + bde[col]));
      }
    }
}

// ---------------- fp32 64x64 GEMM (router only) ----------------
template<int ACT, bool NG, typename TA>
__global__ __launch_bounds__(256) void k_gemm(const TA* __restrict__ A,
                                              const float* __restrict__ W,
                                              const float* __restrict__ bias,
                                              float* __restrict__ C,
                                              int N, int K) {
  __shared__ float As[16][64];
  __shared__ float Bs[16][64];
  const int tid = threadIdx.x;
  const int m0 = blockIdx.x * 64;
  const int n0 = blockIdx.y * 64;
  const int tr = tid >> 4, tc = tid & 15;
  const int lm = tid >> 2, lk = (tid & 3) * 4;
  const int ln = tid & 63, lkb = (tid >> 6) * 4;
  float acc[4][4] = {};
  for (int k0 = 0; k0 < K; k0 += 16) {
    float4 av = ld4(A + (size_t)(m0 + lm) * K + k0 + lk);
    As[lk + 0][lm] = av.x; As[lk + 1][lm] = av.y;
    As[lk + 2][lm] = av.z; As[lk + 3][lm] = av.w;
#pragma unroll
    for (int s = 0; s < 4; ++s) {
      int kk = lkb + s;
      float v = 0.f;
      if (!NG || (n0 + ln) < N) v = W[(size_t)(k0 + kk) * N + n0 + ln];
      Bs[kk][ln] = v;
    }
    __syncthreads();
#pragma unroll
    for (int kk = 0; kk < 16; ++kk) {
      float4 a4 = *(const float4*)&As[kk][tr * 4];
      float4 b4 = *(const float4*)&Bs[kk][tc * 4];
      float a[4] = {a4.x, a4.y, a4.z, a4.w};
      float b[4] = {b4.x, b4.y, b4.z, b4.w};
#pragma unroll
      for (int i = 0; i < 4; ++i)
#pragma unroll
        for (int j = 0; j < 4; ++j) acc[i][j] = fmaf(a[i], b[j], acc[i][j]);
    }
    __syncthreads();
  }
#pragma unroll
  for (int i = 0; i < 4; ++i) {
    int m = m0 + tr * 4 + i;
#pragma unroll
    for (int j = 0; j < 4; ++j) {
      int n = n0 + tc * 4 + j;
      if (NG && n >= N) continue;
      float v = acc[i][j] + bias[n];
      if (ACT == 1) v = silu_f(v);
      C[(size_t)m * N + n] = v;
    }
  }
}

// ---------------- small elementwise / router kernels ----------------
__global__ void k_mean7(const u16* __restrict__ y3, u16* __restrict__ hb) {
  int idx = blockIdx.x * 256 + threadIdx.x;
  if (idx >= BATCH * 1024) return;
  int b = idx >> 10, o = idx & 1023;
  const u16* p = y3 + (size_t)b * 7 * 1024 + o;
  float s = 0.f;
#pragma unroll
  for (int t = 0; t < 7; ++t) s += b2f(p[(size_t)t * 1024]);
  hb[idx] = f2b(s * (1.f / 7.f));
}

__global__ void k_z(const float* __restrict__ e3, const float* __restrict__ noise,
                    float* __restrict__ z) {
  int idx = blockIdx.x * 256 + threadIdx.x;
  if (idx >= BATCH * 64) return;
  int b = idx >> 6, j = idx & 63;
  float mu = e3[(size_t)b * 128 + j];
  float lv = e3[(size_t)b * 128 + 64 + j];
  z[idx] = mu + expf(0.5f * lv) * noise[idx];
}

__global__ void k_router(const float* __restrict__ logits, int* __restrict__ tidA,
                         float* __restrict__ twA, int* __restrict__ posA,
                         int* __restrict__ counts) {
  int b = blockIdx.x * 256 + threadIdx.x;
  if (b >= BATCH) return;
  float s[16];
#pragma unroll
  for (int e = 0; e < 16; ++e)
    s[e] = 1.f / (1.f + expf(-logits[(size_t)b * 16 + e]));
  float gsc[4];
#pragma unroll
  for (int g = 0; g < 4; ++g) {
    float m1 = -1e30f; int i1 = -1;
    for (int i = 0; i < 4; ++i) { float v = s[g * 4 + i]; if (v > m1) { m1 = v; i1 = i; } }
    float m2 = -1e30f;
    for (int i = 0; i < 4; ++i) { if (i == i1) continue; float v = s[g * 4 + i]; if (v > m2) m2 = v; }
    gsc[g] = m1 + m2;
  }
  int g1 = 0; float b1 = gsc[0];
  for (int g = 1; g < 4; ++g) if (gsc[g] > b1) { b1 = gsc[g]; g1 = g; }
  int g2 = -1; float b2 = -1e30f;
  for (int g = 0; g < 4; ++g) { if (g == g1) continue; if (gsc[g] > b2) { b2 = gsc[g]; g2 = g; } }
  float ms[16]; bool used[16];
#pragma unroll
  for (int e = 0; e < 16; ++e) {
    int g = e >> 2;
    ms[e] = (g == g1 || g == g2) ? s[e] : 0.f;
    used[e] = false;
  }
  int te[4]; float tv[4]; float tsum = 0.f;
  for (int t = 0; t < 4; ++t) {
    float best = -1.f; int bi = 0;
    for (int e = 0; e < 16; ++e)
      if (!used[e] && ms[e] > best) { best = ms[e]; bi = e; }
    used[bi] = true;
    te[t] = bi;
    tv[t] = s[bi];
    tsum += s[bi];
  }
  float inv = 1.f / (tsum + 1e-20f);
  for (int t = 0; t < 4; ++t) {
    int e = te[t];
    tidA[b * 4 + t] = e;
    twA[b * 4 + t] = tv[t] * inv;  // ROUTE_SCALE = 1.0
    posA[b * 4 + t] = atomicAdd(&counts[e], 1);
  }
}

__global__ void k_offsets(const int* __restrict__ counts, int* __restrict__ offs) {
  if (threadIdx.x == 0 && blockIdx.x == 0) {
    int a = 0;
    for (int e = 0; e < 16; ++e) { offs[e] = a; a += counts[e]; }
    offs[16] = a;
  }
}

__global__ void k_build(const int* __restrict__ tidA, const float* __restrict__ twA,
                        const int* __restrict__ posA, const int* __restrict__ offs,
                        int* __restrict__ rowlist, float* __restrict__ wlist) {
  int idx = blockIdx.x * 256 + threadIdx.x;
  if (idx >= BATCH * 4) return;
  int e = tidA[idx];
  int p = offs[e] + posA[idx];
  rowlist[p] = idx >> 2;
  wlist[p] = twA[idx];
}

// ============================================================================
extern "C" void kernel_launch(void* const* d_in, const int* in_sizes, int n_in,
                              void* d_out, int out_size, void* d_ws, size_t ws_size,
                              hipStream_t stream) {
  const float* cur_obs  = (const float*)d_in[0];
  const float* hist_seq = (const float*)d_in[1];
  const float* fut_ref  = (const float*)d_in[2];
  const float* noise    = (const float*)d_in[3];
  const float* conv1_w  = (const float*)d_in[4];
  const float* conv1_b  = (const float*)d_in[5];
  const float* conv2_w  = (const float*)d_in[6];
  const float* conv2_b  = (const float*)d_in[7];
  const float* conv3_w  = (const float*)d_in[8];
  const float* conv3_b  = (const float*)d_in[9];
  const float* hlin1_w  = (const float*)d_in[10];
  const float* hlin1_b  = (const float*)d_in[11];
  const float* hlin2_w  = (const float*)d_in[12];
  const float* hlin2_b  = (const float*)d_in[13];
  const float* enc1_w   = (const float*)d_in[14];
  const float* enc1_b   = (const float*)d_in[15];
  const float* enc2_w   = (const float*)d_in[16];
  const float* enc2_b   = (const float*)d_in[17];
  const float* enc3_w   = (const float*)d_in[18];
  const float* enc3_b   = (const float*)d_in[19];
  const float* proj_w   = (const float*)d_in[20];
  const float* proj_b   = (const float*)d_in[21];
  const float* router_w = (const float*)d_in[22];
  const float* router_b = (const float*)d_in[23];
  const float* Wg       = (const float*)d_in[24];
  const float* bg       = (const float*)d_in[25];
  const float* Wu       = (const float*)d_in[26];
  const float* bu       = (const float*)d_in[27];
  const float* Wd       = (const float*)d_in[28];
  const float* bd       = (const float*)d_in[29];
  const float* shg_w    = (const float*)d_in[30];
  const float* shg_b    = (const float*)d_in[31];
  const float* shu_w    = (const float*)d_in[32];
  const float* shu_b    = (const float*)d_in[33];
  const float* shd_w    = (const float*)d_in[34];
  const float* shd_b    = (const float*)d_in[35];
  const float* out1_w   = (const float*)d_in[36];
  const float* out1_b   = (const float*)d_in[37];
  const float* out2_w   = (const float*)d_in[38];
  const float* out2_b   = (const float*)d_in[39];
  const float* head_w   = (const float*)d_in[40];
  const float* head_b   = (const float*)d_in[41];
  (void)in_sizes; (void)n_in; (void)out_size; (void)ws_size;

  char* wsb = (char*)d_ws;
  u16* wt1T  = (u16*)(wsb + WT1T_B);
  u16* wt2T  = (u16*)(wsb + WT2T_B);
  u16* wt3T  = (u16*)(wsb + WT3T_B);
  u16* hl1T  = (u16*)(wsb + HL1T_B);
  u16* frh   = (u16*)(wsb + FRH_B);
  u16* frl   = (u16*)(wsb + FRL_B);
  u16* e1h   = (u16*)(wsb + E1H_B);
  u16* e1l   = (u16*)(wsb + E1L_B);
  u16* e2h   = (u16*)(wsb + E2H_B);
  u16* e2l   = (u16*)(wsb + E2L_B);
  u16* y1b   = (u16*)(wsb + Y1_B);
  u16* y2b   = (u16*)(wsb + Y2_B);
  u16* y3b   = (u16*)(wsb + Y3_B);
  u16* wgT   = (u16*)(wsb + WGT_B);
  u16* wuT   = (u16*)(wsb + WUT_B);
  u16* wdT   = (u16*)(wsb + WDT_B);
  float* x   = (float*)(wsb + X_B);
  u16* shgT  = (u16*)(wsb + SHGT_B);
  u16* shuT  = (u16*)(wsb + SHUT_B);
  u16* shdT  = (u16*)(wsb + SHDT_B);
  u16* o1T   = (u16*)(wsb + O1T_B);
  u16* o2T   = (u16*)(wsb + O2T_B);
  float* h2  = (float*)(wsb + H2_B);
  u16* h2b   = (u16*)(wsb + H2B_B);
  u16* e1Th  = (u16*)(wsb + E1TH_B);
  u16* e1Tl  = (u16*)(wsb + E1TL_B);
  u16* e2Th  = (u16*)(wsb + E2TH_B);
  u16* e2Tl  = (u16*)(wsb + E2TL_B);
  float* Penc = (float*)(wsb + PENC_B);
  float* Phl2 = (float*)(wsb + PHL2_B);
  float* Psh  = (float*)(wsb + PSH_B);
  float* Phd  = (float*)(wsb + PHD_B);
  u16* hsb   = (u16*)(wsb + HSB_B);
  u16* hb    = (u16*)(wsb + HB_B);
  u16* hi1b  = (u16*)(wsb + HI1_B);
  u16* xch   = (u16*)(wsb + XCH_B);
  u16* xcl   = (u16*)(wsb + XCL_B);
  u16* xh    = (u16*)(wsb + XH_B);
  u16* tmoeb = (u16*)(wsb + TM_B);
  u16* stb   = (u16*)(wsb + STB_B);
  u16* o1b   = (u16*)(wsb + O1B_B);
  u16* o2h   = (u16*)(wsb + O2H_B);
  u16* o2l   = (u16*)(wsb + O2L_B);
  float* hlat = (float*)(wsb + HLAT_B);
  float* e3   = (float*)(wsb + E3P_B);
  float* z    = (float*)(wsb + Z_B);
  float* logitsb = (float*)(wsb + LOG_B);
  int*   tidA  = (int*)(wsb + TID_B);
  float* twA   = (float*)(wsb + TW_B);
  int*   posA  = (int*)(wsb + POS_B);
  int*   counts = (int*)(wsb + CNT_B);
  int*   offs  = (int*)(wsb + OFS_B);
  int*   rowlist = (int*)(wsb + ROWL_B);
  float* wlist = (float*)(wsb + WL_B);
  u16*   zp    = (u16*)(wsb + ZP_B);
  u16* prjTh = (u16*)(wsb + PRJH_B);
  u16* prjTl = (u16*)(wsb + PRJL_B);
  u16* e3Th  = (u16*)(wsb + E3TH_B);
  u16* e3Tl  = (u16*)(wsb + E3TL_B);
  u16* hl2P  = (u16*)(wsb + HL2P_B);
  u16* hdTh  = (u16*)(wsb + HDH_B);
  u16* hdTl  = (u16*)(wsb + HDL_B);

  k_zero2<<<dim3(5), 256, 0, stream>>>(counts, 16, (int*)zp, 1024);

  // ---- weight prep ----
  k_wt_conv3<<<dim3(7968), 256, 0, stream>>>(conv1_w, wt1T, conv2_w, wt2T, conv3_w, wt3T);
  k_transpose_bf<<<dim3(32, 32), 256, 0, stream>>>(hlin1_w, hl1T, 1024, 1024);
  k_transpose_hilo<<<dim3(32, 80), 256, 0, stream>>>(enc1_w, e1Th, e1Tl, 2560, 1024);
  k_transpose_hilo<<<dim3(32, 32), 256, 0, stream>>>(enc2_w, e2Th, e2Tl, 1024, 1024);
  k_transpose_hilo<<<dim3(4, 32), 256, 0, stream>>>(enc3_w, e3Th, e3Tl, 1024, 128);
  k_transpose_hilo<<<dim3(16, 12), 256, 0, stream>>>(proj_w, prjTh, prjTl, 384, 512);
  k_transpose_bf_pad<<<dim3(4, 32), 256, 0, stream>>>(hlin2_w, hl2P, 1024, 64);
  k_transpose_hilo_pad<<<dim3(4, 32), 256, 0, stream>>>(head_w, hdTh, hdTl, 1024, 23);

  // ---- VAE encoder (hi/lo 3-term, K-split) + reparameterize ----
  k_split_x<<<dim3(10240), 256, 0, stream>>>(fut_ref, frh, frl, BATCH * 2560 / 4);
  k_ggps<2, 2><<<dim3(512), 256, 0, stream>>>(frh, frl, e1Th, e1Tl, Penc,
                                              1280, 2560, 2560, 8, 1024, 256);
  k_comb2<1><<<dim3(4096), 256, 0, stream>>>(Penc, Penc + (size_t)BATCH * 1024,
                                             enc1_b, e1h, e1l, 1024, BATCH * 1024 / 4);
  k_ggps<2, 2><<<dim3(512), 256, 0, stream>>>(e1h, e1l, e2Th, e2Tl, Penc,
                                              512, 1024, 1024, 8, 1024, 256);
  k_comb2<1><<<dim3(4096), 256, 0, stream>>>(Penc, Penc + (size_t)BATCH * 1024,
                                             enc2_b, e2h, e2l, 1024, BATCH * 1024 / 4);
  // enc3: K-split x4 (32 -> 128 blocks)
  k_ggps<2, 2><<<dim3(128), 256, 0, stream>>>(e2h, e2l, e3Th, e3Tl, Penc,
                                              256, 1024, 1024, 1, 128, 32);
  k_combS<0, 0><<<dim3(2048), 256, 0, stream>>>(Penc, enc3_b, e3, 4, 7, 128, BATCH * 128);
  k_z<<<dim3(1024), 256, 0, stream>>>(e3, noise, z);

  // ---- history conv encoder ----
  k_f32_to_bf4<<<dim3(9600), 256, 0, stream>>>(hist_seq, hsb, BATCH * 25 * 96 / 4);
  k_gconv32<96, 25, 25, 1><<<dim3(1600), 256, 0, stream>>>(hsb, wt1T, conv1_b, y1b, zp, 256, 2);
  k_gconv64<256, 25, 13, 2><<<dim3(1664), 256, 0, stream>>>(y1b, wt2T, conv2_b, y2b, zp, 512, 4);
  k_gconv64<512, 13, 7, 2><<<dim3(1792), 256, 0, stream>>>(y2b, wt3T, conv3_b, y3b, zp, 1024, 8);
  k_mean7<<<dim3(16384), 256, 0, stream>>>(y3b, hb);
  k_gg64<1, 1><<<dim3(256), 256, 0, stream>>>(hb, hl1T, hlin1_b,
      nullptr, hi1b, nullptr, 1024, 1024, 1024, 8, 1024);
  // hlin2: K-split x4 (32 -> 128 blocks)
  k_ggps<1, 1><<<dim3(128), 256, 0, stream>>>(hi1b, nullptr, hl2P, nullptr, Phl2,
                                              256, 1024, 1024, 1, 128, 32);
  k_combS<0, 0><<<dim3(2048), 256, 0, stream>>>(Phl2, hlin2_b, hlat, 4, 7, 64, BATCH * 128);

  // ---- expert weight transposes (y3 dead) ----
  k_transpose_bf_b<<<dim3(32, 16, 16), 256, 0, stream>>>(Wg, wgT, 512, 1024);
  k_transpose_bf_b<<<dim3(32, 16, 16), 256, 0, stream>>>(Wu, wuT, 512, 1024);
  k_transpose_bf_b<<<dim3(16, 32, 16), 256, 0, stream>>>(Wd, wdT, 1024, 512);

  // ---- projection (3-term hi/lo MFMA) + router (fp32) ----
  k_concat_split<<<dim3(6144), 256, 0, stream>>>(cur_obs, hlat, z, xch, xcl);
  k_gg<0, 0, 2, 2><<<dim3(128), 256, 0, stream>>>(xch, xcl, prjTh, prjTl, proj_b,
      x, nullptr, nullptr, 384, 384, 384, 4, 512);
  k_gemm<0, true, float><<<dim3(64, 1), 256, 0, stream>>>(x, router_w, router_b, logitsb, 16, 512);
  k_router<<<dim3(16), 256, 0, stream>>>(logitsb, tidA, twA, posA, counts);
  k_offsets<<<dim3(1), 64, 0, stream>>>(counts, offs);
  k_build<<<dim3(64), 256, 0, stream>>>(tidA, twA, posA, offs, rowlist, wlist);
  k_f32_to_bf4<<<dim3(2048), 256, 0, stream>>>(x, xh, BATCH * 512 / 4);

  // ---- MoE up (expert->XCD swizzled, pure bf16) ----
  k_gmoeup<<<dim3(4096), 256, 0, stream>>>(xh, wgT, wuT, bg, bu,
                                           rowlist, counts, offs, zp, tmoeb);

  // ---- sh/out bf16 weights into dead wg/wu region; zero h2 ----
  k_transpose_bf<<<dim3(64, 16), 256, 0, stream>>>(shg_w, shgT, 512, 2048);
  k_transpose_bf<<<dim3(64, 16), 256, 0, stream>>>(shu_w, shuT, 512, 2048);
  k_transpose_bf<<<dim3(16, 64), 256, 0, stream>>>(shd_w, shdT, 2048, 512);
  k_transpose_bf<<<dim3(32, 16), 256, 0, stream>>>(out1_w, o1T, 512, 1024);
  k_transpose_bf<<<dim3(32, 32), 256, 0, stream>>>(out2_w, o2T, 1024, 1024);
  k_zero_f4<<<dim3(2048), 256, 0, stream>>>((float4*)h2, BATCH * 512 / 4);

  // ---- MoE down (BK=64, atomic scatter into h2) ----
  k_gmoedown64<<<dim3(2048), 256, 0, stream>>>(tmoeb, wdT, bd, rowlist, wlist,
                                               counts, offs, zp, h2);

  // ---- shared experts (1-term dual); down K-split x2 (128 -> 256 blocks) ----
  k_gdual1<<<dim3(512), 256, 0, stream>>>(xh, shgT, shuT, shg_b, shu_b,
                                          stb, 2048, 512, 512, 512, 16);
  k_ggps<1, 1><<<dim3(256), 256, 0, stream>>>(stb, nullptr, shdT, nullptr, Psh,
                                              1024, 2048, 2048, 4, 512, 128);
  k_combS<0, 2><<<dim3(8192), 256, 0, stream>>>(Psh, shd_b, h2, 2, 9, 512, BATCH * 512);

  // ---- output MLP (1-term bf16, BK=64; out2 emits pair) ----
  k_f32_to_bf4<<<dim3(2048), 256, 0, stream>>>(h2, h2b, BATCH * 512 / 4);
  k_gg64<1, 1><<<dim3(256), 256, 0, stream>>>(h2b, o1T, out1_b,
      nullptr, o1b, nullptr, 512, 512, 512, 8, 1024);
  k_gg64<0, 3><<<dim3(256), 256, 0, stream>>>(o1b, o2T, out2_b,
      nullptr, o2h, o2l, 1024, 1024, 1024, 8, 1024);
  // head: K-split x4 (32 -> 128 blocks), combine into d_out (Nout=23)
  k_ggps<2, 2><<<dim3(128), 256, 0, stream>>>(o2h, o2l, hdTh, hdTl, Phd,
                                              256, 1024, 1024, 1, 128, 32);
  k_combS<0, 0><<<dim3(2048), 256, 0, stream>>>(Phd, head_b, (float*)d_out, 4, 7, 23, BATCH * 128);
}

// Round 17
// 903.871 us; speedup vs baseline: 1.3321x; 1.0969x over previous
//
#include <hip/hip_runtime.h>
#include <hip/hip_bf16.h>

// ============================================================================
// EstVAEStudent forward, round 17: round 16 +
//  (a) mega-fused prep kernels (k_prep_w / k_prep_exp / k_prep_post): 13
//      launches removed via blockIdx range dispatch of independent work.
//  (b) router logits -> 512-block LDS kernel (was 64-block fp32 GEMM).
//  (c) S=8 K-split for enc3/hlin2/head (grid 128 -> 256).
//  (d) epilogue fusions: combz (enc3 combine + reparam), combS EPI=3
//      (shdown combine -> h2b bf16 direct), build+xh fused.
// ============================================================================

#define BATCH 4096
typedef unsigned short u16;
typedef unsigned int u32;
using bf16x8 = __attribute__((ext_vector_type(8))) __bf16;
using f32x4  = __attribute__((ext_vector_type(4))) float;

__device__ __forceinline__ float silu_f(float v) { return v / (1.f + __expf(-v)); }

__device__ __forceinline__ float b2f(u16 u) {
  union { u32 i; float f; } c; c.i = ((u32)u) << 16; return c.f;
}
__device__ __forceinline__ u16 f2b(float f) {
  union { float f; u32 i; } c; c.f = f;
  u32 r = c.i + 0x7FFFu + ((c.i >> 16) & 1u);
  return (u16)(r >> 16);
}

// global_load_lds, 16B per lane, wave-uniform LDS base (lane l -> base+l*16B).
__device__ __forceinline__ void gll16(const u16* g, u16* l) {
  __attribute__((address_space(3))) u32* lp =
      reinterpret_cast<__attribute__((address_space(3))) u32*>(
          reinterpret_cast<uintptr_t>(l));
  __builtin_amdgcn_global_load_lds(reinterpret_cast<const u32*>(g), lp, 16, 0, 0);
}

union U8 { uint4 u; bf16x8 b; };

// ---------------- workspace layout (BYTE offsets) ----------------
static constexpr size_t WT1T_B = 0;               // 256x288 bf16
static constexpr size_t WT2T_B = 147456;          // 512x768
static constexpr size_t WT3T_B = 933888;          // 1024x1536
static constexpr size_t HL1T_B = 4079616;         // 1024x1024 -> ends 6176768
static constexpr size_t RA_B   = 6176768;         // 58,720,256 B
static constexpr size_t RB_B   = 64897024;        // 54,525,952 B
static constexpr size_t P_B    = 119422976;
// RA phases:
static constexpr size_t FRH_B  = RA_B;                    // fut_ref hi bf16 20,971,520
static constexpr size_t FRL_B  = RA_B + 20971520;
static constexpr size_t E1H_B  = RA_B + 41943040;         // e1 pair bf16 8,388,608 ea
static constexpr size_t E1L_B  = RA_B + 50331648;
static constexpr size_t E2H_B  = RA_B;                    // e2 pair (fr dead) 8,388,608 ea
static constexpr size_t E2L_B  = RA_B + 8388608;
static constexpr size_t Y1_B   = RA_B;                    // conv1 out (52,428,800)
static constexpr size_t Y3_B   = RA_B;                    // conv3 out bf16 (y1 dead)
static constexpr size_t WGT_B  = RA_B;                    // experts bf16 (y3 dead)
static constexpr size_t WUT_B  = RA_B + 16777216;
static constexpr size_t WDT_B  = RA_B + 33554432;
static constexpr size_t X_B    = RA_B + 50331648;         // x f32 8,388,608
static constexpr size_t SHGT_B = RA_B;                    // after moe_up (wg/wu dead)
static constexpr size_t SHUT_B = RA_B + 2097152;
static constexpr size_t SHDT_B = RA_B + 4194304;
static constexpr size_t O1T_B  = RA_B + 6291456;
static constexpr size_t O2T_B  = RA_B + 7340032;          // ends RA+9,437,184
static constexpr size_t H2_B   = RA_B + 25165824;         // f32 8,388,608
static constexpr size_t H2B_B  = RA_B + 33554432;         // h2 bf16 4,194,304 (wdT dead)
// RB phases:
static constexpr size_t E1TH_B = RB_B;                    // enc1 WT pair 5,242,880 ea
static constexpr size_t E1TL_B = RB_B + 5242880;
static constexpr size_t E2TH_B = RB_B + 10485760;         // enc2 WT pair 2,097,152 ea
static constexpr size_t E2TL_B = RB_B + 12582912;         // ends 14,680,064
static constexpr size_t PENC_B = RB_B + 14680064;         // K-split partials f32 (<=33MB)
static constexpr size_t HSB_B  = RB_B;                    // hist_seq bf16 (enc dead)
static constexpr size_t Y2_B   = RB_B;                    // conv2 out
static constexpr size_t HB_B   = RB_B;                    // hb bf16 8,388,608 (y2 dead)
static constexpr size_t HI1_B  = RB_B + 8388608;          // hi1b bf16 8,388,608
static constexpr size_t PHL2_B = RB_B + 16777216;         // hlin2 partials f32 8x2MB
static constexpr size_t XCH_B  = RB_B + 16777216;         // concat pair bf16 (after hlin2)
static constexpr size_t XCL_B  = RB_B + 19922944;
static constexpr size_t XH_B   = RB_B;                    // x bf16 4,194,304 (hb dead)
static constexpr size_t TM_B   = RB_B + 8388608;          // t_moe bf16 33,554,432
static constexpr size_t STB_B  = RB_B + 8388608;          // stb bf16 16,777,216 (tm dead)
static constexpr size_t PSH_B  = RB_B + 25165824;         // shdown partials f32 2x8MB
static constexpr size_t O1B_B  = RB_B;                    // o1 bf16 8,388,608 (xh dead)
static constexpr size_t O2H_B  = RB_B + 16777216;         // o2 pair bf16 8,388,608 ea
static constexpr size_t O2L_B  = RB_B + 25165824;
static constexpr size_t PHD_B  = RB_B + 33554432;         // head partials f32 8x2MB
// P smalls:
static constexpr size_t HLAT_B = P_B;
static constexpr size_t Z_B    = P_B + 3145728;
static constexpr size_t LOG_B  = P_B + 4194304;
static constexpr size_t TID_B  = P_B + 4456448;
static constexpr size_t TW_B   = P_B + 4521984;
static constexpr size_t POS_B  = P_B + 4587520;
static constexpr size_t CNT_B  = P_B + 4653056;
static constexpr size_t OFS_B  = P_B + 4653184;
static constexpr size_t ROWL_B = P_B + 4653312;
static constexpr size_t WL_B   = P_B + 4718848;
static constexpr size_t ZP_B   = P_B + 4784384;           // 4096 B zero page
static constexpr size_t PRJH_B = P_B + 4788480;           // proj WT pair 393,216 ea
static constexpr size_t PRJL_B = P_B + 5181696;
static constexpr size_t E3TH_B = P_B + 5574912;           // enc3 WT pair 262,144 ea
static constexpr size_t E3TL_B = P_B + 5837056;
static constexpr size_t HL2P_B = P_B + 6099200;           // hlin2 padded WT 262,144
static constexpr size_t HDH_B  = P_B + 6361344;           // head padded WT pair 262,144 ea
static constexpr size_t HDL_B  = P_B + 6623488;           // ends P+6,885,632

// XCD-coherent tile decode (128-row m-tiles): m-tiles % 8 == 0.
#define TILE_DECODE(nn_)                         \
  const int bid = blockIdx.x;                    \
  const int xcd = bid & 7;                       \
  const int tt_ = bid >> 3;                      \
  const int n0 = (tt_ % (nn_)) * 128;            \
  const int m0 = ((tt_ / (nn_)) * 8 + xcd) * 128;

// ---------------- device transpose helpers ----------------
__device__ __forceinline__ void dev_tr_bf(const float* __restrict__ W, u16* __restrict__ WT,
                                          int K, int N, int Ng, int n0, int k0,
                                          int tid, float (*t)[33]) {
  int lx = tid & 31, ly = tid >> 5;
#pragma unroll
  for (int r = 0; r < 32; r += 8)
    t[ly + r][lx] = (n0 + lx < Ng) ? W[(size_t)(k0 + ly + r) * N + n0 + lx] : 0.f;
  __syncthreads();
#pragma unroll
  for (int r = 0; r < 32; r += 8)
    WT[(size_t)(n0 + ly + r) * K + k0 + lx] = f2b(t[lx][ly + r]);
}
__device__ __forceinline__ void dev_tr_hilo(const float* __restrict__ W, u16* __restrict__ WTh,
                                            u16* __restrict__ WTl, int K, int N, int Ng,
                                            int n0, int k0, int tid, float (*t)[33]) {
  int lx = tid & 31, ly = tid >> 5;
#pragma unroll
  for (int r = 0; r < 32; r += 8)
    t[ly + r][lx] = (n0 + lx < Ng) ? W[(size_t)(k0 + ly + r) * N + n0 + lx] : 0.f;
  __syncthreads();
#pragma unroll
  for (int r = 0; r < 32; r += 8) {
    float f = t[lx][ly + r];
    u16 h = f2b(f);
    size_t o = (size_t)(n0 + ly + r) * K + k0 + lx;
    WTh[o] = h;
    WTl[o] = f2b(f - b2f(h));
  }
}

// ---------------- mega prep kernels ----------------
// k_prep_w: counts/zp zero + conv weight preps + hlin1 + enc/proj hilo +
// head/hlin2 padded. grid = 13157 blocks (range dispatch, branch uniform).
__global__ __launch_bounds__(256) void k_prep_w(
    int* __restrict__ counts, int* __restrict__ zpi,
    const float* __restrict__ c1w, u16* __restrict__ wt1T,
    const float* __restrict__ c2w, u16* __restrict__ wt2T,
    const float* __restrict__ c3w, u16* __restrict__ wt3T,
    const float* __restrict__ hlin1_w, u16* __restrict__ hl1T,
    const float* __restrict__ enc1_w, u16* __restrict__ e1Th, u16* __restrict__ e1Tl,
    const float* __restrict__ enc2_w, u16* __restrict__ e2Th, u16* __restrict__ e2Tl,
    const float* __restrict__ enc3_w, u16* __restrict__ e3Th, u16* __restrict__ e3Tl,
    const float* __restrict__ proj_w, u16* __restrict__ prjTh, u16* __restrict__ prjTl,
    const float* __restrict__ head_w, u16* __restrict__ hdTh, u16* __restrict__ hdTl,
    const float* __restrict__ hlin2_w, u16* __restrict__ hl2P) {
  __shared__ float t[32][33];
  int b = blockIdx.x;
  const int tid = threadIdx.x;
  if (b < 5) {
    int i = b * 256 + tid;
    if (i < 16) counts[i] = 0;
    else if (i < 1040) zpi[i - 16] = 0;
    return;
  }
  b -= 5;
  if (b < 7968) {  // conv weight repack
    int idx = b * 256 + tid;
    const float* w; u16* tt; int CIN;
    if (idx < 73728)        { w = c1w; tt = wt1T; CIN = 96; }
    else if (idx < 466944)  { idx -= 73728;  w = c2w; tt = wt2T; CIN = 256; }
    else if (idx < 2039808) { idx -= 466944; w = c3w; tt = wt3T; CIN = 512; }
    else return;
    int Kc = CIN * 3;
    int o = idx / Kc, c = idx - o * Kc;
    int k = c / CIN, i = c - k * CIN;
    tt[idx] = f2b(w[(size_t)o * Kc + i * 3 + k]);
    return;
  }
  b -= 7968;
  if (b < 1024) { dev_tr_bf(hlin1_w, hl1T, 1024, 1024, 1024, (b & 31) * 32, (b >> 5) * 32, tid, t); return; }
  b -= 1024;
  if (b < 2560) { dev_tr_hilo(enc1_w, e1Th, e1Tl, 2560, 1024, 1024, (b & 31) * 32, (b >> 5) * 32, tid, t); return; }
  b -= 2560;
  if (b < 1024) { dev_tr_hilo(enc2_w, e2Th, e2Tl, 1024, 1024, 1024, (b & 31) * 32, (b >> 5) * 32, tid, t); return; }
  b -= 1024;
  if (b < 128) { dev_tr_hilo(enc3_w, e3Th, e3Tl, 1024, 128, 128, (b & 3) * 32, (b >> 2) * 32, tid, t); return; }
  b -= 128;
  if (b < 192) { dev_tr_hilo(proj_w, prjTh, prjTl, 384, 512, 512, (b & 15) * 32, (b >> 4) * 32, tid, t); return; }
  b -= 192;
  if (b < 128) { dev_tr_hilo(head_w, hdTh, hdTl, 1024, 23, 23, (b & 3) * 32, (b >> 2) * 32, tid, t); return; }
  b -= 128;
  dev_tr_bf(hlin2_w, hl2P, 1024, 64, 64, (b & 3) * 32, (b >> 2) * 32, tid, t);
}

// k_prep_exp: 16-expert Wg/Wu/Wd transposes. grid = 24576.
__global__ __launch_bounds__(256) void k_prep_exp(
    const float* __restrict__ Wg, u16* __restrict__ wgT,
    const float* __restrict__ Wu, u16* __restrict__ wuT,
    const float* __restrict__ Wd, u16* __restrict__ wdT) {
  __shared__ float t[32][33];
  int b = blockIdx.x;
  const int tid = threadIdx.x;
  if (b < 8192) {
    int e = b >> 9, r = b & 511;
    dev_tr_bf(Wg + (size_t)e * 512 * 1024, wgT + (size_t)e * 512 * 1024,
              512, 1024, 1024, (r & 31) * 32, (r >> 5) * 32, tid, t);
    return;
  }
  b -= 8192;
  if (b < 8192) {
    int e = b >> 9, r = b & 511;
    dev_tr_bf(Wu + (size_t)e * 512 * 1024, wuT + (size_t)e * 512 * 1024,
              512, 1024, 1024, (r & 31) * 32, (r >> 5) * 32, tid, t);
    return;
  }
  b -= 8192;
  {
    int e = b >> 9, r = b & 511;
    dev_tr_bf(Wd + (size_t)e * 1024 * 512, wdT + (size_t)e * 1024 * 512,
              1024, 512, 512, (r & 15) * 32, (r >> 4) * 32, tid, t);
  }
}

// k_prep_post: sh/out transposes (wg/wu dead) + h2 zero. grid = 6656.
__global__ __launch_bounds__(256) void k_prep_post(
    const float* __restrict__ shg_w, u16* __restrict__ shgT,
    const float* __restrict__ shu_w, u16* __restrict__ shuT,
    const float* __restrict__ shd_w, u16* __restrict__ shdT,
    const float* __restrict__ o1w, u16* __restrict__ o1T,
    const float* __restrict__ o2w, u16* __restrict__ o2T,
    float4* __restrict__ h2z) {
  __shared__ float t[32][33];
  int b = blockIdx.x;
  const int tid = threadIdx.x;
  if (b < 1024) { dev_tr_bf(shg_w, shgT, 512, 2048, 2048, (b & 63) * 32, (b >> 6) * 32, tid, t); return; }
  b -= 1024;
  if (b < 1024) { dev_tr_bf(shu_w, shuT, 512, 2048, 2048, (b & 63) * 32, (b >> 6) * 32, tid, t); return; }
  b -= 1024;
  if (b < 1024) { dev_tr_bf(shd_w, shdT, 2048, 512, 512, (b & 15) * 32, (b >> 4) * 32, tid, t); return; }
  b -= 1024;
  if (b < 512) { dev_tr_bf(o1w, o1T, 512, 1024, 1024, (b & 31) * 32, (b >> 5) * 32, tid, t); return; }
  b -= 512;
  if (b < 1024) { dev_tr_bf(o2w, o2T, 1024, 1024, 1024, (b & 31) * 32, (b >> 5) * 32, tid, t); return; }
  b -= 1024;
  {
    int i = b * 256 + tid;
    if (i < BATCH * 512 / 4) h2z[i] = make_float4(0.f, 0.f, 0.f, 0.f);
  }
}

// ---------------- small prep kernels (still standalone) ----------------
__global__ void k_f32_to_bf4(const float* __restrict__ s, u16* __restrict__ d, int n4) {
  int i = blockIdx.x * 256 + threadIdx.x;
  if (i >= n4) return;
  float4 v = *(const float4*)(s + (size_t)i * 4);
  *(ushort4*)(d + (size_t)i * 4) = make_ushort4(f2b(v.x), f2b(v.y), f2b(v.z), f2b(v.w));
}
// f32 -> (hi, lo) bf16 pair
__global__ void k_split_x(const float* __restrict__ s, u16* __restrict__ dh,
                          u16* __restrict__ dl, int n4) {
  int i = blockIdx.x * 256 + threadIdx.x;
  if (i >= n4) return;
  float4 v = *(const float4*)(s + (size_t)i * 4);
  float a[4] = {v.x, v.y, v.z, v.w};
  ushort4 h, l;
  u16* hp = (u16*)&h; u16* lp = (u16*)&l;
#pragma unroll
  for (int j = 0; j < 4; ++j) {
    u16 hh = f2b(a[j]);
    hp[j] = hh;
    lp[j] = f2b(a[j] - b2f(hh));
  }
  *(ushort4*)(dh + (size_t)i * 4) = h;
  *(ushort4*)(dl + (size_t)i * 4) = l;
}
// combine two f32 K-split partials (vectorized, full-width N pow2).
template<int ACT>
__global__ void k_comb2(const float* __restrict__ P0, const float* __restrict__ P1,
                        const float* __restrict__ bias, u16* __restrict__ Ch,
                        u16* __restrict__ Cl, int N, int n4) {
  int i = blockIdx.x * 256 + threadIdx.x;
  if (i >= n4) return;
  float4 a = *(const float4*)(P0 + (size_t)i * 4);
  float4 b = *(const float4*)(P1 + (size_t)i * 4);
  int col = (i * 4) & (N - 1);
  float r[4] = {a.x + b.x, a.y + b.y, a.z + b.z, a.w + b.w};
  ushort4 h, l;
  u16* hp = (u16*)&h; u16* lp = (u16*)&l;
#pragma unroll
  for (int j = 0; j < 4; ++j) {
    float v = r[j] + bias[col + j];
    if (ACT) v = silu_f(v);
    u16 hh = f2b(v);
    hp[j] = hh;
    lp[j] = f2b(v - b2f(hh));
  }
  *(ushort4*)(Ch + (size_t)i * 4) = h;
  *(ushort4*)(Cl + (size_t)i * 4) = l;
}
// generic scalar S-way combine; partial stride Np=2^lgNp; out stride/guard Nout.
// EPI: 0 f32 store, 2 f32 +=, 3 read-Cf-add + bf16 store to Ch.
template<int ACT, int EPI>
__global__ void k_combS(const float* __restrict__ P, const float* __restrict__ bias,
                        float* __restrict__ Cf, u16* __restrict__ Ch,
                        int S, int lgNp, int Nout, int total) {
  int idx = blockIdx.x * 256 + threadIdx.x;
  if (idx >= total) return;
  int row = idx >> lgNp;
  int col = idx & ((1 << lgNp) - 1);
  if (col >= Nout) return;
  float s = 0.f;
  for (int si = 0; si < S; ++si) s += P[(size_t)si * total + idx];
  s += bias[col];
  if (ACT) s = silu_f(s);
  if (EPI == 0) Cf[(size_t)row * Nout + col] = s;
  else if (EPI == 2) Cf[(size_t)row * Nout + col] += s;
  else {
    s += Cf[(size_t)row * Nout + col];
    Ch[(size_t)row * Nout + col] = f2b(s);
  }
}
// enc3 combine fused with reparameterize: z = mu + exp(0.5*logvar)*noise.
// P layout [S][BATCH][128]; mu col j, logvar col 64+j.
__global__ void k_combz(const float* __restrict__ P, const float* __restrict__ eb,
                        const float* __restrict__ noise, float* __restrict__ z, int S) {
  int idx = blockIdx.x * 256 + threadIdx.x;
  if (idx >= BATCH * 64) return;
  int b = idx >> 6, j = idx & 63;
  float mu = eb[j], lv = eb[64 + j];
  for (int si = 0; si < S; ++si) {
    const float* Pk = P + (size_t)si * BATCH * 128 + (size_t)b * 128;
    mu += Pk[j];
    lv += Pk[64 + j];
  }
  z[idx] = mu + expf(0.5f * lv) * noise[idx];
}
// concat [obs|hlat|z] -> hi/lo bf16 pair [4096][384]
__global__ void k_concat_split(const float* __restrict__ obs,
                               const float* __restrict__ hl,
                               const float* __restrict__ z,
                               u16* __restrict__ dh, u16* __restrict__ dl) {
  int idx = blockIdx.x * 256 + threadIdx.x;
  if (idx >= BATCH * 384) return;
  int b = idx / 384, c = idx - b * 384;
  float v;
  if (c < 256)      v = obs[(size_t)b * 256 + c];
  else if (c < 320) v = hl[(size_t)b * 64 + (c - 256)];
  else              v = z[(size_t)b * 64 + (c - 320)];
  u16 h = f2b(v);
  dh[idx] = h;
  dl[idx] = f2b(v - b2f(h));
}

// ============================================================================
// 128x128 gll GEMM cores: BK=32, 4 waves (2x2 of 64x64).
// ============================================================================
#define PRO128 \
  const int tid = threadIdx.x; \
  const int lane = tid & 63; \
  const int wid = tid >> 6; \
  const int wr = (wid >> 1) * 64, wc = (wid & 1) * 64; \
  const int l15 = lane & 15, lsub = lane >> 4;

#define MFMA_BF16(a, b, c) __builtin_amdgcn_mfma_f32_16x16x32_bf16(a, b, c, 0, 0, 0)

// AP/BP = hi/lo parts of A/B; EPI: 0 f32, 1 bf16, 2 f32 +=, 3 bf16 pair.
template<int ACT, int EPI, int AP, int BP>
__global__ __launch_bounds__(256) void k_gg(
    const u16* __restrict__ A0, const u16* __restrict__ A1,
    const u16* __restrict__ B0, const u16* __restrict__ B1,
    const float* __restrict__ bias,
    float* __restrict__ Cf, u16* __restrict__ Ch, u16* __restrict__ Cl,
    int K, int lda, int ldb, int nn, int Nout) {
  constexpr int NT = AP + BP;
  __shared__ u16 lds[NT * 4096];
  PRO128
  TILE_DECODE(nn)
  const int r0 = wid * 32 + (lane >> 2);
  const int sl = ((lane & 3) ^ ((r0 >> 1) & 3)) * 8;
  const u16* sA0 = A0 + (size_t)(m0 + r0) * lda + sl;
  const u16* sA1 = (AP == 2) ? A1 + (size_t)(m0 + r0) * lda + sl : nullptr;
  const u16* sB0 = B0 + (size_t)(n0 + r0) * ldb + sl;
  const u16* sB1 = (BP == 2) ? B1 + (size_t)(n0 + r0) * ldb + sl : nullptr;
  const size_t stepA = (size_t)16 * lda, stepB = (size_t)16 * ldb;
  const int wb = wid * 1024;

  f32x4 acc[4][4];
  const f32x4 zf = {0.f, 0.f, 0.f, 0.f};
#pragma unroll
  for (int i = 0; i < 4; ++i)
#pragma unroll
    for (int j = 0; j < 4; ++j) acc[i][j] = zf;

  for (int k0 = 0; k0 < K; k0 += 32) {
    {
      int t = 0;
      gll16(sA0 + k0, &lds[t * 4096 + wb]);
      gll16(sA0 + stepA + k0, &lds[t * 4096 + wb + 512]);
      ++t;
      if (AP == 2) {
        gll16(sA1 + k0, &lds[t * 4096 + wb]);
        gll16(sA1 + stepA + k0, &lds[t * 4096 + wb + 512]);
        ++t;
      }
      gll16(sB0 + k0, &lds[t * 4096 + wb]);
      gll16(sB0 + stepB + k0, &lds[t * 4096 + wb + 512]);
      ++t;
      if (BP == 2) {
        gll16(sB1 + k0, &lds[t * 4096 + wb]);
        gll16(sB1 + stepB + k0, &lds[t * 4096 + wb + 512]);
      }
    }
    __syncthreads();
    U8 fah[4], fal[4];
#pragma unroll
    for (int i = 0; i < 4; ++i) {
      int ra = wr + i * 16 + l15;
      int ao = ra * 32 + ((lsub ^ ((ra >> 1) & 3))) * 8;
      fah[i].u = *(const uint4*)&lds[ao];
      if (AP == 2) fal[i].u = *(const uint4*)&lds[4096 + ao];
    }
#pragma unroll
    for (int ni = 0; ni < 4; ++ni) {
      int rb = wc + ni * 16 + l15;
      int bo = AP * 4096 + rb * 32 + ((lsub ^ ((rb >> 1) & 3))) * 8;
      U8 fbh, fbl;
      fbh.u = *(const uint4*)&lds[bo];
      if (BP == 2) fbl.u = *(const uint4*)&lds[4096 + bo];
#pragma unroll
      for (int mi = 0; mi < 4; ++mi) {
        acc[mi][ni] = MFMA_BF16(fah[mi].b, fbh.b, acc[mi][ni]);
        if (BP == 2) acc[mi][ni] = MFMA_BF16(fah[mi].b, fbl.b, acc[mi][ni]);
        if (AP == 2) acc[mi][ni] = MFMA_BF16(fal[mi].b, fbh.b, acc[mi][ni]);
      }
    }
    __syncthreads();
  }
  const int row4 = lsub * 4;
#pragma unroll
  for (int mi = 0; mi < 4; ++mi)
#pragma unroll
    for (int ni = 0; ni < 4; ++ni) {
      int col = n0 + wc + ni * 16 + l15;
      if (col >= Nout) continue;
      float bv = bias[col];
#pragma unroll
      for (int j = 0; j < 4; ++j) {
        int row = m0 + wr + mi * 16 + row4 + j;
        float v = acc[mi][ni][j] + bv;
        if (ACT) v = silu_f(v);
        if (EPI == 0) Cf[(size_t)row * Nout + col] = v;
        else if (EPI == 1) Ch[(size_t)row * Nout + col] = f2b(v);
        else if (EPI == 2) Cf[(size_t)row * Nout + col] += v;
        else {
          u16 vh = f2b(v);
          Ch[(size_t)row * Nout + col] = vh;
          Cl[(size_t)row * Nout + col] = f2b(v - b2f(vh));
        }
      }
    }
}

// generic K-split partial GEMM: grid = base*S; kh = bid/base; writes raw f32
// partials (no bias/act) to P + kh*BATCH*Nt. K arg = Kh (per-split).
template<int AP, int BP>
__global__ __launch_bounds__(256) void k_ggps(
    const u16* __restrict__ A0, const u16* __restrict__ A1,
    const u16* __restrict__ B0, const u16* __restrict__ B1,
    float* __restrict__ P, int Kh, int lda, int ldb, int nn, int Nt, int base) {
  constexpr int NT = AP + BP;
  __shared__ u16 lds[NT * 4096];
  PRO128
  const int bidx = blockIdx.x;
  const int kh = bidx / base;
  const int b2 = bidx - kh * base;
  const int xcd = b2 & 7;
  const int tt_ = b2 >> 3;
  const int n0 = (tt_ % nn) * 128;
  const int m0 = ((tt_ / nn) * 8 + xcd) * 128;
  const int koff = kh * Kh;
  const int r0 = wid * 32 + (lane >> 2);
  const int sl = ((lane & 3) ^ ((r0 >> 1) & 3)) * 8;
  const u16* sA0 = A0 + (size_t)(m0 + r0) * lda + sl + koff;
  const u16* sA1 = (AP == 2) ? A1 + (size_t)(m0 + r0) * lda + sl + koff : nullptr;
  const u16* sB0 = B0 + (size_t)(n0 + r0) * ldb + sl + koff;
  const u16* sB1 = (BP == 2) ? B1 + (size_t)(n0 + r0) * ldb + sl + koff : nullptr;
  const size_t stepA = (size_t)16 * lda, stepB = (size_t)16 * ldb;
  const int wb = wid * 1024;

  f32x4 acc[4][4];
  const f32x4 zf = {0.f, 0.f, 0.f, 0.f};
#pragma unroll
  for (int i = 0; i < 4; ++i)
#pragma unroll
    for (int j = 0; j < 4; ++j) acc[i][j] = zf;

  for (int k0 = 0; k0 < Kh; k0 += 32) {
    {
      int t = 0;
      gll16(sA0 + k0, &lds[t * 4096 + wb]);
      gll16(sA0 + stepA + k0, &lds[t * 4096 + wb + 512]);
      ++t;
      if (AP == 2) {
        gll16(sA1 + k0, &lds[t * 4096 + wb]);
        gll16(sA1 + stepA + k0, &lds[t * 4096 + wb + 512]);
        ++t;
      }
      gll16(sB0 + k0, &lds[t * 4096 + wb]);
      gll16(sB0 + stepB + k0, &lds[t * 4096 + wb + 512]);
      ++t;
      if (BP == 2) {
        gll16(sB1 + k0, &lds[t * 4096 + wb]);
        gll16(sB1 + stepB + k0, &lds[t * 4096 + wb + 512]);
      }
    }
    __syncthreads();
    U8 fah[4], fal[4];
#pragma unroll
    for (int i = 0; i < 4; ++i) {
      int ra = wr + i * 16 + l15;
      int ao = ra * 32 + ((lsub ^ ((ra >> 1) & 3))) * 8;
      fah[i].u = *(const uint4*)&lds[ao];
      if (AP == 2) fal[i].u = *(const uint4*)&lds[4096 + ao];
    }
#pragma unroll
    for (int ni = 0; ni < 4; ++ni) {
      int rb = wc + ni * 16 + l15;
      int bo = AP * 4096 + rb * 32 + ((lsub ^ ((rb >> 1) & 3))) * 8;
      U8 fbh, fbl;
      fbh.u = *(const uint4*)&lds[bo];
      if (BP == 2) fbl.u = *(const uint4*)&lds[4096 + bo];
#pragma unroll
      for (int mi = 0; mi < 4; ++mi) {
        acc[mi][ni] = MFMA_BF16(fah[mi].b, fbh.b, acc[mi][ni]);
        if (BP == 2) acc[mi][ni] = MFMA_BF16(fah[mi].b, fbl.b, acc[mi][ni]);
        if (AP == 2) acc[mi][ni] = MFMA_BF16(fal[mi].b, fbh.b, acc[mi][ni]);
      }
    }
    __syncthreads();
  }
  float* Pk = P + (size_t)kh * ((size_t)BATCH * Nt);
  const int row4 = lsub * 4;
#pragma unroll
  for (int mi = 0; mi < 4; ++mi)
#pragma unroll
    for (int ni = 0; ni < 4; ++ni) {
      int col = n0 + wc + ni * 16 + l15;
#pragma unroll
      for (int j = 0; j < 4; ++j) {
        int row = m0 + wr + mi * 16 + row4 + j;
        Pk[(size_t)row * Nt + col] = acc[mi][ni][j];
      }
    }
}

// BK=64 1-term GEMM (K%64==0): half the barriers. 8-slot swizzle f(r)=r&7.
template<int ACT, int EPI>
__global__ __launch_bounds__(256) void k_gg64(
    const u16* __restrict__ A0, const u16* __restrict__ B0,
    const float* __restrict__ bias,
    float* __restrict__ Cf, u16* __restrict__ Ch, u16* __restrict__ Cl,
    int K, int lda, int ldb, int nn, int Nout) {
  __shared__ u16 lds[2 * 8192];
  PRO128
  TILE_DECODE(nn)
  const int soff = ((lane & 7) ^ (lane >> 3)) * 8;
  const u16* sAb = A0 + (size_t)(m0 + wid * 32 + (lane >> 3)) * lda + soff;
  const u16* sBb = B0 + (size_t)(n0 + wid * 32 + (lane >> 3)) * ldb + soff;
  const int wb = wid * 2048;

  f32x4 acc[4][4];
  const f32x4 zf = {0.f, 0.f, 0.f, 0.f};
#pragma unroll
  for (int i = 0; i < 4; ++i)
#pragma unroll
    for (int j = 0; j < 4; ++j) acc[i][j] = zf;

  for (int k0 = 0; k0 < K; k0 += 64) {
#pragma unroll
    for (int c = 0; c < 4; ++c) {
      gll16(sAb + (size_t)c * 8 * lda + k0, &lds[wb + c * 512]);
      gll16(sBb + (size_t)c * 8 * ldb + k0, &lds[8192 + wb + c * 512]);
    }
    __syncthreads();
#pragma unroll
    for (int h = 0; h < 2; ++h) {
      U8 fa[4], fb[4];
#pragma unroll
      for (int i = 0; i < 4; ++i) {
        int ra = wr + i * 16 + l15;
        fa[i].u = *(const uint4*)&lds[ra * 64 + (((h * 4 + lsub) ^ (ra & 7))) * 8];
        int rb = wc + i * 16 + l15;
        fb[i].u = *(const uint4*)&lds[8192 + rb * 64 + (((h * 4 + lsub) ^ (rb & 7))) * 8];
      }
#pragma unroll
      for (int mi = 0; mi < 4; ++mi)
#pragma unroll
        for (int ni = 0; ni < 4; ++ni)
          acc[mi][ni] = MFMA_BF16(fa[mi].b, fb[ni].b, acc[mi][ni]);
    }
    __syncthreads();
  }
  const int row4 = lsub * 4;
#pragma unroll
  for (int mi = 0; mi < 4; ++mi)
#pragma unroll
    for (int ni = 0; ni < 4; ++ni) {
      int col = n0 + wc + ni * 16 + l15;
      if (col >= Nout) continue;
      float bv = bias[col];
#pragma unroll
      for (int j = 0; j < 4; ++j) {
        int row = m0 + wr + mi * 16 + row4 + j;
        float v = acc[mi][ni][j] + bv;
        if (ACT) v = silu_f(v);
        if (EPI == 0) Cf[(size_t)row * Nout + col] = v;
        else if (EPI == 1) Ch[(size_t)row * Nout + col] = f2b(v);
        else if (EPI == 2) Cf[(size_t)row * Nout + col] += v;
        else {
          u16 vh = f2b(v);
          Ch[(size_t)row * Nout + col] = vh;
          Cl[(size_t)row * Nout + col] = f2b(v - b2f(vh));
        }
      }
    }
}

// shared-expert dual, pure bf16 1-term: C bf16 = silu(A@G+bg)*(A@U+bu)
__global__ __launch_bounds__(256) void k_gdual1(
    const u16* __restrict__ A0, const u16* __restrict__ G0,
    const u16* __restrict__ U0,
    const float* __restrict__ bg, const float* __restrict__ bu,
    u16* __restrict__ C, int N, int K, int lda, int ldb, int nn) {
  __shared__ u16 lds[3 * 4096];
  PRO128
  TILE_DECODE(nn)
  const int r0 = wid * 32 + (lane >> 2);
  const int sl = ((lane & 3) ^ ((r0 >> 1) & 3)) * 8;
  const u16* sA = A0 + (size_t)(m0 + r0) * lda + sl;
  const u16* sG = G0 + (size_t)(n0 + r0) * ldb + sl;
  const u16* sU = U0 + (size_t)(n0 + r0) * ldb + sl;
  const size_t stepA = (size_t)16 * lda, stepB = (size_t)16 * ldb;
  const int wb = wid * 1024;
  f32x4 ag[4][4], au[4][4];
  const f32x4 zf = {0.f, 0.f, 0.f, 0.f};
#pragma unroll
  for (int i = 0; i < 4; ++i)
#pragma unroll
    for (int j = 0; j < 4; ++j) { ag[i][j] = zf; au[i][j] = zf; }

  for (int k0 = 0; k0 < K; k0 += 32) {
    gll16(sA + k0, &lds[wb]);
    gll16(sA + stepA + k0, &lds[wb + 512]);
    gll16(sG + k0, &lds[4096 + wb]);
    gll16(sG + stepB + k0, &lds[4096 + wb + 512]);
    gll16(sU + k0, &lds[2 * 4096 + wb]);
    gll16(sU + stepB + k0, &lds[2 * 4096 + wb + 512]);
    __syncthreads();
    U8 fa[4];
#pragma unroll
    for (int i = 0; i < 4; ++i) {
      int ra = wr + i * 16 + l15;
      fa[i].u = *(const uint4*)&lds[ra * 32 + ((lsub ^ ((ra >> 1) & 3))) * 8];
    }
#pragma unroll
    for (int ni = 0; ni < 4; ++ni) {
      int rb = wc + ni * 16 + l15;
      int bo = rb * 32 + ((lsub ^ ((rb >> 1) & 3))) * 8;
      U8 fg, fu;
      fg.u = *(const uint4*)&lds[4096 + bo];
      fu.u = *(const uint4*)&lds[2 * 4096 + bo];
#pragma unroll
      for (int mi = 0; mi < 4; ++mi) {
        ag[mi][ni] = MFMA_BF16(fa[mi].b, fg.b, ag[mi][ni]);
        au[mi][ni] = MFMA_BF16(fa[mi].b, fu.b, au[mi][ni]);
      }
    }
    __syncthreads();
  }
  const int row4 = lsub * 4;
#pragma unroll
  for (int mi = 0; mi < 4; ++mi)
#pragma unroll
    for (int ni = 0; ni < 4; ++ni) {
      int col = n0 + wc + ni * 16 + l15;
      float bgv = bg[col], buv = bu[col];
#pragma unroll
      for (int j = 0; j < 4; ++j) {
        int row = m0 + wr + mi * 16 + row4 + j;
        float v = silu_f(ag[mi][ni][j] + bgv) * (au[mi][ni][j] + buv);
        C[(size_t)row * N + col] = f2b(v);
      }
    }
}

// conv as implicit-im2col gll GEMM, BK=32 (conv1).
template<int CIN, int TIN, int TOUT, int STRIDE>
__global__ __launch_bounds__(256) void k_gconv32(
    const u16* __restrict__ X, const u16* __restrict__ WT,
    const float* __restrict__ bias, u16* __restrict__ Y,
    const u16* __restrict__ zp, int COUT, int nn) {
  constexpr int K = CIN * 3;
  __shared__ u16 lds[2 * 4096];
  PRO128
  TILE_DECODE(nn)
  int bA_[2], tb_[2], sl_[2];
  const u16* sB[2];
#pragma unroll
  for (int i = 0; i < 2; ++i) {
    int r = wid * 32 + i * 16 + (lane >> 2);
    int sl = ((lane & 3) ^ ((r >> 1) & 3)) * 8;
    sl_[i] = sl;
    int m = m0 + r;
    int bb = m / TOUT;
    int tt = m - bb * TOUT;
    bA_[i] = bb;
    tb_[i] = tt * STRIDE - 1;
    sB[i] = WT + (size_t)(n0 + r) * K + sl;
  }
  const int wb = wid * 1024;
  f32x4 acc[4][4];
  const f32x4 zf = {0.f, 0.f, 0.f, 0.f};
#pragma unroll
  for (int i = 0; i < 4; ++i)
#pragma unroll
    for (int j = 0; j < 4; ++j) acc[i][j] = zf;

  for (int k0 = 0; k0 < K; k0 += 32) {
#pragma unroll
    for (int i = 0; i < 2; ++i) {
      int kk = k0 + sl_[i];
      int ker = kk / CIN;
      int i0 = kk - ker * CIN;
      int tin = tb_[i] + ker;
      const u16* sa = (tin >= 0 && tin < TIN)
          ? X + ((size_t)bA_[i] * TIN + tin) * CIN + i0 : zp;
      gll16(sa, &lds[wb + i * 512]);
      gll16(sB[i] + k0, &lds[4096 + wb + i * 512]);
    }
    __syncthreads();
    U8 fa[4], fb[4];
#pragma unroll
    for (int i = 0; i < 4; ++i) {
      int ra = wr + i * 16 + l15;
      fa[i].u = *(const uint4*)&lds[ra * 32 + ((lsub ^ ((ra >> 1) & 3))) * 8];
      int rb = wc + i * 16 + l15;
      fb[i].u = *(const uint4*)&lds[4096 + rb * 32 + ((lsub ^ ((rb >> 1) & 3))) * 8];
    }
#pragma unroll
    for (int mi = 0; mi < 4; ++mi)
#pragma unroll
      for (int ni = 0; ni < 4; ++ni)
        acc[mi][ni] = MFMA_BF16(fa[mi].b, fb[ni].b, acc[mi][ni]);
    __syncthreads();
  }
  const int row4 = lsub * 4;
#pragma unroll
  for (int mi = 0; mi < 4; ++mi)
#pragma unroll
    for (int ni = 0; ni < 4; ++ni) {
      int col = n0 + wc + ni * 16 + l15;
      float bv = bias[col];
#pragma unroll
      for (int j = 0; j < 4; ++j) {
        int row = m0 + wr + mi * 16 + row4 + j;
        Y[(size_t)row * COUT + col] = f2b(silu_f(acc[mi][ni][j] + bv));
      }
    }
}

// conv as implicit-im2col gll GEMM, BK=64, bf16 output (conv2/conv3).
template<int CIN, int TIN, int TOUT, int STRIDE>
__global__ __launch_bounds__(256) void k_gconv64(
    const u16* __restrict__ X, const u16* __restrict__ WT,
    const float* __restrict__ bias, u16* __restrict__ Y,
    const u16* __restrict__ zp, int COUT, int nn) {
  constexpr int K = CIN * 3;
  __shared__ u16 lds[2 * 8192];
  PRO128
  TILE_DECODE(nn)
  const int soff = ((lane & 7) ^ (lane >> 3)) * 8;
  int bA_[4], tb_[4];
#pragma unroll
  for (int c = 0; c < 4; ++c) {
    int m = m0 + wid * 32 + c * 8 + (lane >> 3);
    int bb = m / TOUT;
    int tt = m - bb * TOUT;
    bA_[c] = bb;
    tb_[c] = tt * STRIDE - 1;
  }
  const u16* sBb = WT + (size_t)(n0 + wid * 32 + (lane >> 3)) * K + soff;
  const int wb = wid * 2048;

  f32x4 acc[4][4];
  const f32x4 zf = {0.f, 0.f, 0.f, 0.f};
#pragma unroll
  for (int i = 0; i < 4; ++i)
#pragma unroll
    for (int j = 0; j < 4; ++j) acc[i][j] = zf;

  for (int k0 = 0; k0 < K; k0 += 64) {
    int kk = k0 + soff;
    int ker = kk / CIN;
    int i0 = kk - ker * CIN;
#pragma unroll
    for (int c = 0; c < 4; ++c) {
      int tin = tb_[c] + ker;
      const u16* sa = (tin >= 0 && tin < TIN)
          ? X + ((size_t)bA_[c] * TIN + tin) * CIN + i0 : zp;
      gll16(sa, &lds[wb + c * 512]);
      gll16(sBb + (size_t)c * 8 * K + k0, &lds[8192 + wb + c * 512]);
    }
    __syncthreads();
#pragma unroll
    for (int h = 0; h < 2; ++h) {
      U8 fa[4], fb[4];
#pragma unroll
      for (int i = 0; i < 4; ++i) {
        int ra = wr + i * 16 + l15;
        fa[i].u = *(const uint4*)&lds[ra * 64 + (((h * 4 + lsub) ^ (ra & 7))) * 8];
        int rb = wc + i * 16 + l15;
        fb[i].u = *(const uint4*)&lds[8192 + rb * 64 + (((h * 4 + lsub) ^ (rb & 7))) * 8];
      }
#pragma unroll
      for (int mi = 0; mi < 4; ++mi)
#pragma unroll
        for (int ni = 0; ni < 4; ++ni)
          acc[mi][ni] = MFMA_BF16(fa[mi].b, fb[ni].b, acc[mi][ni]);
    }
    __syncthreads();
  }
  const int row4 = lsub * 4;
#pragma unroll
  for (int mi = 0; mi < 4; ++mi)
#pragma unroll
    for (int ni = 0; ni < 4; ++ni) {
      int col = n0 + wc + ni * 16 + l15;
      float bv = bias[col];
#pragma unroll
      for (int j = 0; j < 4; ++j) {
        int row = m0 + wr + mi * 16 + row4 + j;
        Y[(size_t)row * COUT + col] = f2b(silu_f(acc[mi][ni][j] + bv));
      }
    }
}

// MoE up: expert->XCD swizzled 1D grid; gathered bf16 (1-term) dual.
__global__ __launch_bounds__(256) void k_gmoeup(
    const u16* __restrict__ xh,
    const u16* __restrict__ WgT, const u16* __restrict__ WuT,
    const float* __restrict__ bg, const float* __restrict__ bu,
    const int* __restrict__ rowlist, const int* __restrict__ counts,
    const int* __restrict__ offs, const u16* __restrict__ zp,
    u16* __restrict__ t_moe) {
  const int bid = blockIdx.x;
  const int xcd = bid & 7, sidx = bid >> 3;
  const int eo = sidx >> 8, r2 = sidx & 255;
  const int mt = r2 >> 3, nt = r2 & 7;
  const int e = xcd + 8 * eo;
  const int ne = counts[e];
  const int m0 = mt * 128;
  if (m0 >= ne) return;
  const int n0 = nt * 128;
  const int base = offs[e];
  constexpr int K = 512, N = 1024;
  const u16* Wge = WgT + (size_t)e * N * K;
  const u16* Wue = WuT + (size_t)e * N * K;
  const float* bge = bg + (size_t)e * N;
  const float* bue = bu + (size_t)e * N;
  __shared__ u16 lds[3 * 4096];
  PRO128
  const u16* sA[2]; const u16* sG[2]; const u16* sU[2];
#pragma unroll
  for (int i = 0; i < 2; ++i) {
    int r = wid * 32 + i * 16 + (lane >> 2);
    int sl = ((lane & 3) ^ ((r >> 1) & 3)) * 8;
    int grow = m0 + r;
    int xr = (grow < ne) ? rowlist[base + grow] : -1;
    sA[i] = (xr >= 0) ? xh + (size_t)xr * K + sl : zp;
    sG[i] = Wge + (size_t)(n0 + r) * K + sl;
    sU[i] = Wue + (size_t)(n0 + r) * K + sl;
  }
  const int wb = wid * 1024;
  f32x4 ag[4][4], au[4][4];
  const f32x4 zf = {0.f, 0.f, 0.f, 0.f};
#pragma unroll
  for (int i = 0; i < 4; ++i)
#pragma unroll
    for (int j = 0; j < 4; ++j) { ag[i][j] = zf; au[i][j] = zf; }

  for (int k0 = 0; k0 < K; k0 += 32) {
#pragma unroll
    for (int i = 0; i < 2; ++i) {
      gll16(sA[i] + k0, &lds[0 * 4096 + wb + i * 512]);
      gll16(sG[i] + k0, &lds[1 * 4096 + wb + i * 512]);
      gll16(sU[i] + k0, &lds[2 * 4096 + wb + i * 512]);
    }
    __syncthreads();
    U8 fa[4];
#pragma unroll
    for (int i = 0; i < 4; ++i) {
      int ra = wr + i * 16 + l15;
      fa[i].u = *(const uint4*)&lds[ra * 32 + ((lsub ^ ((ra >> 1) & 3))) * 8];
    }
#pragma unroll
    for (int ni = 0; ni < 4; ++ni) {
      int rb = wc + ni * 16 + l15;
      int bo = rb * 32 + ((lsub ^ ((rb >> 1) & 3))) * 8;
      U8 fg, fu;
      fg.u = *(const uint4*)&lds[1 * 4096 + bo];
      fu.u = *(const uint4*)&lds[2 * 4096 + bo];
#pragma unroll
      for (int mi = 0; mi < 4; ++mi) {
        ag[mi][ni] = MFMA_BF16(fa[mi].b, fg.b, ag[mi][ni]);
        au[mi][ni] = MFMA_BF16(fa[mi].b, fu.b, au[mi][ni]);
      }
    }
    __syncthreads();
  }
  const int row4 = lsub * 4;
#pragma unroll
  for (int mi = 0; mi < 4; ++mi)
#pragma unroll
    for (int ni = 0; ni < 4; ++ni) {
      int col = n0 + wc + ni * 16 + l15;
      float bgv = bge[col], buv = bue[col];
#pragma unroll
      for (int j = 0; j < 4; ++j) {
        int row = m0 + wr + mi * 16 + row4 + j;
        if (row >= ne) continue;
        float v = silu_f(ag[mi][ni][j] + bgv) * (au[mi][ni][j] + buv);
        t_moe[(size_t)(base + row) * N + col] = f2b(v);
      }
    }
}

// MoE down, BK=64: t_moe x WdT -> weighted atomic scatter into h2.
__global__ __launch_bounds__(256) void k_gmoedown64(
    const u16* __restrict__ t_moe, const u16* __restrict__ WdT,
    const float* __restrict__ bd, const int* __restrict__ rowlist,
    const float* __restrict__ wlist, const int* __restrict__ counts,
    const int* __restrict__ offs, const u16* __restrict__ zp,
    float* __restrict__ h2) {
  const int bid = blockIdx.x;
  const int xcd = bid & 7, sidx = bid >> 3;
  const int eo = sidx >> 7, r2 = sidx & 127;
  const int mt = r2 >> 2, nt = r2 & 3;
  const int e = xcd + 8 * eo;
  const int ne = counts[e];
  const int m0 = mt * 128;
  if (m0 >= ne) return;
  const int n0 = nt * 128;
  const int base = offs[e];
  constexpr int K = 1024, N = 512;
  const u16* Wde = WdT + (size_t)e * N * K;
  const float* bde = bd + (size_t)e * N;
  __shared__ u16 lds[2 * 8192];
  PRO128
  const int soff = ((lane & 7) ^ (lane >> 3)) * 8;
  const u16* sA[4];
#pragma unroll
  for (int c = 0; c < 4; ++c) {
    int grow = m0 + wid * 32 + c * 8 + (lane >> 3);
    sA[c] = (grow < ne) ? t_moe + (size_t)(base + grow) * K + soff : zp;
  }
  const u16* sBb = Wde + (size_t)(n0 + wid * 32 + (lane >> 3)) * K + soff;
  const int wb = wid * 2048;

  f32x4 acc[4][4];
  const f32x4 zf = {0.f, 0.f, 0.f, 0.f};
#pragma unroll
  for (int i = 0; i < 4; ++i)
#pragma unroll
    for (int j = 0; j < 4; ++j) acc[i][j] = zf;

  for (int k0 = 0; k0 < K; k0 += 64) {
#pragma unroll
    for (int c = 0; c < 4; ++c) {
      gll16(sA[c] + k0, &lds[wb + c * 512]);
      gll16(sBb + (size_t)c * 8 * K + k0, &lds[8192 + wb + c * 512]);
    }
    __syncthreads();
#pragma unroll
    for (int h = 0; h < 2; ++h) {
      U8 fa[4], fb[4];
#pragma unroll
      for (int i = 0; i < 4; ++i) {
        int ra = wr + i * 16 + l15;
        fa[i].u = *(const uint4*)&lds[ra * 64 + (((h * 4 + lsub) ^ (ra & 7))) * 8];
        int rb = wc + i * 16 + l15;
        fb[i].u = *(const uint4*)&lds[8192 + rb * 64 + (((h * 4 + lsub) ^ (rb & 7))) * 8];
      }
#pragma unroll
      for (int mi = 0; mi < 4; ++mi)
#pragma unroll
        for (int ni = 0; ni < 4; ++ni)
          acc[mi][ni] = MFMA_BF16(fa[mi].b, fb[ni].b, acc[mi][ni]);
    }
    __syncthreads();
  }
  const int row4 = lsub * 4;
#pragma unroll
  for (int mi = 0; mi < 4; ++mi)
#pragma unroll
    for (int j = 0; j < 4; ++j) {
      int row = m0 + wr + mi * 16 + row4 + j;
      if (row >= ne) continue;
      int r = rowlist[base + row];
      float wl = wlist[base + row];
#pragma unroll
      for (int ni = 0; ni < 4; ++ni) {
        int col = n0 + wc + ni * 16 + l15;
        atomicAdd(&h2[(size_t)r * 512 + col], wl * (acc[mi][ni][j] + bde[col]));
      }
    }
}

// ---------------- router logits: 512 blocks, LDS W (17-pad, conflict-free) ----
__global__ __launch_bounds__(256) void k_logits(const float* __restrict__ x,
                                                const float* __restrict__ W,
                                                const float* __restrict__ bias,
                                                float* __restrict__ out) {
  __shared__ float Ws[512 * 17];
  const int tid = threadIdx.x;
  for (int i = tid; i < 8192; i += 256) {
    int k = i >> 4, e = i & 15;
    Ws[k * 17 + e] = W[i];
  }
  __syncthreads();
  const int rowg = tid >> 5, l32 = tid & 31;
  const int row = blockIdx.x * 8 + rowg;
  const float* xr = x + (size_t)row * 512;
  float acc[16];
#pragma unroll
  for (int e = 0; e < 16; ++e) acc[e] = 0.f;
#pragma unroll
  for (int kb = 0; kb < 16; ++kb) {
    int k = l32 + 32 * kb;
    float xv = xr[k];
    const float* wr = Ws + k * 17;
#pragma unroll
    for (int e = 0; e < 16; ++e) acc[e] = fmaf(xv, wr[e], acc[e]);
  }
#pragma unroll
  for (int m = 1; m < 32; m <<= 1)
#pragma unroll
    for (int e = 0; e < 16; ++e) acc[e] += __shfl_xor(acc[e], m, 64);
  if (l32 == 0) {
#pragma unroll
    for (int e = 0; e < 16; ++e) out[(size_t)row * 16 + e] = acc[e] + bias[e];
  }
}

// ---------------- small elementwise / router kernels ----------------
__global__ void k_mean7(const u16* __restrict__ y3, u16* __restrict__ hb) {
  int idx = blockIdx.x * 256 + threadIdx.x;
  if (idx >= BATCH * 1024) return;
  int b = idx >> 10, o = idx & 1023;
  const u16* p = y3 + (size_t)b * 7 * 1024 + o;
  float s = 0.f;
#pragma unroll
  for (int t = 0; t < 7; ++t) s += b2f(p[(size_t)t * 1024]);
  hb[idx] = f2b(s * (1.f / 7.f));
}

__global__ void k_router(const float* __restrict__ logits, int* __restrict__ tidA,
                         float* __restrict__ twA, int* __restrict__ posA,
                         int* __restrict__ counts) {
  int b = blockIdx.x * 256 + threadIdx.x;
  if (b >= BATCH) return;
  float s[16];
#pragma unroll
  for (int e = 0; e < 16; ++e)
    s[e] = 1.f / (1.f + expf(-logits[(size_t)b * 16 + e]));
  float gsc[4];
#pragma unroll
  for (int g = 0; g < 4; ++g) {
    float m1 = -1e30f; int i1 = -1;
    for (int i = 0; i < 4; ++i) { float v = s[g * 4 + i]; if (v > m1) { m1 = v; i1 = i; } }
    float m2 = -1e30f;
    for (int i = 0; i < 4; ++i) { if (i == i1) continue; float v = s[g * 4 + i]; if (v > m2) m2 = v; }
    gsc[g] = m1 + m2;
  }
  int g1 = 0; float b1 = gsc[0];
  for (int g = 1; g < 4; ++g) if (gsc[g] > b1) { b1 = gsc[g]; g1 = g; }
  int g2 = -1; float b2 = -1e30f;
  for (int g = 0; g < 4; ++g) { if (g == g1) continue; if (gsc[g] > b2) { b2 = gsc[g]; g2 = g; } }
  float ms[16]; bool used[16];
#pragma unroll
  for (int e = 0; e < 16; ++e) {
    int g = e >> 2;
    ms[e] = (g == g1 || g == g2) ? s[e] : 0.f;
    used[e] = false;
  }
  int te[4]; float tv[4]; float tsum = 0.f;
  for (int t = 0; t < 4; ++t) {
    float best = -1.f; int bi = 0;
    for (int e = 0; e < 16; ++e)
      if (!used[e] && ms[e] > best) { best = ms[e]; bi = e; }
    used[bi] = true;
    te[t] = bi;
    tv[t] = s[bi];
    tsum += s[bi];
  }
  float inv = 1.f / (tsum + 1e-20f);
  for (int t = 0; t < 4; ++t) {
    int e = te[t];
    tidA[b * 4 + t] = e;
    twA[b * 4 + t] = tv[t] * inv;  // ROUTE_SCALE = 1.0
    posA[b * 4 + t] = atomicAdd(&counts[e], 1);
  }
}

__global__ void k_offsets(const int* __restrict__ counts, int* __restrict__ offs) {
  if (threadIdx.x == 0 && blockIdx.x == 0) {
    int a = 0;
    for (int e = 0; e < 16; ++e) { offs[e] = a; a += counts[e]; }
    offs[16] = a;
  }
}

// build rowlist/wlist + x f32 -> bf16 (fused, independent ranges). grid 2112.
__global__ void k_build_bf(const int* __restrict__ tidA, const float* __restrict__ twA,
                           const int* __restrict__ posA, const int* __restrict__ offs,
                           int* __restrict__ rowlist, float* __restrict__ wlist,
                           const float* __restrict__ x, u16* __restrict__ xh) {
  int idx = blockIdx.x * 256 + threadIdx.x;
  if (idx < BATCH * 4) {
    int e = tidA[idx];
    int p = offs[e] + posA[idx];
    rowlist[p] = idx >> 2;
    wlist[p] = twA[idx];
    return;
  }
  int j = idx - BATCH * 4;
  if (j >= BATCH * 512 / 4) return;
  float4 v = *(const float4*)(x + (size_t)j * 4);
  *(ushort4*)(xh + (size_t)j * 4) = make_ushort4(f2b(v.x), f2b(v.y), f2b(v.z), f2b(v.w));
}

// ============================================================================
extern "C" void kernel_launch(void* const* d_in, const int* in_sizes, int n_in,
                              void* d_out, int out_size, void* d_ws, size_t ws_size,
                              hipStream_t stream) {
  const float* cur_obs  = (const float*)d_in[0];
  const float* hist_seq = (const float*)d_in[1];
  const float* fut_ref  = (const float*)d_in[2];
  const float* noise    = (const float*)d_in[3];
  const float* conv1_w  = (const float*)d_in[4];
  const float* conv1_b  = (const float*)d_in[5];
  const float* conv2_w  = (const float*)d_in[6];
  const float* conv2_b  = (const float*)d_in[7];
  const float* conv3_w  = (const float*)d_in[8];
  const float* conv3_b  = (const float*)d_in[9];
  const float* hlin1_w  = (const float*)d_in[10];
  const float* hlin1_b  = (const float*)d_in[11];
  const float* hlin2_w  = (const float*)d_in[12];
  const float* hlin2_b  = (const float*)d_in[13];
  const float* enc1_w   = (const float*)d_in[14];
  const float* enc1_b   = (const float*)d_in[15];
  const float* enc2_w   = (const float*)d_in[16];
  const float* enc2_b   = (const float*)d_in[17];
  const float* enc3_w   = (const float*)d_in[18];
  const float* enc3_b   = (const float*)d_in[19];
  const float* proj_w   = (const float*)d_in[20];
  const float* proj_b   = (const float*)d_in[21];
  const float* router_w = (const float*)d_in[22];
  const float* router_b = (const float*)d_in[23];
  const float* Wg       = (const float*)d_in[24];
  const float* bg       = (const float*)d_in[25];
  const float* Wu       = (const float*)d_in[26];
  const float* bu       = (const float*)d_in[27];
  const float* Wd       = (const float*)d_in[28];
  const float* bd       = (const float*)d_in[29];
  const float* shg_w    = (const float*)d_in[30];
  const float* shg_b    = (const float*)d_in[31];
  const float* shu_w    = (const float*)d_in[32];
  const float* shu_b    = (const float*)d_in[33];
  const float* shd_w    = (const float*)d_in[34];
  const float* shd_b    = (const float*)d_in[35];
  const float* out1_w   = (const float*)d_in[36];
  const float* out1_b   = (const float*)d_in[37];
  const float* out2_w   = (const float*)d_in[38];
  const float* out2_b   = (const float*)d_in[39];
  const float* head_w   = (const float*)d_in[40];
  const float* head_b   = (const float*)d_in[41];
  (void)in_sizes; (void)n_in; (void)out_size; (void)ws_size;

  char* wsb = (char*)d_ws;
  u16* wt1T  = (u16*)(wsb + WT1T_B);
  u16* wt2T  = (u16*)(wsb + WT2T_B);
  u16* wt3T  = (u16*)(wsb + WT3T_B);
  u16* hl1T  = (u16*)(wsb + HL1T_B);
  u16* frh   = (u16*)(wsb + FRH_B);
  u16* frl   = (u16*)(wsb + FRL_B);
  u16* e1h   = (u16*)(wsb + E1H_B);
  u16* e1l   = (u16*)(wsb + E1L_B);
  u16* e2h   = (u16*)(wsb + E2H_B);
  u16* e2l   = (u16*)(wsb + E2L_B);
  u16* y1b   = (u16*)(wsb + Y1_B);
  u16* y2b   = (u16*)(wsb + Y2_B);
  u16* y3b   = (u16*)(wsb + Y3_B);
  u16* wgT   = (u16*)(wsb + WGT_B);
  u16* wuT   = (u16*)(wsb + WUT_B);
  u16* wdT   = (u16*)(wsb + WDT_B);
  float* x   = (float*)(wsb + X_B);
  u16* shgT  = (u16*)(wsb + SHGT_B);
  u16* shuT  = (u16*)(wsb + SHUT_B);
  u16* shdT  = (u16*)(wsb + SHDT_B);
  u16* o1T   = (u16*)(wsb + O1T_B);
  u16* o2T   = (u16*)(wsb + O2T_B);
  float* h2  = (float*)(wsb + H2_B);
  u16* h2b   = (u16*)(wsb + H2B_B);
  u16* e1Th  = (u16*)(wsb + E1TH_B);
  u16* e1Tl  = (u16*)(wsb + E1TL_B);
  u16* e2Th  = (u16*)(wsb + E2TH_B);
  u16* e2Tl  = (u16*)(wsb + E2TL_B);
  float* Penc = (float*)(wsb + PENC_B);
  float* Phl2 = (float*)(wsb + PHL2_B);
  float* Psh  = (float*)(wsb + PSH_B);
  float* Phd  = (float*)(wsb + PHD_B);
  u16* hsb   = (u16*)(wsb + HSB_B);
  u16* hb    = (u16*)(wsb + HB_B);
  u16* hi1b  = (u16*)(wsb + HI1_B);
  u16* xch   = (u16*)(wsb + XCH_B);
  u16* xcl   = (u16*)(wsb + XCL_B);
  u16* xh    = (u16*)(wsb + XH_B);
  u16* tmoeb = (u16*)(wsb + TM_B);
  u16* stb   = (u16*)(wsb + STB_B);
  u16* o1b   = (u16*)(wsb + O1B_B);
  u16* o2h   = (u16*)(wsb + O2H_B);
  u16* o2l   = (u16*)(wsb + O2L_B);
  float* hlat = (float*)(wsb + HLAT_B);
  float* z    = (float*)(wsb + Z_B);
  float* logitsb = (float*)(wsb + LOG_B);
  int*   tidA  = (int*)(wsb + TID_B);
  float* twA   = (float*)(wsb + TW_B);
  int*   posA  = (int*)(wsb + POS_B);
  int*   counts = (int*)(wsb + CNT_B);
  int*   offs  = (int*)(wsb + OFS_B);
  int*   rowlist = (int*)(wsb + ROWL_B);
  float* wlist = (float*)(wsb + WL_B);
  u16*   zp    = (u16*)(wsb + ZP_B);
  u16* prjTh = (u16*)(wsb + PRJH_B);
  u16* prjTl = (u16*)(wsb + PRJL_B);
  u16* e3Th  = (u16*)(wsb + E3TH_B);
  u16* e3Tl  = (u16*)(wsb + E3TL_B);
  u16* hl2P  = (u16*)(wsb + HL2P_B);
  u16* hdTh  = (u16*)(wsb + HDH_B);
  u16* hdTl  = (u16*)(wsb + HDL_B);

  // ---- fused weight prep (zero + conv repack + all pre-MoE transposes) ----
  k_prep_w<<<dim3(13157), 256, 0, stream>>>(
      counts, (int*)zp,
      conv1_w, wt1T, conv2_w, wt2T, conv3_w, wt3T,
      hlin1_w, hl1T,
      enc1_w, e1Th, e1Tl, enc2_w, e2Th, e2Tl, enc3_w, e3Th, e3Tl,
      proj_w, prjTh, prjTl, head_w, hdTh, hdTl, hlin2_w, hl2P);

  // ---- VAE encoder (hi/lo 3-term, K-split) + reparameterize ----
  k_split_x<<<dim3(10240), 256, 0, stream>>>(fut_ref, frh, frl, BATCH * 2560 / 4);
  k_ggps<2, 2><<<dim3(512), 256, 0, stream>>>(frh, frl, e1Th, e1Tl, Penc,
                                              1280, 2560, 2560, 8, 1024, 256);
  k_comb2<1><<<dim3(4096), 256, 0, stream>>>(Penc, Penc + (size_t)BATCH * 1024,
                                             enc1_b, e1h, e1l, 1024, BATCH * 1024 / 4);
  k_ggps<2, 2><<<dim3(512), 256, 0, stream>>>(e1h, e1l, e2Th, e2Tl, Penc,
                                              512, 1024, 1024, 8, 1024, 256);
  k_comb2<1><<<dim3(4096), 256, 0, stream>>>(Penc, Penc + (size_t)BATCH * 1024,
                                             enc2_b, e2h, e2l, 1024, BATCH * 1024 / 4);
  // enc3: K-split x8 (grid 256) then fused combine+reparameterize
  k_ggps<2, 2><<<dim3(256), 256, 0, stream>>>(e2h, e2l, e3Th, e3Tl, Penc,
                                              128, 1024, 1024, 1, 128, 32);
  k_combz<<<dim3(1024), 256, 0, stream>>>(Penc, enc3_b, noise, z, 8);

  // ---- history conv encoder ----
  k_f32_to_bf4<<<dim3(9600), 256, 0, stream>>>(hist_seq, hsb, BATCH * 25 * 96 / 4);
  k_gconv32<96, 25, 25, 1><<<dim3(1600), 256, 0, stream>>>(hsb, wt1T, conv1_b, y1b, zp, 256, 2);
  k_gconv64<256, 25, 13, 2><<<dim3(1664), 256, 0, stream>>>(y1b, wt2T, conv2_b, y2b, zp, 512, 4);
  k_gconv64<512, 13, 7, 2><<<dim3(1792), 256, 0, stream>>>(y2b, wt3T, conv3_b, y3b, zp, 1024, 8);
  k_mean7<<<dim3(16384), 256, 0, stream>>>(y3b, hb);
  k_gg64<1, 1><<<dim3(256), 256, 0, stream>>>(hb, hl1T, hlin1_b,
      nullptr, hi1b, nullptr, 1024, 1024, 1024, 8, 1024);
  // hlin2: K-split x8 (grid 256)
  k_ggps<1, 1><<<dim3(256), 256, 0, stream>>>(hi1b, nullptr, hl2P, nullptr, Phl2,
                                              128, 1024, 1024, 1, 128, 32);
  k_combS<0, 0><<<dim3(2048), 256, 0, stream>>>(Phl2, hlin2_b, hlat, nullptr,
                                                8, 7, 64, BATCH * 128);

  // ---- expert weight transposes, fused (y3 dead) ----
  k_prep_exp<<<dim3(24576), 256, 0, stream>>>(Wg, wgT, Wu, wuT, Wd, wdT);

  // ---- projection (3-term hi/lo MFMA) + router ----
  k_concat_split<<<dim3(6144), 256, 0, stream>>>(cur_obs, hlat, z, xch, xcl);
  k_gg<0, 0, 2, 2><<<dim3(128), 256, 0, stream>>>(xch, xcl, prjTh, prjTl, proj_b,
      x, nullptr, nullptr, 384, 384, 384, 4, 512);
  k_logits<<<dim3(512), 256, 0, stream>>>(x, router_w, router_b, logitsb);
  k_router<<<dim3(16), 256, 0, stream>>>(logitsb, tidA, twA, posA, counts);
  k_offsets<<<dim3(1), 64, 0, stream>>>(counts, offs);
  k_build_bf<<<dim3(2112), 256, 0, stream>>>(tidA, twA, posA, offs, rowlist, wlist, x, xh);

  // ---- MoE up (expert->XCD swizzled, pure bf16) ----
  k_gmoeup<<<dim3(4096), 256, 0, stream>>>(xh, wgT, wuT, bg, bu,
                                           rowlist, counts, offs, zp, tmoeb);

  // ---- sh/out weights + h2 zero, fused (wg/wu dead) ----
  k_prep_post<<<dim3(6656), 256, 0, stream>>>(shg_w, shgT, shu_w, shuT, shd_w, shdT,
                                              out1_w, o1T, out2_w, o2T, (float4*)h2);

  // ---- MoE down (BK=64, atomic scatter into h2) ----
  k_gmoedown64<<<dim3(2048), 256, 0, stream>>>(tmoeb, wdT, bd, rowlist, wlist,
                                               counts, offs, zp, h2);

  // ---- shared experts (1-term dual); down K-split x2; combine -> h2b bf16 ----
  k_gdual1<<<dim3(512), 256, 0, stream>>>(xh, shgT, shuT, shg_b, shu_b,
                                          stb, 2048, 512, 512, 512, 16);
  k_ggps<1, 1><<<dim3(256), 256, 0, stream>>>(stb, nullptr, shdT, nullptr, Psh,
                                              1024, 2048, 2048, 4, 512, 128);
  k_combS<0, 3><<<dim3(8192), 256, 0, stream>>>(Psh, shd_b, h2, h2b,
                                                2, 9, 512, BATCH * 512);

  // ---- output MLP (1-term bf16, BK=64; out2 emits pair) ----
  k_gg64<1, 1><<<dim3(256), 256, 0, stream>>>(h2b, o1T, out1_b,
      nullptr, o1b, nullptr, 512, 512, 512, 8, 1024);
  k_gg64<0, 3><<<dim3(256), 256, 0, stream>>>(o1b, o2T, out2_b,
      nullptr, o2h, o2l, 1024, 1024, 1024, 8, 1024);
  // head: K-split x8 (grid 256), combine into d_out (Nout=23)
  k_ggps<2, 2><<<dim3(256), 256, 0, stream>>>(o2h, o2l, hdTh, hdTl, Phd,
                                              128, 1024, 1024, 1, 128, 32);
  k_combS<0, 0><<<dim3(2048), 256, 0, stream>>>(Phd, head_b, (float*)d_out, nullptr,
                                                8, 7, 23, BATCH * 128);
}